// Round 6
// baseline (356.686 us; speedup 1.0000x reference)
//
#include <hip/hip_runtime.h>
#include <math.h>

// Problem constants
#define BB 16
#define CC 512
#define HW 784
#define RR 32
#define NHD 8
#define HD 64
#define NT 784
#define NTILE 49                       // 784 = 49 * 16 n-tiles
#define SPAD 788                       // padded LDS stripe stride

// workspace layout (float offsets)
#define OFS_AVGP   0
#define OFS_MAXP   8192
#define OFS_CHS    16384
#define OFS_CMAX   24576
#define OFS_CMEAN  37120
#define OFS_SP     49664
#define OFS_P1     62208
#define OFS_ABAR   70400
#define OFS_XG     78592
#define XG_SZ      (BB*CC*HW)          // 6,422,528 floats (region reused below)
#define OFS_XGT    (OFS_XG + XG_SZ)            // bf16 frag xg^T  (XG_SZ bf16)
#define OFS_QBF    (OFS_XGT + XG_SZ/2)         // bf16 frag Q     (XG_SZ bf16)
#define OFS_KBF    (OFS_QBF + XG_SZ/2)         // bf16 frag K     (XG_SZ bf16)
#define OFS_V2     (OFS_KBF + XG_SZ/2)         // bf16 V [bh][n][d]
#define OFS_WF     (OFS_V2 + XG_SZ)            // bf16 frag weights (786432 bf16)
// overlays inside the dead xg region:
#define OFS_W      OFS_XG                      // wsum   (100352 floats)
#define OFS_PV     (OFS_XG + 131072)           // pv     (8192)
#define OFS_LNV    (OFS_PV + 8192)             // lnv    (8192)
#define OFS_H1     (OFS_LNV + 8192)            // h1     (8192)
#define OFS_CGB    (OFS_XG + 262144)           // bf16 channel-gated x (XG_SZ bf16)

typedef __attribute__((ext_vector_type(8))) short bf16x8;
typedef __attribute__((ext_vector_type(4))) float f32x4;

__device__ __forceinline__ unsigned short f2bf(float x) {
  union { float f; unsigned u; } v; v.f = x;
  unsigned r = v.u + 0x7fffu + ((v.u >> 16) & 1u);
  return (unsigned short)(r >> 16);
}
__device__ __forceinline__ float bf2f(unsigned short x) {
  union { unsigned u; float f; } v; v.u = ((unsigned)x) << 16;
  return v.f;
}

// ---------------- K1: per-(b,c) avg + max pooling over HW -------------------
__global__ void k_pool(const float* __restrict__ x, float* avg_p, float* max_p) {
  int wid = threadIdx.x >> 6;
  int lane = threadIdx.x & 63;
  int row = blockIdx.x * 4 + wid;                 // b*C + c, 8192 rows
  const float* xr = x + (size_t)row * HW;
  float s = 0.f, m = -INFINITY;
  for (int i = lane; i < HW; i += 64) { float v = xr[i]; s += v; m = fmaxf(m, v); }
  for (int o = 32; o; o >>= 1) { s += __shfl_down(s, o, 64); m = fmaxf(m, __shfl_down(m, o, 64)); }
  if (lane == 0) { avg_p[row] = s * (1.f/HW); max_p[row] = m; }
}

// ---------------- K2: channel-gate MLP, one block per batch -----------------
__global__ void k_chmlp(const float* avg_p, const float* max_p,
                        const float* w1, const float* b1,
                        const float* w2, const float* b2, float* chs) {
  __shared__ float pa[CC], pm[CC], hr[64];
  int b = blockIdx.x, t = threadIdx.x;
  for (int i = t; i < CC; i += 256) { pa[i] = avg_p[b*CC+i]; pm[i] = max_p[b*CC+i]; }
  __syncthreads();
  if (t < 64) {
    int r = t & 31;
    const float* src = (t < 32) ? pa : pm;
    float h = b1[r];
    const float* wr = w1 + r*CC;
    for (int c = 0; c < CC; c++) h += src[c]*wr[c];
    hr[t] = fmaxf(h, 0.f);
  }
  __syncthreads();
  for (int c = t; c < CC; c += 256) {
    float a = 2.f*b2[c];                          // b2 added by both mlp() calls
    const float* wr = w2 + c*RR;
    for (int r = 0; r < RR; r++) a += (hr[r]+hr[32+r])*wr[r];
    chs[b*CC+c] = 1.f/(1.f+__expf(-a));
  }
}

// ---- K3: channel gate -> cmax/cmean per pixel + bf16 gated x (cgb) ---------
__global__ void k_chgate3(const float* __restrict__ x, const float* __restrict__ chs,
                          unsigned short* __restrict__ cgb, float* cmax, float* cmean) {
  __shared__ float cs[CC];
  int b = blockIdx.x, t = threadIdx.x;
  for (int i = t; i < CC; i += 256) cs[i] = chs[b*CC+i];
  __syncthreads();
  int pix = blockIdx.y * 256 + t;
  if (pix >= HW) return;
  const float* xb = x + (size_t)b*CC*HW + pix;
  unsigned short* cb = cgb + (size_t)b*CC*HW + pix;
  float mx = -INFINITY, sm = 0.f;
  for (int c = 0; c < CC; c++) {
    float v = xb[(size_t)c*HW] * cs[c];
    cb[(size_t)c*HW] = f2bf(v);
    mx = fmaxf(mx, v); sm += v;
  }
  cmax[b*HW+pix] = mx; cmean[b*HW+pix] = sm*(1.f/CC);
}

// ---------------- K4: 7x7 spatial conv + BN(eval) + sigmoid -----------------
__global__ void k_spconv(const float* __restrict__ cmax, const float* __restrict__ cmean,
                         const float* __restrict__ w,
                         const float* g, const float* be, const float* mu, const float* var,
                         float* sp) {
  int b = blockIdx.x;
  int pix = blockIdx.y*256 + threadIdx.x;
  if (pix >= HW) return;
  int h = pix/28, wd = pix%28;
  float acc = 0.f;
  for (int kh = 0; kh < 7; kh++) {
    int ih = h + kh - 3; if (ih < 0 || ih >= 28) continue;
    for (int kw = 0; kw < 7; kw++) {
      int iw = wd + kw - 3; if (iw < 0 || iw >= 28) continue;
      int ip = ih*28+iw;
      acc += cmax[b*HW+ip]*w[kh*7+kw] + cmean[b*HW+ip]*w[49+kh*7+kw];
    }
  }
  float s = (acc - mu[0])*rsqrtf(var[0]+1e-5f)*g[0] + be[0];
  sp[b*HW+pix] = 1.f/(1.f+__expf(-s));
}

// ---- K5: spatial gate on cgb -> fragment-ready bf16 xgT + pooled p1 --------
__global__ void k_sfuse2(const unsigned short* __restrict__ cgb, const float* __restrict__ sp,
                         unsigned short* __restrict__ xgT, float* __restrict__ p1) {
  int nt = blockIdx.x, b = blockIdx.y;
  int t = threadIdx.x, ln = t & 63;
  int n = nt*16 + (ln & 15);
  float spv = sp[b*HW + n];
  const unsigned short* cb = cgb + (size_t)b*CC*HW;
  #pragma unroll
  for (int i = 0; i < 4; i++) {
    int s = (t >> 6) + 4*i;
    int c = s*32 + (ln >> 4)*8;
    float v[8]; bf16x8 p;
    #pragma unroll
    for (int j = 0; j < 8; j++) {
      v[j] = bf2f(cb[(size_t)(c+j)*HW + n]) * spv;
      p[j] = (short)f2bf(v[j]);
    }
    *(bf16x8*)(xgT + ((((size_t)b*NTILE + nt)*16 + s)*64 + ln)*8) = p;
    #pragma unroll
    for (int j = 0; j < 8; j++) {
      float sv = v[j];
      sv += __shfl_xor(sv, 1, 64); sv += __shfl_xor(sv, 2, 64);
      sv += __shfl_xor(sv, 4, 64); sv += __shfl_xor(sv, 8, 64);
      if ((ln & 15) == 0) atomicAdd(&p1[b*CC + c + j], sv * (1.f/HW));
    }
  }
}

// ---- K5c: reformat wq/wk/wv into fragment-ready bf16 ----------------------
__global__ void k_wfrag(const float* __restrict__ wq, const float* __restrict__ wk,
                        const float* __restrict__ wv, unsigned short* __restrict__ Wf) {
  int idx = blockIdx.x*256 + threadIdx.x;         // 98304 chunks
  int ln = idx & 63;
  int s  = (idx >> 6) & 15;
  int ct = (idx >> 10) & 31;
  int mat = idx >> 15;
  const float* W = (mat==0)? wq : (mat==1)? wk : wv;
  const float* src = W + (size_t)(ct*16 + (ln & 15))*CC + s*32 + (ln >> 4)*8;
  float4 f0 = *(const float4*)src;
  float4 f1 = *(const float4*)(src + 4);
  bf16x8 p;
  p[0]=(short)f2bf(f0.x); p[1]=(short)f2bf(f0.y); p[2]=(short)f2bf(f0.z); p[3]=(short)f2bf(f0.w);
  p[4]=(short)f2bf(f1.x); p[5]=(short)f2bf(f1.y); p[6]=(short)f2bf(f1.z); p[7]=(short)f2bf(f1.w);
  *(bf16x8*)(Wf + (size_t)idx*8) = p;
}

// ---------------- K6: QKV projection — pure-MFMA, no LDS in K-loop ----------
__global__ __launch_bounds__(256) void k_qkv_mfma(
    const unsigned short* __restrict__ xgT, const unsigned short* __restrict__ Wf,
    const float* __restrict__ bq, const float* __restrict__ bk, const float* __restrict__ bv,
    unsigned short* __restrict__ Qbf, unsigned short* __restrict__ Kbf,
    unsigned short* __restrict__ Vbf) {
  __shared__ float Cb[64*132];                    // padded bounce tile (33.8 KB)
  int mt = blockIdx.x;                            // 0..12: n-tiles 4mt..4mt+3
  int yb = blockIdx.y;                            // 0..11: mat=yb>>2, c0=(yb&3)*128
  int b  = blockIdx.z;
  int mat = yb >> 2;
  int c0 = (yb & 3) * 128;
  int t = threadIdx.x, w = t >> 6, ln = t & 63;
  const unsigned short* Ab = xgT + (size_t)b*NTILE*8192;
  const unsigned short* Bb = Wf + (size_t)mat*32*8192;
  int ctg0 = (c0 >> 4) + w*2;
  f32x4 acc[4][2];
  #pragma unroll
  for (int m = 0; m < 4; m++)
    #pragma unroll
    for (int c2 = 0; c2 < 2; c2++) acc[m][c2] = (f32x4){0.f,0.f,0.f,0.f};
  int ntc[4];
  #pragma unroll
  for (int m = 0; m < 4; m++) { int nt = 4*mt + m; ntc[m] = (nt > 48) ? 48 : nt; }
  for (int s = 0; s < 16; s++) {
    bf16x8 bf0 = *(const bf16x8*)(Bb + (size_t)(ctg0*16 + s)*512 + ln*8);
    bf16x8 bf1 = *(const bf16x8*)(Bb + (size_t)((ctg0+1)*16 + s)*512 + ln*8);
    bf16x8 af[4];
    #pragma unroll
    for (int m = 0; m < 4; m++)
      af[m] = *(const bf16x8*)(Ab + (size_t)(ntc[m]*16 + s)*512 + ln*8);
    #pragma unroll
    for (int m = 0; m < 4; m++) {
      acc[m][0] = __builtin_amdgcn_mfma_f32_16x16x32_bf16(af[m], bf0, acc[m][0], 0,0,0);
      acc[m][1] = __builtin_amdgcn_mfma_f32_16x16x32_bf16(af[m], bf1, acc[m][1], 0,0,0);
    }
  }
  #pragma unroll
  for (int m = 0; m < 4; m++)
    #pragma unroll
    for (int c2 = 0; c2 < 2; c2++)
      #pragma unroll
      for (int r = 0; r < 4; r++)
        Cb[(m*16 + (ln>>4)*4 + r)*132 + w*32 + c2*16 + (ln&15)] = acc[m][c2][r];
  __syncthreads();
  const float* bias = (mat==0)? bq : (mat==1)? bk : bv;
  #pragma unroll
  for (int i = 0; i < 4; i++) {
    int p = w*4 + i;                              // 16 (ntl, sl) pairs
    int ntl = p >> 2, sl = p & 3;
    int nt = 4*mt + ntl;
    if (nt > 48) continue;
    int row = ntl*16 + (ln & 15);
    int col = sl*32 + (ln >> 4)*8;
    float v[8];
    #pragma unroll
    for (int j = 0; j < 8; j++) v[j] = Cb[row*132 + col + j] + bias[c0 + col + j];
    int token = nt*16 + (ln & 15);
    int h = (c0 >> 6) + (sl >> 1);
    int bh = b*NHD + h;
    bf16x8 pk;
    #pragma unroll
    for (int j = 0; j < 8; j++) pk[j] = (short)f2bf(v[j]);
    if (mat < 2) {
      unsigned short* Out = (mat == 0) ? Qbf : Kbf;
      *(bf16x8*)(Out + ((size_t)bh*NTILE + nt)*1024 + (size_t)(sl & 1)*512 + ln*8) = pk;
    } else {
      int d = (sl & 1)*32 + (ln >> 4)*8;
      *(bf16x8*)(Vbf + ((size_t)bh*NT + token)*HD + d) = pk;
    }
  }
}

// ---------------- K7: single-pass MFMA attention -> w_m ---------------------
// Block = (16-query n-tile nt, bh). Score stripe e=exp(s/8) computed ONCE into
// LDS (16 x 788 fp32), l_n accumulated in the same sweep, then column phase
// emits w_m partials: w_m += sum_n e[n][m] / l_n.
__global__ __launch_bounds__(256, 3) void k_attn4(const unsigned short* __restrict__ Qbf,
    const unsigned short* __restrict__ Kbf, float* __restrict__ wsum) {
  __shared__ float Se[16*SPAD];                   // 50.4 KB
  __shared__ float l_tmp[4*16];
  __shared__ float rl[16];
  int bh = blockIdx.x & 127, nt = blockIdx.x >> 7;
  int t = threadIdx.x, w = t >> 6, ln = t & 63;
  const unsigned short* Qb = Qbf + ((size_t)bh*NTILE + nt)*1024;
  const unsigned short* Kb = Kbf + (size_t)bh*NTILE*1024;
  bf16x8 q0 = *(const bf16x8*)(Qb + ln*8);
  bf16x8 q1 = *(const bf16x8*)(Qb + 512 + ln*8);
  float lp[4] = {0.f,0.f,0.f,0.f};
  for (int mt = w; mt < NTILE; mt += 4) {
    bf16x8 k0 = *(const bf16x8*)(Kb + (size_t)mt*1024 + ln*8);
    bf16x8 k1 = *(const bf16x8*)(Kb + (size_t)mt*1024 + 512 + ln*8);
    f32x4 a = {0.f,0.f,0.f,0.f};
    a = __builtin_amdgcn_mfma_f32_16x16x32_bf16(q0, k0, a, 0,0,0);
    a = __builtin_amdgcn_mfma_f32_16x16x32_bf16(q1, k1, a, 0,0,0);
    int m = mt*16 + (ln & 15);
    #pragma unroll
    for (int r = 0; r < 4; r++) {
      float e = __expf(a[r]*0.125f);
      Se[((ln>>4)*4 + r)*SPAD + m] = e;
      lp[r] += e;
    }
  }
  #pragma unroll
  for (int r = 0; r < 4; r++) {
    float v = lp[r];
    v += __shfl_xor(v,1,64); v += __shfl_xor(v,2,64);
    v += __shfl_xor(v,4,64); v += __shfl_xor(v,8,64);
    if ((ln & 15) == 0) l_tmp[w*16 + (ln>>4)*4 + r] = v;
  }
  __syncthreads();
  if (t < 16) rl[t] = 1.f / (l_tmp[t] + l_tmp[16+t] + l_tmp[32+t] + l_tmp[48+t]);
  __syncthreads();
  for (int m = t; m < NT; m += 256) {
    float s = 0.f;
    #pragma unroll
    for (int n = 0; n < 16; n++) s += Se[n*SPAD + m] * rl[n];
    atomicAdd(&wsum[bh*NT + m], s);
  }
}

// ---- K7c: abar[bh,d] = (1/N) sum_m w_m V[m,d] (V bf16) ---------------------
__global__ void k_attn_av(const float* __restrict__ w, const unsigned short* __restrict__ Vm,
                          float* __restrict__ abar) {
  __shared__ float red[256];
  int bh = blockIdx.x, t = threadIdx.x;
  int d = t & 63, chunk = t >> 6;                 // 4 chunks of 196 keys
  float acc = 0.f;
  const unsigned short* vb = Vm + (size_t)bh*NT*HD;
  const float* wb = w + bh*NT;
  for (int m = chunk*196; m < (chunk+1)*196; m++)
    acc += wb[m] * bf2f(vb[(size_t)m*HD + d]);
  red[t] = acc;
  __syncthreads();
  if (t < 64)
    abar[bh*HD + t] = (red[t] + red[64+t] + red[128+t] + red[192+t]) * (1.f/NT);
}

// --------- K8: pooled head, parallelized ------------------------------------
__global__ void k_headA(const float* __restrict__ p1, const float* __restrict__ abar,
                        const float* __restrict__ wo, const float* __restrict__ bo,
                        float* __restrict__ pv) {
  int b = blockIdx.x, cg = blockIdx.y;
  int t = threadIdx.x, w = t >> 6, ln = t & 63;
  float a[8];
  #pragma unroll
  for (int k = 0; k < 8; k++) a[k] = abar[b*CC + ln + 64*k];
  int c0 = cg*64 + w*16;
  for (int i = 0; i < 16; i++) {
    int c = c0 + i;
    const float* wr = wo + (size_t)c*CC;
    float s = 0.f;
    #pragma unroll
    for (int k = 0; k < 8; k++) s += a[k] * wr[ln + 64*k];
    for (int o = 32; o; o >>= 1) s += __shfl_down(s, o, 64);
    if (ln == 0) pv[b*CC + c] = s + bo[c] + p1[b*CC + c];
  }
}

__global__ void k_headB(const float* __restrict__ pv, const float* __restrict__ ln_g,
                        const float* __restrict__ ln_b, float* __restrict__ lnv) {
  int b = blockIdx.x, ln = threadIdx.x;
  float v[8], s = 0.f, s2 = 0.f;
  #pragma unroll
  for (int k = 0; k < 8; k++) { v[k] = pv[b*CC + ln + 64*k]; s += v[k]; s2 += v[k]*v[k]; }
  for (int o = 32; o; o >>= 1) { s += __shfl_down(s, o, 64); s2 += __shfl_down(s2, o, 64); }
  s = __shfl(s, 0, 64); s2 = __shfl(s2, 0, 64);
  float mean = s * (1.f/CC);
  float rs = rsqrtf(s2*(1.f/CC) - mean*mean + 1e-5f);
  #pragma unroll
  for (int k = 0; k < 8; k++) {
    int c = ln + 64*k;
    lnv[b*CC + c] = (v[k]-mean)*rs*ln_g[c] + ln_b[c];
  }
}

__global__ void k_headC(const float* __restrict__ lnv, const float* __restrict__ fc1_w,
                        const float* __restrict__ fc1_b, float* __restrict__ h1) {
  int b = blockIdx.x, cg = blockIdx.y;
  int t = threadIdx.x, w = t >> 6, ln = t & 63;
  float a[8];
  #pragma unroll
  for (int k = 0; k < 8; k++) a[k] = lnv[b*CC + ln + 64*k];
  int c0 = cg*64 + w*16;
  for (int i = 0; i < 16; i++) {
    int c = c0 + i;
    const float* wr = fc1_w + (size_t)c*CC;
    float s = 0.f;
    #pragma unroll
    for (int k = 0; k < 8; k++) s += a[k] * wr[ln + 64*k];
    for (int o = 32; o; o >>= 1) s += __shfl_down(s, o, 64);
    if (ln == 0) h1[b*CC + c] = fmaxf(s + fc1_b[c], 0.f);
  }
}

__global__ void k_headD(const float* __restrict__ h1, const float* __restrict__ fc2_w,
                        const float* __restrict__ fc2_b, float* __restrict__ out) {
  int b = blockIdx.x, ln = threadIdx.x;
  float s = 0.f;
  #pragma unroll
  for (int k = 0; k < 8; k++) s += h1[b*CC + ln + 64*k] * fc2_w[ln + 64*k];
  for (int o = 32; o; o >>= 1) s += __shfl_down(s, o, 64);
  if (ln == 0) out[b] = s + fc2_b[0];
}

extern "C" void kernel_launch(void* const* d_in, const int* in_sizes, int n_in,
                              void* d_out, int out_size, void* d_ws, size_t ws_size,
                              hipStream_t stream) {
  const float* x       = (const float*)d_in[0];
  const float* mlp_w1  = (const float*)d_in[1];
  const float* mlp_b1  = (const float*)d_in[2];
  const float* mlp_w2  = (const float*)d_in[3];
  const float* mlp_b2  = (const float*)d_in[4];
  const float* sp_w    = (const float*)d_in[5];
  const float* sp_g    = (const float*)d_in[6];
  const float* sp_b    = (const float*)d_in[7];
  const float* sp_mu   = (const float*)d_in[8];
  const float* sp_var  = (const float*)d_in[9];
  const float* wq      = (const float*)d_in[10];
  const float* bq      = (const float*)d_in[11];
  const float* wk      = (const float*)d_in[12];
  const float* bk      = (const float*)d_in[13];
  const float* wv      = (const float*)d_in[14];
  const float* bv      = (const float*)d_in[15];
  const float* wo      = (const float*)d_in[16];
  const float* bo      = (const float*)d_in[17];
  const float* ln_g    = (const float*)d_in[18];
  const float* ln_b    = (const float*)d_in[19];
  const float* fc1_w   = (const float*)d_in[20];
  const float* fc1_b   = (const float*)d_in[21];
  const float* fc2_w   = (const float*)d_in[22];
  const float* fc2_b   = (const float*)d_in[23];

  float* ws = (float*)d_ws;
  float* avg_p = ws + OFS_AVGP;
  float* max_p = ws + OFS_MAXP;
  float* chs   = ws + OFS_CHS;
  float* cmax  = ws + OFS_CMAX;
  float* cmean = ws + OFS_CMEAN;
  float* sp    = ws + OFS_SP;
  float* p1    = ws + OFS_P1;
  float* abar  = ws + OFS_ABAR;
  unsigned short* xgT = (unsigned short*)(ws + OFS_XGT);
  unsigned short* Qbf = (unsigned short*)(ws + OFS_QBF);
  unsigned short* Kbf = (unsigned short*)(ws + OFS_KBF);
  unsigned short* Vbf = (unsigned short*)(ws + OFS_V2);
  unsigned short* Wf  = (unsigned short*)(ws + OFS_WF);
  unsigned short* cgb = (unsigned short*)(ws + OFS_CGB);
  float* wsum  = ws + OFS_W;
  float* pv    = ws + OFS_PV;
  float* lnv   = ws + OFS_LNV;
  float* h1    = ws + OFS_H1;

  hipMemsetAsync(p1, 0, BB*CC*sizeof(float), stream);
  hipMemsetAsync(wsum, 0, BB*NHD*NT*sizeof(float), stream);

  k_pool   <<<2048, 256, 0, stream>>>(x, avg_p, max_p);
  k_chmlp  <<<BB, 256, 0, stream>>>(avg_p, max_p, mlp_w1, mlp_b1, mlp_w2, mlp_b2, chs);
  k_chgate3<<<dim3(BB,4), 256, 0, stream>>>(x, chs, cgb, cmax, cmean);
  k_spconv <<<dim3(BB,4), 256, 0, stream>>>(cmax, cmean, sp_w, sp_g, sp_b, sp_mu, sp_var, sp);
  k_wfrag  <<<384, 256, 0, stream>>>(wq, wk, wv, Wf);
  k_sfuse2 <<<dim3(NTILE,BB), 256, 0, stream>>>(cgb, sp, xgT, p1);
  k_qkv_mfma<<<dim3(13,12,BB), 256, 0, stream>>>(xgT, Wf, bq, bk, bv, Qbf, Kbf, Vbf);
  k_attn4  <<<NTILE*128, 256, 0, stream>>>(Qbf, Kbf, wsum);
  k_attn_av<<<128, 256, 0, stream>>>(wsum, Vbf, abar);
  k_headA  <<<dim3(BB,8), 256, 0, stream>>>(p1, abar, wo, bo, pv);
  k_headB  <<<BB, 64, 0, stream>>>(pv, ln_g, ln_b, lnv);
  k_headC  <<<dim3(BB,8), 256, 0, stream>>>(lnv, fc1_w, fc1_b, h1);
  k_headD  <<<BB, 64, 0, stream>>>(h1, fc2_w, fc2_b, (float*)d_out);
}

// Round 7
// 318.887 us; speedup vs baseline: 1.1185x; 1.1185x over previous
//
#include <hip/hip_runtime.h>
#include <math.h>

// Problem constants
#define BB 16
#define CC 512
#define HW 784
#define RR 32
#define NHD 8
#define HD 64
#define NT 784
#define NTILE 49                       // 784 = 49 * 16 n-tiles
#define SROW 20                        // words per m-row in attn LDS stripe

// workspace layout (float offsets)
#define OFS_AVGP   0
#define OFS_MAXP   8192
#define OFS_CHS    16384
#define OFS_CMAX   24576
#define OFS_CMEAN  37120
#define OFS_SP     49664
#define OFS_P1     62208
#define OFS_ABAR   70400
#define OFS_XG     78592
#define XG_SZ      (BB*CC*HW)          // 6,422,528 floats (region reused below)
#define OFS_XGT    (OFS_XG + XG_SZ)            // bf16 frag xg^T  (XG_SZ bf16)
#define OFS_QBF    (OFS_XGT + XG_SZ/2)         // bf16 frag Q     (XG_SZ bf16)
#define OFS_KBF    (OFS_QBF + XG_SZ/2)         // bf16 frag K     (XG_SZ bf16)
#define OFS_V2     (OFS_KBF + XG_SZ/2)         // bf16 V [bh][n][d]
#define OFS_WF     (OFS_V2 + XG_SZ)            // bf16 frag weights (786432 bf16)
// overlays inside the dead xg region:
#define OFS_W      OFS_XG                      // wsum   (100352 floats)
#define OFS_PV     (OFS_XG + 131072)           // pv     (8192)
#define OFS_LNV    (OFS_PV + 8192)             // lnv    (8192)
#define OFS_H1     (OFS_LNV + 8192)            // h1     (8192)
#define OFS_CMAXP  (OFS_XG + 262144)           // partial cmax [16][16][784]
#define OFS_CMEANP (OFS_CMAXP + 200704)        // partial csum [16][16][784]

typedef __attribute__((ext_vector_type(8))) short bf16x8;
typedef __attribute__((ext_vector_type(4))) float f32x4;

__device__ __forceinline__ unsigned short f2bf(float x) {
  union { float f; unsigned u; } v; v.f = x;
  unsigned r = v.u + 0x7fffu + ((v.u >> 16) & 1u);
  return (unsigned short)(r >> 16);
}
__device__ __forceinline__ float bf2f(unsigned short x) {
  union { unsigned u; float f; } v; v.u = ((unsigned)x) << 16;
  return v.f;
}

// ---------------- K1: per-(b,c) avg + max pooling over HW -------------------
__global__ void k_pool(const float* __restrict__ x, float* avg_p, float* max_p) {
  int wid = threadIdx.x >> 6;
  int lane = threadIdx.x & 63;
  int row = blockIdx.x * 4 + wid;                 // b*C + c, 8192 rows
  const float* xr = x + (size_t)row * HW;
  float s = 0.f, m = -INFINITY;
  for (int i = lane; i < HW; i += 64) { float v = xr[i]; s += v; m = fmaxf(m, v); }
  for (int o = 32; o; o >>= 1) { s += __shfl_down(s, o, 64); m = fmaxf(m, __shfl_down(m, o, 64)); }
  if (lane == 0) { avg_p[row] = s * (1.f/HW); max_p[row] = m; }
}

// ---------------- K2: channel-gate MLP, one block per batch -----------------
__global__ void k_chmlp(const float* avg_p, const float* max_p,
                        const float* w1, const float* b1,
                        const float* w2, const float* b2, float* chs) {
  __shared__ float pa[CC], pm[CC], part[256], hr[64];
  int b = blockIdx.x, t = threadIdx.x;
  for (int i = t; i < CC; i += 256) { pa[i] = avg_p[b*CC+i]; pm[i] = max_p[b*CC+i]; }
  __syncthreads();
  // phase 1: 64 dots (r,pool) x 4 chunks of 128
  {
    int rp = t & 63, ch = t >> 6;
    int r = rp & 31;
    const float* src = (rp < 32) ? pa : pm;
    const float* wr = w1 + (size_t)r*CC + ch*128;
    float s = 0.f;
    #pragma unroll 8
    for (int c = 0; c < 128; c++) s += src[ch*128 + c] * wr[c];
    part[t] = s;
  }
  __syncthreads();
  if (t < 64)
    hr[t] = fmaxf(part[t] + part[64+t] + part[128+t] + part[192+t] + b1[t & 31], 0.f);
  __syncthreads();
  for (int c = t; c < CC; c += 256) {
    float a = 2.f*b2[c];                          // b2 added by both mlp() calls
    const float* wr = w2 + c*RR;
    #pragma unroll
    for (int r = 0; r < RR; r++) a += (hr[r]+hr[32+r])*wr[r];
    chs[b*CC+c] = 1.f/(1.f+__expf(-a));
  }
}

// ---- K3a: channel gate partials: per (b, 32-ch chunk) max/sum per pixel ----
__global__ void k_chgatep(const float* __restrict__ x, const float* __restrict__ chs,
                          float* __restrict__ cmaxp, float* __restrict__ cmeanp) {
  __shared__ float cs[32];
  int b = blockIdx.x, cg = blockIdx.y, t = threadIdx.x;
  if (t < 32) cs[t] = chs[b*CC + cg*32 + t];
  __syncthreads();
  const float* xb = x + ((size_t)b*CC + cg*32)*HW;
  for (int pix = t; pix < HW; pix += 256) {
    float mx = -INFINITY, sm = 0.f;
    #pragma unroll
    for (int c = 0; c < 32; c++) {
      float v = xb[(size_t)c*HW + pix] * cs[c];
      mx = fmaxf(mx, v); sm += v;
    }
    cmaxp[(size_t)(cg*BB + b)*HW + pix] = mx;
    cmeanp[(size_t)(cg*BB + b)*HW + pix] = sm;
  }
}

// ---- K3b: reduce 16 partials -> final cmax / cmean -------------------------
__global__ void k_cred(const float* __restrict__ cmaxp, const float* __restrict__ cmeanp,
                       float* __restrict__ cmax, float* __restrict__ cmean) {
  int idx = blockIdx.x*256 + threadIdx.x;         // b*HW + pix
  if (idx >= BB*HW) return;
  int b = idx / HW, pix = idx % HW;
  float mx = -INFINITY, sm = 0.f;
  #pragma unroll
  for (int cg = 0; cg < 16; cg++) {
    mx = fmaxf(mx, cmaxp[(size_t)(cg*BB + b)*HW + pix]);
    sm += cmeanp[(size_t)(cg*BB + b)*HW + pix];
  }
  cmax[idx] = mx; cmean[idx] = sm * (1.f/CC);
}

// ---------------- K4: 7x7 spatial conv + BN(eval) + sigmoid -----------------
__global__ void k_spconv(const float* __restrict__ cmax, const float* __restrict__ cmean,
                         const float* __restrict__ w,
                         const float* g, const float* be, const float* mu, const float* var,
                         float* sp) {
  int b = blockIdx.x;
  int pix = blockIdx.y*256 + threadIdx.x;
  if (pix >= HW) return;
  int h = pix/28, wd = pix%28;
  float acc = 0.f;
  for (int kh = 0; kh < 7; kh++) {
    int ih = h + kh - 3; if (ih < 0 || ih >= 28) continue;
    for (int kw = 0; kw < 7; kw++) {
      int iw = wd + kw - 3; if (iw < 0 || iw >= 28) continue;
      int ip = ih*28+iw;
      acc += cmax[b*HW+ip]*w[kh*7+kw] + cmean[b*HW+ip]*w[49+kh*7+kw];
    }
  }
  float s = (acc - mu[0])*rsqrtf(var[0]+1e-5f)*g[0] + be[0];
  sp[b*HW+pix] = 1.f/(1.f+__expf(-s));
}

// ---- K5: fused gates -> fragment-ready bf16 xgT + pooled p1 ----------------
__global__ void k_sfuse(const float* __restrict__ x, const float* __restrict__ chs,
                        const float* __restrict__ sp, unsigned short* __restrict__ xgT,
                        float* __restrict__ p1) {
  __shared__ float cs[CC];
  int nt = blockIdx.x, b = blockIdx.y;
  int t = threadIdx.x, ln = t & 63;
  for (int i = t; i < CC; i += 256) cs[i] = chs[b*CC+i];
  __syncthreads();
  int n = nt*16 + (ln & 15);
  float spv = sp[b*HW + n];
  const float* xb = x + (size_t)b*CC*HW;
  #pragma unroll
  for (int i = 0; i < 4; i++) {
    int s = (t >> 6) + 4*i;
    int c = s*32 + (ln >> 4)*8;
    float v[8]; bf16x8 p;
    #pragma unroll
    for (int j = 0; j < 8; j++) {
      v[j] = xb[(size_t)(c+j)*HW + n] * cs[c+j] * spv;
      p[j] = (short)f2bf(v[j]);
    }
    *(bf16x8*)(xgT + ((((size_t)b*NTILE + nt)*16 + s)*64 + ln)*8) = p;
    #pragma unroll
    for (int j = 0; j < 8; j++) {
      float sv = v[j];
      sv += __shfl_xor(sv, 1, 64); sv += __shfl_xor(sv, 2, 64);
      sv += __shfl_xor(sv, 4, 64); sv += __shfl_xor(sv, 8, 64);
      if ((ln & 15) == 0) atomicAdd(&p1[b*CC + c + j], sv * (1.f/HW));
    }
  }
}

// ---- K5c: reformat wq/wk/wv into fragment-ready bf16 ----------------------
__global__ void k_wfrag(const float* __restrict__ wq, const float* __restrict__ wk,
                        const float* __restrict__ wv, unsigned short* __restrict__ Wf) {
  int idx = blockIdx.x*256 + threadIdx.x;         // 98304 chunks
  int ln = idx & 63;
  int s  = (idx >> 6) & 15;
  int ct = (idx >> 10) & 31;
  int mat = idx >> 15;
  const float* W = (mat==0)? wq : (mat==1)? wk : wv;
  const float* src = W + (size_t)(ct*16 + (ln & 15))*CC + s*32 + (ln >> 4)*8;
  float4 f0 = *(const float4*)src;
  float4 f1 = *(const float4*)(src + 4);
  bf16x8 p;
  p[0]=(short)f2bf(f0.x); p[1]=(short)f2bf(f0.y); p[2]=(short)f2bf(f0.z); p[3]=(short)f2bf(f0.w);
  p[4]=(short)f2bf(f1.x); p[5]=(short)f2bf(f1.y); p[6]=(short)f2bf(f1.z); p[7]=(short)f2bf(f1.w);
  *(bf16x8*)(Wf + (size_t)idx*8) = p;
}

// ---------------- K6: QKV projection — pure-MFMA, no LDS in K-loop ----------
__global__ __launch_bounds__(256) void k_qkv_mfma(
    const unsigned short* __restrict__ xgT, const unsigned short* __restrict__ Wf,
    const float* __restrict__ bq, const float* __restrict__ bk, const float* __restrict__ bv,
    unsigned short* __restrict__ Qbf, unsigned short* __restrict__ Kbf,
    unsigned short* __restrict__ Vbf) {
  __shared__ float Cb[64*132];                    // padded bounce tile (33.8 KB)
  int mt = blockIdx.x;                            // 0..12: n-tiles 4mt..4mt+3
  int yb = blockIdx.y;                            // 0..11: mat=yb>>2, c0=(yb&3)*128
  int b  = blockIdx.z;
  int mat = yb >> 2;
  int c0 = (yb & 3) * 128;
  int t = threadIdx.x, w = t >> 6, ln = t & 63;
  const unsigned short* Ab = xgT + (size_t)b*NTILE*8192;
  const unsigned short* Bb = Wf + (size_t)mat*32*8192;
  int ctg0 = (c0 >> 4) + w*2;
  f32x4 acc[4][2];
  #pragma unroll
  for (int m = 0; m < 4; m++)
    #pragma unroll
    for (int c2 = 0; c2 < 2; c2++) acc[m][c2] = (f32x4){0.f,0.f,0.f,0.f};
  int ntc[4];
  #pragma unroll
  for (int m = 0; m < 4; m++) { int nt = 4*mt + m; ntc[m] = (nt > 48) ? 48 : nt; }
  for (int s = 0; s < 16; s++) {
    bf16x8 bf0 = *(const bf16x8*)(Bb + (size_t)(ctg0*16 + s)*512 + ln*8);
    bf16x8 bf1 = *(const bf16x8*)(Bb + (size_t)((ctg0+1)*16 + s)*512 + ln*8);
    bf16x8 af[4];
    #pragma unroll
    for (int m = 0; m < 4; m++)
      af[m] = *(const bf16x8*)(Ab + (size_t)(ntc[m]*16 + s)*512 + ln*8);
    #pragma unroll
    for (int m = 0; m < 4; m++) {
      acc[m][0] = __builtin_amdgcn_mfma_f32_16x16x32_bf16(af[m], bf0, acc[m][0], 0,0,0);
      acc[m][1] = __builtin_amdgcn_mfma_f32_16x16x32_bf16(af[m], bf1, acc[m][1], 0,0,0);
    }
  }
  #pragma unroll
  for (int m = 0; m < 4; m++)
    #pragma unroll
    for (int c2 = 0; c2 < 2; c2++)
      #pragma unroll
      for (int r = 0; r < 4; r++)
        Cb[(m*16 + (ln>>4)*4 + r)*132 + w*32 + c2*16 + (ln&15)] = acc[m][c2][r];
  __syncthreads();
  const float* bias = (mat==0)? bq : (mat==1)? bk : bv;
  #pragma unroll
  for (int i = 0; i < 4; i++) {
    int p = w*4 + i;                              // 16 (ntl, sl) pairs
    int ntl = p >> 2, sl = p & 3;
    int nt = 4*mt + ntl;
    if (nt > 48) continue;
    int row = ntl*16 + (ln & 15);
    int col = sl*32 + (ln >> 4)*8;
    float v[8];
    #pragma unroll
    for (int j = 0; j < 8; j++) v[j] = Cb[row*132 + col + j] + bias[c0 + col + j];
    int token = nt*16 + (ln & 15);
    int h = (c0 >> 6) + (sl >> 1);
    int bh = b*NHD + h;
    bf16x8 pk;
    #pragma unroll
    for (int j = 0; j < 8; j++) pk[j] = (short)f2bf(v[j]);
    if (mat < 2) {
      unsigned short* Out = (mat == 0) ? Qbf : Kbf;
      *(bf16x8*)(Out + ((size_t)bh*NTILE + nt)*1024 + (size_t)(sl & 1)*512 + ln*8) = pk;
    } else {
      int d = (sl & 1)*32 + (ln >> 4)*8;
      *(bf16x8*)(Vbf + ((size_t)bh*NT + token)*HD + d) = pk;
    }
  }
}

// ---------------- K7: single-pass MFMA attention -> w_m ---------------------
// Block = (16-query n-tile nt, bh). Score stripe e=exp(s/8) stored m-major
// (row stride 20 words -> banks spread): score phase writes one b128/lane,
// column phase reads each m-row as 4x b128.
__global__ __launch_bounds__(256, 2) void k_attn5(const unsigned short* __restrict__ Qbf,
    const unsigned short* __restrict__ Kbf, float* __restrict__ wsum) {
  __shared__ float Se[NTILE*16*SROW];             // 62.7 KB
  __shared__ float l_tmp[64];
  __shared__ float rl[16];
  int bh = blockIdx.x & 127, nt = blockIdx.x >> 7;
  int t = threadIdx.x, w = t >> 6, ln = t & 63;
  const unsigned short* Qb = Qbf + ((size_t)bh*NTILE + nt)*1024;
  const unsigned short* Kb = Kbf + (size_t)bh*NTILE*1024;
  bf16x8 q0 = *(const bf16x8*)(Qb + ln*8);
  bf16x8 q1 = *(const bf16x8*)(Qb + 512 + ln*8);
  float lp[4] = {0.f,0.f,0.f,0.f};
  for (int mt = w; mt < NTILE; mt += 4) {
    bf16x8 k0 = *(const bf16x8*)(Kb + (size_t)mt*1024 + ln*8);
    bf16x8 k1 = *(const bf16x8*)(Kb + (size_t)mt*1024 + 512 + ln*8);
    f32x4 a = {0.f,0.f,0.f,0.f};
    a = __builtin_amdgcn_mfma_f32_16x16x32_bf16(q0, k0, a, 0,0,0);
    a = __builtin_amdgcn_mfma_f32_16x16x32_bf16(q1, k1, a, 0,0,0);
    int m = mt*16 + (ln & 15);
    f32x4 ev;
    #pragma unroll
    for (int r = 0; r < 4; r++) {
      ev[r] = __expf(a[r]*0.125f);                // n = (ln>>4)*4 + r
      lp[r] += ev[r];
    }
    *(f32x4*)&Se[m*SROW + (ln>>4)*4] = ev;        // one ds_write_b128
  }
  #pragma unroll
  for (int r = 0; r < 4; r++) {
    float v = lp[r];
    v += __shfl_xor(v,1,64); v += __shfl_xor(v,2,64);
    v += __shfl_xor(v,4,64); v += __shfl_xor(v,8,64);
    if ((ln & 15) == 0) l_tmp[w*16 + (ln>>4)*4 + r] = v;
  }
  __syncthreads();
  if (t < 16) rl[t] = 1.f / (l_tmp[t] + l_tmp[16+t] + l_tmp[32+t] + l_tmp[48+t]);
  __syncthreads();
  f32x4 rlv[4];
  #pragma unroll
  for (int j = 0; j < 4; j++) rlv[j] = *(const f32x4*)&rl[j*4];
  for (int m = t; m < NT; m += 256) {
    const float* row = &Se[m*SROW];
    float s = 0.f;
    #pragma unroll
    for (int j = 0; j < 4; j++) {
      f32x4 e = *(const f32x4*)&row[j*4];         // ds_read_b128
      s += e[0]*rlv[j][0] + e[1]*rlv[j][1] + e[2]*rlv[j][2] + e[3]*rlv[j][3];
    }
    atomicAdd(&wsum[bh*NT + m], s);
  }
}

// ---- K7c: abar[bh,d] = (1/N) sum_m w_m V[m,d] (V bf16) ---------------------
__global__ void k_attn_av(const float* __restrict__ w, const unsigned short* __restrict__ Vm,
                          float* __restrict__ abar) {
  __shared__ float red[256];
  int bh = blockIdx.x, t = threadIdx.x;
  int d = t & 63, chunk = t >> 6;                 // 4 chunks of 196 keys
  float acc = 0.f;
  const unsigned short* vb = Vm + (size_t)bh*NT*HD;
  const float* wb = w + bh*NT;
  for (int m = chunk*196; m < (chunk+1)*196; m++)
    acc += wb[m] * bf2f(vb[(size_t)m*HD + d]);
  red[t] = acc;
  __syncthreads();
  if (t < 64)
    abar[bh*HD + t] = (red[t] + red[64+t] + red[128+t] + red[192+t]) * (1.f/NT);
}

// --------- K8: pooled head, parallelized ------------------------------------
__global__ void k_headA(const float* __restrict__ p1, const float* __restrict__ abar,
                        const float* __restrict__ wo, const float* __restrict__ bo,
                        float* __restrict__ pv) {
  int b = blockIdx.x, cg = blockIdx.y;
  int t = threadIdx.x, w = t >> 6, ln = t & 63;
  float a[8];
  #pragma unroll
  for (int k = 0; k < 8; k++) a[k] = abar[b*CC + ln + 64*k];
  int c0 = cg*64 + w*16;
  for (int i = 0; i < 16; i++) {
    int c = c0 + i;
    const float* wr = wo + (size_t)c*CC;
    float s = 0.f;
    #pragma unroll
    for (int k = 0; k < 8; k++) s += a[k] * wr[ln + 64*k];
    for (int o = 32; o; o >>= 1) s += __shfl_down(s, o, 64);
    if (ln == 0) pv[b*CC + c] = s + bo[c] + p1[b*CC + c];
  }
}

__global__ void k_headB(const float* __restrict__ pv, const float* __restrict__ ln_g,
                        const float* __restrict__ ln_b, float* __restrict__ lnv) {
  int b = blockIdx.x, ln = threadIdx.x;
  float v[8], s = 0.f, s2 = 0.f;
  #pragma unroll
  for (int k = 0; k < 8; k++) { v[k] = pv[b*CC + ln + 64*k]; s += v[k]; s2 += v[k]*v[k]; }
  for (int o = 32; o; o >>= 1) { s += __shfl_down(s, o, 64); s2 += __shfl_down(s2, o, 64); }
  s = __shfl(s, 0, 64); s2 = __shfl(s2, 0, 64);
  float mean = s * (1.f/CC);
  float rs = rsqrtf(s2*(1.f/CC) - mean*mean + 1e-5f);
  #pragma unroll
  for (int k = 0; k < 8; k++) {
    int c = ln + 64*k;
    lnv[b*CC + c] = (v[k]-mean)*rs*ln_g[c] + ln_b[c];
  }
}

__global__ void k_headC(const float* __restrict__ lnv, const float* __restrict__ fc1_w,
                        const float* __restrict__ fc1_b, float* __restrict__ h1) {
  int b = blockIdx.x, cg = blockIdx.y;
  int t = threadIdx.x, w = t >> 6, ln = t & 63;
  float a[8];
  #pragma unroll
  for (int k = 0; k < 8; k++) a[k] = lnv[b*CC + ln + 64*k];
  int c0 = cg*64 + w*16;
  for (int i = 0; i < 16; i++) {
    int c = c0 + i;
    const float* wr = fc1_w + (size_t)c*CC;
    float s = 0.f;
    #pragma unroll
    for (int k = 0; k < 8; k++) s += a[k] * wr[ln + 64*k];
    for (int o = 32; o; o >>= 1) s += __shfl_down(s, o, 64);
    if (ln == 0) h1[b*CC + c] = fmaxf(s + fc1_b[c], 0.f);
  }
}

__global__ void k_headD(const float* __restrict__ h1, const float* __restrict__ fc2_w,
                        const float* __restrict__ fc2_b, float* __restrict__ out) {
  int b = blockIdx.x, ln = threadIdx.x;
  float s = 0.f;
  #pragma unroll
  for (int k = 0; k < 8; k++) s += h1[b*CC + ln + 64*k] * fc2_w[ln + 64*k];
  for (int o = 32; o; o >>= 1) s += __shfl_down(s, o, 64);
  if (ln == 0) out[b] = s + fc2_b[0];
}

extern "C" void kernel_launch(void* const* d_in, const int* in_sizes, int n_in,
                              void* d_out, int out_size, void* d_ws, size_t ws_size,
                              hipStream_t stream) {
  const float* x       = (const float*)d_in[0];
  const float* mlp_w1  = (const float*)d_in[1];
  const float* mlp_b1  = (const float*)d_in[2];
  const float* mlp_w2  = (const float*)d_in[3];
  const float* mlp_b2  = (const float*)d_in[4];
  const float* sp_w    = (const float*)d_in[5];
  const float* sp_g    = (const float*)d_in[6];
  const float* sp_b    = (const float*)d_in[7];
  const float* sp_mu   = (const float*)d_in[8];
  const float* sp_var  = (const float*)d_in[9];
  const float* wq      = (const float*)d_in[10];
  const float* bq      = (const float*)d_in[11];
  const float* wk      = (const float*)d_in[12];
  const float* bk      = (const float*)d_in[13];
  const float* wv      = (const float*)d_in[14];
  const float* bv      = (const float*)d_in[15];
  const float* wo      = (const float*)d_in[16];
  const float* bo      = (const float*)d_in[17];
  const float* ln_g    = (const float*)d_in[18];
  const float* ln_b    = (const float*)d_in[19];
  const float* fc1_w   = (const float*)d_in[20];
  const float* fc1_b   = (const float*)d_in[21];
  const float* fc2_w   = (const float*)d_in[22];
  const float* fc2_b   = (const float*)d_in[23];

  float* ws = (float*)d_ws;
  float* avg_p = ws + OFS_AVGP;
  float* max_p = ws + OFS_MAXP;
  float* chs   = ws + OFS_CHS;
  float* cmax  = ws + OFS_CMAX;
  float* cmean = ws + OFS_CMEAN;
  float* sp    = ws + OFS_SP;
  float* p1    = ws + OFS_P1;
  float* abar  = ws + OFS_ABAR;
  unsigned short* xgT = (unsigned short*)(ws + OFS_XGT);
  unsigned short* Qbf = (unsigned short*)(ws + OFS_QBF);
  unsigned short* Kbf = (unsigned short*)(ws + OFS_KBF);
  unsigned short* Vbf = (unsigned short*)(ws + OFS_V2);
  unsigned short* Wf  = (unsigned short*)(ws + OFS_WF);
  float* wsum  = ws + OFS_W;
  float* pv    = ws + OFS_PV;
  float* lnv   = ws + OFS_LNV;
  float* h1    = ws + OFS_H1;
  float* cmaxp = ws + OFS_CMAXP;
  float* cmeanp= ws + OFS_CMEANP;

  hipMemsetAsync(p1, 0, BB*CC*sizeof(float), stream);
  hipMemsetAsync(wsum, 0, BB*NHD*NT*sizeof(float), stream);

  k_pool   <<<2048, 256, 0, stream>>>(x, avg_p, max_p);
  k_chmlp  <<<BB, 256, 0, stream>>>(avg_p, max_p, mlp_w1, mlp_b1, mlp_w2, mlp_b2, chs);
  k_chgatep<<<dim3(BB,16), 256, 0, stream>>>(x, chs, cmaxp, cmeanp);
  k_cred   <<<49, 256, 0, stream>>>(cmaxp, cmeanp, cmax, cmean);
  k_spconv <<<dim3(BB,4), 256, 0, stream>>>(cmax, cmean, sp_w, sp_g, sp_b, sp_mu, sp_var, sp);
  k_wfrag  <<<384, 256, 0, stream>>>(wq, wk, wv, Wf);
  k_sfuse  <<<dim3(NTILE,BB), 256, 0, stream>>>(x, chs, sp, xgT, p1);
  k_qkv_mfma<<<dim3(13,12,BB), 256, 0, stream>>>(xgT, Wf, bq, bk, bv, Qbf, Kbf, Vbf);
  k_attn5  <<<NTILE*128, 256, 0, stream>>>(Qbf, Kbf, wsum);
  k_attn_av<<<128, 256, 0, stream>>>(wsum, Vbf, abar);
  k_headA  <<<dim3(BB,8), 256, 0, stream>>>(p1, abar, wo, bo, pv);
  k_headB  <<<BB, 64, 0, stream>>>(pv, ln_g, ln_b, lnv);
  k_headC  <<<dim3(BB,8), 256, 0, stream>>>(lnv, fc1_w, fc1_b, h1);
  k_headD  <<<BB, 64, 0, stream>>>(h1, fc2_w, fc2_b, (float*)d_out);
}

// Round 8
// 301.779 us; speedup vs baseline: 1.1819x; 1.0567x over previous
//
#include <hip/hip_runtime.h>
#include <math.h>

// Problem constants
#define BB 16
#define CC 512
#define HW 784
#define RR 32
#define NHD 8
#define HD 64
#define NT 784
#define NTILE 49                       // 784 = 49 * 16 n-tiles
#define SROWH 20                       // halfs per m-row (16 data + 4 pad)

// workspace layout (float offsets)
#define OFS_AVGP   0
#define OFS_MAXP   8192
#define OFS_CHS    16384
#define OFS_CMAX   24576
#define OFS_CMEAN  37120
#define OFS_SP     49664
#define OFS_P1     62208
#define OFS_ABAR   70400
#define OFS_XG     78592
#define XG_SZ      (BB*CC*HW)          // 6,422,528 floats (region reused below)
#define OFS_XGT    (OFS_XG + XG_SZ)            // bf16 frag xg^T  (XG_SZ bf16)
#define OFS_QBF    (OFS_XGT + XG_SZ/2)         // bf16 frag Q     (XG_SZ bf16)
#define OFS_KBF    (OFS_QBF + XG_SZ/2)         // bf16 frag K     (XG_SZ bf16)
#define OFS_V2     (OFS_KBF + XG_SZ/2)         // bf16 V [bh][n][d]
#define OFS_WF     (OFS_V2 + XG_SZ)            // bf16 frag weights (786432 bf16)
// overlays inside the dead xg region:
#define OFS_W      OFS_XG                      // wsum   (100352 floats)
#define OFS_PV     (OFS_XG + 131072)           // pv     (8192)
#define OFS_LNV    (OFS_PV + 8192)             // lnv    (8192)
#define OFS_H1     (OFS_LNV + 8192)            // h1     (8192)
#define OFS_CMAXP  (OFS_XG + 262144)           // partial cmax [16][16][784]
#define OFS_CMEANP (OFS_CMAXP + 200704)        // partial csum [16][16][784]

typedef __attribute__((ext_vector_type(8))) short bf16x8;
typedef __attribute__((ext_vector_type(4))) float f32x4;
typedef __attribute__((ext_vector_type(4))) _Float16 h16x4;

__device__ __forceinline__ unsigned short f2bf(float x) {
  union { float f; unsigned u; } v; v.f = x;
  unsigned r = v.u + 0x7fffu + ((v.u >> 16) & 1u);
  return (unsigned short)(r >> 16);
}
__device__ __forceinline__ float bf2f(unsigned short x) {
  union { unsigned u; float f; } v; v.u = ((unsigned)x) << 16;
  return v.f;
}

// ---------------- K1: per-(b,c) avg + max pooling over HW -------------------
__global__ void k_pool(const float* __restrict__ x, float* avg_p, float* max_p) {
  int wid = threadIdx.x >> 6;
  int lane = threadIdx.x & 63;
  int row = blockIdx.x * 4 + wid;                 // b*C + c, 8192 rows
  const float* xr = x + (size_t)row * HW;
  float s = 0.f, m = -INFINITY;
  for (int i = lane; i < HW; i += 64) { float v = xr[i]; s += v; m = fmaxf(m, v); }
  for (int o = 32; o; o >>= 1) { s += __shfl_down(s, o, 64); m = fmaxf(m, __shfl_down(m, o, 64)); }
  if (lane == 0) { avg_p[row] = s * (1.f/HW); max_p[row] = m; }
}

// ---------------- K2: channel-gate MLP, one block per batch -----------------
__global__ void k_chmlp(const float* avg_p, const float* max_p,
                        const float* w1, const float* b1,
                        const float* w2, const float* b2, float* chs) {
  __shared__ float pa[CC], pm[CC], part[256], hr[64];
  int b = blockIdx.x, t = threadIdx.x;
  for (int i = t; i < CC; i += 256) { pa[i] = avg_p[b*CC+i]; pm[i] = max_p[b*CC+i]; }
  __syncthreads();
  // phase 1: 64 dots (r,pool) x 4 chunks of 128
  {
    int rp = t & 63, ch = t >> 6;
    int r = rp & 31;
    const float* src = (rp < 32) ? pa : pm;
    const float* wr = w1 + (size_t)r*CC + ch*128;
    float s = 0.f;
    #pragma unroll 8
    for (int c = 0; c < 128; c++) s += src[ch*128 + c] * wr[c];
    part[t] = s;
  }
  __syncthreads();
  if (t < 64)
    hr[t] = fmaxf(part[t] + part[64+t] + part[128+t] + part[192+t] + b1[t & 31], 0.f);
  __syncthreads();
  for (int c = t; c < CC; c += 256) {
    float a = 2.f*b2[c];                          // b2 added by both mlp() calls
    const float* wr = w2 + c*RR;
    #pragma unroll
    for (int r = 0; r < RR; r++) a += (hr[r]+hr[32+r])*wr[r];
    chs[b*CC+c] = 1.f/(1.f+__expf(-a));
  }
}

// ---- K3a: channel gate partials: per (b, 32-ch chunk) max/sum per pixel ----
__global__ void k_chgatep(const float* __restrict__ x, const float* __restrict__ chs,
                          float* __restrict__ cmaxp, float* __restrict__ cmeanp) {
  __shared__ float cs[32];
  int b = blockIdx.x, cg = blockIdx.y, t = threadIdx.x;
  if (t < 32) cs[t] = chs[b*CC + cg*32 + t];
  __syncthreads();
  const float* xb = x + ((size_t)b*CC + cg*32)*HW;
  for (int pix = t; pix < HW; pix += 256) {
    float mx = -INFINITY, sm = 0.f;
    #pragma unroll
    for (int c = 0; c < 32; c++) {
      float v = xb[(size_t)c*HW + pix] * cs[c];
      mx = fmaxf(mx, v); sm += v;
    }
    cmaxp[(size_t)(cg*BB + b)*HW + pix] = mx;
    cmeanp[(size_t)(cg*BB + b)*HW + pix] = sm;
  }
}

// ---- K3b: reduce 16 partials -> final cmax / cmean -------------------------
__global__ void k_cred(const float* __restrict__ cmaxp, const float* __restrict__ cmeanp,
                       float* __restrict__ cmax, float* __restrict__ cmean) {
  int idx = blockIdx.x*256 + threadIdx.x;         // b*HW + pix
  if (idx >= BB*HW) return;
  int b = idx / HW, pix = idx % HW;
  float mx = -INFINITY, sm = 0.f;
  #pragma unroll
  for (int cg = 0; cg < 16; cg++) {
    mx = fmaxf(mx, cmaxp[(size_t)(cg*BB + b)*HW + pix]);
    sm += cmeanp[(size_t)(cg*BB + b)*HW + pix];
  }
  cmax[idx] = mx; cmean[idx] = sm * (1.f/CC);
}

// ---------------- K4: 7x7 spatial conv + BN(eval) + sigmoid -----------------
__global__ void k_spconv(const float* __restrict__ cmax, const float* __restrict__ cmean,
                         const float* __restrict__ w,
                         const float* g, const float* be, const float* mu, const float* var,
                         float* sp) {
  int b = blockIdx.x;
  int pix = blockIdx.y*256 + threadIdx.x;
  if (pix >= HW) return;
  int h = pix/28, wd = pix%28;
  float acc = 0.f;
  for (int kh = 0; kh < 7; kh++) {
    int ih = h + kh - 3; if (ih < 0 || ih >= 28) continue;
    for (int kw = 0; kw < 7; kw++) {
      int iw = wd + kw - 3; if (iw < 0 || iw >= 28) continue;
      int ip = ih*28+iw;
      acc += cmax[b*HW+ip]*w[kh*7+kw] + cmean[b*HW+ip]*w[49+kh*7+kw];
    }
  }
  float s = (acc - mu[0])*rsqrtf(var[0]+1e-5f)*g[0] + be[0];
  sp[b*HW+pix] = 1.f/(1.f+__expf(-s));
}

// ---- K5: fused gates -> fragment-ready bf16 xgT + pooled p1 ----------------
__global__ void k_sfuse(const float* __restrict__ x, const float* __restrict__ chs,
                        const float* __restrict__ sp, unsigned short* __restrict__ xgT,
                        float* __restrict__ p1) {
  __shared__ float cs[CC];
  int nt = blockIdx.x, b = blockIdx.y;
  int t = threadIdx.x, ln = t & 63;
  for (int i = t; i < CC; i += 256) cs[i] = chs[b*CC+i];
  __syncthreads();
  int n = nt*16 + (ln & 15);
  float spv = sp[b*HW + n];
  const float* xb = x + (size_t)b*CC*HW;
  #pragma unroll
  for (int i = 0; i < 4; i++) {
    int s = (t >> 6) + 4*i;
    int c = s*32 + (ln >> 4)*8;
    float v[8]; bf16x8 p;
    #pragma unroll
    for (int j = 0; j < 8; j++) {
      v[j] = xb[(size_t)(c+j)*HW + n] * cs[c+j] * spv;
      p[j] = (short)f2bf(v[j]);
    }
    *(bf16x8*)(xgT + ((((size_t)b*NTILE + nt)*16 + s)*64 + ln)*8) = p;
    #pragma unroll
    for (int j = 0; j < 8; j++) {
      float sv = v[j];
      sv += __shfl_xor(sv, 1, 64); sv += __shfl_xor(sv, 2, 64);
      sv += __shfl_xor(sv, 4, 64); sv += __shfl_xor(sv, 8, 64);
      if ((ln & 15) == 0) atomicAdd(&p1[b*CC + c + j], sv * (1.f/HW));
    }
  }
}

// ---- K5c: reformat wq/wk/wv into fragment-ready bf16 ----------------------
__global__ void k_wfrag(const float* __restrict__ wq, const float* __restrict__ wk,
                        const float* __restrict__ wv, unsigned short* __restrict__ Wf) {
  int idx = blockIdx.x*256 + threadIdx.x;         // 98304 chunks
  int ln = idx & 63;
  int s  = (idx >> 6) & 15;
  int ct = (idx >> 10) & 31;
  int mat = idx >> 15;
  const float* W = (mat==0)? wq : (mat==1)? wk : wv;
  const float* src = W + (size_t)(ct*16 + (ln & 15))*CC + s*32 + (ln >> 4)*8;
  float4 f0 = *(const float4*)src;
  float4 f1 = *(const float4*)(src + 4);
  bf16x8 p;
  p[0]=(short)f2bf(f0.x); p[1]=(short)f2bf(f0.y); p[2]=(short)f2bf(f0.z); p[3]=(short)f2bf(f0.w);
  p[4]=(short)f2bf(f1.x); p[5]=(short)f2bf(f1.y); p[6]=(short)f2bf(f1.z); p[7]=(short)f2bf(f1.w);
  *(bf16x8*)(Wf + (size_t)idx*8) = p;
}

// ---------------- K6: QKV projection — pure-MFMA, no LDS in K-loop ----------
__global__ __launch_bounds__(256) void k_qkv_mfma(
    const unsigned short* __restrict__ xgT, const unsigned short* __restrict__ Wf,
    const float* __restrict__ bq, const float* __restrict__ bk, const float* __restrict__ bv,
    unsigned short* __restrict__ Qbf, unsigned short* __restrict__ Kbf,
    unsigned short* __restrict__ Vbf) {
  __shared__ float Cb[64*132];                    // padded bounce tile (33.8 KB)
  int mt = blockIdx.x;                            // 0..12: n-tiles 4mt..4mt+3
  int yb = blockIdx.y;                            // 0..11: mat=yb>>2, c0=(yb&3)*128
  int b  = blockIdx.z;
  int mat = yb >> 2;
  int c0 = (yb & 3) * 128;
  int t = threadIdx.x, w = t >> 6, ln = t & 63;
  const unsigned short* Ab = xgT + (size_t)b*NTILE*8192;
  const unsigned short* Bb = Wf + (size_t)mat*32*8192;
  int ctg0 = (c0 >> 4) + w*2;
  f32x4 acc[4][2];
  #pragma unroll
  for (int m = 0; m < 4; m++)
    #pragma unroll
    for (int c2 = 0; c2 < 2; c2++) acc[m][c2] = (f32x4){0.f,0.f,0.f,0.f};
  int ntc[4];
  #pragma unroll
  for (int m = 0; m < 4; m++) { int nt = 4*mt + m; ntc[m] = (nt > 48) ? 48 : nt; }
  for (int s = 0; s < 16; s++) {
    bf16x8 bf0 = *(const bf16x8*)(Bb + (size_t)(ctg0*16 + s)*512 + ln*8);
    bf16x8 bf1 = *(const bf16x8*)(Bb + (size_t)((ctg0+1)*16 + s)*512 + ln*8);
    bf16x8 af[4];
    #pragma unroll
    for (int m = 0; m < 4; m++)
      af[m] = *(const bf16x8*)(Ab + (size_t)(ntc[m]*16 + s)*512 + ln*8);
    #pragma unroll
    for (int m = 0; m < 4; m++) {
      acc[m][0] = __builtin_amdgcn_mfma_f32_16x16x32_bf16(af[m], bf0, acc[m][0], 0,0,0);
      acc[m][1] = __builtin_amdgcn_mfma_f32_16x16x32_bf16(af[m], bf1, acc[m][1], 0,0,0);
    }
  }
  #pragma unroll
  for (int m = 0; m < 4; m++)
    #pragma unroll
    for (int c2 = 0; c2 < 2; c2++)
      #pragma unroll
      for (int r = 0; r < 4; r++)
        Cb[(m*16 + (ln>>4)*4 + r)*132 + w*32 + c2*16 + (ln&15)] = acc[m][c2][r];
  __syncthreads();
  const float* bias = (mat==0)? bq : (mat==1)? bk : bv;
  #pragma unroll
  for (int i = 0; i < 4; i++) {
    int p = w*4 + i;                              // 16 (ntl, sl) pairs
    int ntl = p >> 2, sl = p & 3;
    int nt = 4*mt + ntl;
    if (nt > 48) continue;
    int row = ntl*16 + (ln & 15);
    int col = sl*32 + (ln >> 4)*8;
    float v[8];
    #pragma unroll
    for (int j = 0; j < 8; j++) v[j] = Cb[row*132 + col + j] + bias[c0 + col + j];
    int token = nt*16 + (ln & 15);
    int h = (c0 >> 6) + (sl >> 1);
    int bh = b*NHD + h;
    bf16x8 pk;
    #pragma unroll
    for (int j = 0; j < 8; j++) pk[j] = (short)f2bf(v[j]);
    if (mat < 2) {
      unsigned short* Out = (mat == 0) ? Qbf : Kbf;
      *(bf16x8*)(Out + ((size_t)bh*NTILE + nt)*1024 + (size_t)(sl & 1)*512 + ln*8) = pk;
    } else {
      int d = (sl & 1)*32 + (ln >> 4)*8;
      *(bf16x8*)(Vbf + ((size_t)bh*NT + token)*HD + d) = pk;
    }
  }
}

// ---------------- K7: single-pass MFMA attention -> w_m (fp16 stripe) -------
// Block = (16-query n-tile nt, bh). e=exp(s/8) stored fp16 m-major, row
// stride 20 halfs (8B-aligned b64 writes, non-pow2 bank spread). 31.4 KB LDS
// -> 5 blocks/CU for latency hiding; score loop runs 2 independent K-tile
// MFMA chains per iteration for ILP.
__global__ __launch_bounds__(256, 5) void k_attn6(const unsigned short* __restrict__ Qbf,
    const unsigned short* __restrict__ Kbf, float* __restrict__ wsum) {
  __shared__ __align__(16) _Float16 Se[NT*SROWH]; // 31,360 B
  __shared__ float l_tmp[64];
  __shared__ float rl[16];
  int bh = blockIdx.x & 127, nt = blockIdx.x >> 7;
  int t = threadIdx.x, w = t >> 6, ln = t & 63;
  const unsigned short* Qb = Qbf + ((size_t)bh*NTILE + nt)*1024;
  const unsigned short* Kb = Kbf + (size_t)bh*NTILE*1024;
  bf16x8 q0 = *(const bf16x8*)(Qb + ln*8);
  bf16x8 q1 = *(const bf16x8*)(Qb + 512 + ln*8);
  float lp[4] = {0.f,0.f,0.f,0.f};
  // wave w owns contiguous K-tiles [w*12, w*12+12) (+tile 48 for w==3)
  int mt0 = w*12, cnt = (w == 3) ? 13 : 12;
  for (int i = 0; i < cnt; i += 2) {
    int mtA = mt0 + i;
    bool hasB = (i + 1) < cnt;
    int mtB = hasB ? (mtA + 1) : mtA;
    bf16x8 kA0 = *(const bf16x8*)(Kb + (size_t)mtA*1024 + ln*8);
    bf16x8 kA1 = *(const bf16x8*)(Kb + (size_t)mtA*1024 + 512 + ln*8);
    bf16x8 kB0 = *(const bf16x8*)(Kb + (size_t)mtB*1024 + ln*8);
    bf16x8 kB1 = *(const bf16x8*)(Kb + (size_t)mtB*1024 + 512 + ln*8);
    f32x4 a = {0.f,0.f,0.f,0.f};
    a = __builtin_amdgcn_mfma_f32_16x16x32_bf16(q0, kA0, a, 0,0,0);
    a = __builtin_amdgcn_mfma_f32_16x16x32_bf16(q1, kA1, a, 0,0,0);
    f32x4 c = {0.f,0.f,0.f,0.f};
    c = __builtin_amdgcn_mfma_f32_16x16x32_bf16(q0, kB0, c, 0,0,0);
    c = __builtin_amdgcn_mfma_f32_16x16x32_bf16(q1, kB1, c, 0,0,0);
    int mA = mtA*16 + (ln & 15);
    h16x4 ea;
    #pragma unroll
    for (int r = 0; r < 4; r++) {
      float e = __expf(a[r]*0.125f);              // n = (ln>>4)*4 + r
      lp[r] += e;
      ea[r] = (_Float16)e;
    }
    *(h16x4*)&Se[mA*SROWH + (ln>>4)*4] = ea;      // ds_write_b64
    if (hasB) {
      int mB = mtB*16 + (ln & 15);
      h16x4 eb;
      #pragma unroll
      for (int r = 0; r < 4; r++) {
        float e = __expf(c[r]*0.125f);
        lp[r] += e;
        eb[r] = (_Float16)e;
      }
      *(h16x4*)&Se[mB*SROWH + (ln>>4)*4] = eb;
    }
  }
  #pragma unroll
  for (int r = 0; r < 4; r++) {
    float v = lp[r];
    v += __shfl_xor(v,1,64); v += __shfl_xor(v,2,64);
    v += __shfl_xor(v,4,64); v += __shfl_xor(v,8,64);
    if ((ln & 15) == 0) l_tmp[w*16 + (ln>>4)*4 + r] = v;
  }
  __syncthreads();
  if (t < 16) rl[t] = 1.f / (l_tmp[t] + l_tmp[16+t] + l_tmp[32+t] + l_tmp[48+t]);
  __syncthreads();
  f32x4 rlv[4];
  #pragma unroll
  for (int j = 0; j < 4; j++) rlv[j] = *(const f32x4*)&rl[j*4];
  for (int m = t; m < NT; m += 256) {
    const _Float16* row = &Se[m*SROWH];
    float s = 0.f;
    #pragma unroll
    for (int j = 0; j < 4; j++) {
      h16x4 e = *(const h16x4*)&row[j*4];         // ds_read_b64
      s += (float)e[0]*rlv[j][0] + (float)e[1]*rlv[j][1]
         + (float)e[2]*rlv[j][2] + (float)e[3]*rlv[j][3];
    }
    atomicAdd(&wsum[bh*NT + m], s);
  }
}

// ---- K7c: abar[bh,d] = (1/N) sum_m w_m V[m,d] (V bf16) ---------------------
__global__ void k_attn_av(const float* __restrict__ w, const unsigned short* __restrict__ Vm,
                          float* __restrict__ abar) {
  __shared__ float red[256];
  int bh = blockIdx.x, t = threadIdx.x;
  int d = t & 63, chunk = t >> 6;                 // 4 chunks of 196 keys
  float acc = 0.f;
  const unsigned short* vb = Vm + (size_t)bh*NT*HD;
  const float* wb = w + bh*NT;
  for (int m = chunk*196; m < (chunk+1)*196; m++)
    acc += wb[m] * bf2f(vb[(size_t)m*HD + d]);
  red[t] = acc;
  __syncthreads();
  if (t < 64)
    abar[bh*HD + t] = (red[t] + red[64+t] + red[128+t] + red[192+t]) * (1.f/NT);
}

// --------- K8: pooled head, parallelized ------------------------------------
__global__ void k_headA(const float* __restrict__ p1, const float* __restrict__ abar,
                        const float* __restrict__ wo, const float* __restrict__ bo,
                        float* __restrict__ pv) {
  int b = blockIdx.x, cg = blockIdx.y;
  int t = threadIdx.x, w = t >> 6, ln = t & 63;
  float a[8];
  #pragma unroll
  for (int k = 0; k < 8; k++) a[k] = abar[b*CC + ln + 64*k];
  int c0 = cg*64 + w*16;
  for (int i = 0; i < 16; i++) {
    int c = c0 + i;
    const float* wr = wo + (size_t)c*CC;
    float s = 0.f;
    #pragma unroll
    for (int k = 0; k < 8; k++) s += a[k] * wr[ln + 64*k];
    for (int o = 32; o; o >>= 1) s += __shfl_down(s, o, 64);
    if (ln == 0) pv[b*CC + c] = s + bo[c] + p1[b*CC + c];
  }
}

__global__ void k_headB(const float* __restrict__ pv, const float* __restrict__ ln_g,
                        const float* __restrict__ ln_b, float* __restrict__ lnv) {
  int b = blockIdx.x, ln = threadIdx.x;
  float v[8], s = 0.f, s2 = 0.f;
  #pragma unroll
  for (int k = 0; k < 8; k++) { v[k] = pv[b*CC + ln + 64*k]; s += v[k]; s2 += v[k]*v[k]; }
  for (int o = 32; o; o >>= 1) { s += __shfl_down(s, o, 64); s2 += __shfl_down(s2, o, 64); }
  s = __shfl(s, 0, 64); s2 = __shfl(s2, 0, 64);
  float mean = s * (1.f/CC);
  float rs = rsqrtf(s2*(1.f/CC) - mean*mean + 1e-5f);
  #pragma unroll
  for (int k = 0; k < 8; k++) {
    int c = ln + 64*k;
    lnv[b*CC + c] = (v[k]-mean)*rs*ln_g[c] + ln_b[c];
  }
}

__global__ void k_headC(const float* __restrict__ lnv, const float* __restrict__ fc1_w,
                        const float* __restrict__ fc1_b, float* __restrict__ h1) {
  int b = blockIdx.x, cg = blockIdx.y;
  int t = threadIdx.x, w = t >> 6, ln = t & 63;
  float a[8];
  #pragma unroll
  for (int k = 0; k < 8; k++) a[k] = lnv[b*CC + ln + 64*k];
  int c0 = cg*64 + w*16;
  for (int i = 0; i < 16; i++) {
    int c = c0 + i;
    const float* wr = fc1_w + (size_t)c*CC;
    float s = 0.f;
    #pragma unroll
    for (int k = 0; k < 8; k++) s += a[k] * wr[ln + 64*k];
    for (int o = 32; o; o >>= 1) s += __shfl_down(s, o, 64);
    if (ln == 0) h1[b*CC + c] = fmaxf(s + fc1_b[c], 0.f);
  }
}

__global__ void k_headD(const float* __restrict__ h1, const float* __restrict__ fc2_w,
                        const float* __restrict__ fc2_b, float* __restrict__ out) {
  int b = blockIdx.x, ln = threadIdx.x;
  float s = 0.f;
  #pragma unroll
  for (int k = 0; k < 8; k++) s += h1[b*CC + ln + 64*k] * fc2_w[ln + 64*k];
  for (int o = 32; o; o >>= 1) s += __shfl_down(s, o, 64);
  if (ln == 0) out[b] = s + fc2_b[0];
}

extern "C" void kernel_launch(void* const* d_in, const int* in_sizes, int n_in,
                              void* d_out, int out_size, void* d_ws, size_t ws_size,
                              hipStream_t stream) {
  const float* x       = (const float*)d_in[0];
  const float* mlp_w1  = (const float*)d_in[1];
  const float* mlp_b1  = (const float*)d_in[2];
  const float* mlp_w2  = (const float*)d_in[3];
  const float* mlp_b2  = (const float*)d_in[4];
  const float* sp_w    = (const float*)d_in[5];
  const float* sp_g    = (const float*)d_in[6];
  const float* sp_b    = (const float*)d_in[7];
  const float* sp_mu   = (const float*)d_in[8];
  const float* sp_var  = (const float*)d_in[9];
  const float* wq      = (const float*)d_in[10];
  const float* bq      = (const float*)d_in[11];
  const float* wk      = (const float*)d_in[12];
  const float* bk      = (const float*)d_in[13];
  const float* wv      = (const float*)d_in[14];
  const float* bv      = (const float*)d_in[15];
  const float* wo      = (const float*)d_in[16];
  const float* bo      = (const float*)d_in[17];
  const float* ln_g    = (const float*)d_in[18];
  const float* ln_b    = (const float*)d_in[19];
  const float* fc1_w   = (const float*)d_in[20];
  const float* fc1_b   = (const float*)d_in[21];
  const float* fc2_w   = (const float*)d_in[22];
  const float* fc2_b   = (const float*)d_in[23];

  float* ws = (float*)d_ws;
  float* avg_p = ws + OFS_AVGP;
  float* max_p = ws + OFS_MAXP;
  float* chs   = ws + OFS_CHS;
  float* cmax  = ws + OFS_CMAX;
  float* cmean = ws + OFS_CMEAN;
  float* sp    = ws + OFS_SP;
  float* p1    = ws + OFS_P1;
  float* abar  = ws + OFS_ABAR;
  unsigned short* xgT = (unsigned short*)(ws + OFS_XGT);
  unsigned short* Qbf = (unsigned short*)(ws + OFS_QBF);
  unsigned short* Kbf = (unsigned short*)(ws + OFS_KBF);
  unsigned short* Vbf = (unsigned short*)(ws + OFS_V2);
  unsigned short* Wf  = (unsigned short*)(ws + OFS_WF);
  float* wsum  = ws + OFS_W;
  float* pv    = ws + OFS_PV;
  float* lnv   = ws + OFS_LNV;
  float* h1    = ws + OFS_H1;
  float* cmaxp = ws + OFS_CMAXP;
  float* cmeanp= ws + OFS_CMEANP;

  hipMemsetAsync(p1, 0, BB*CC*sizeof(float), stream);
  hipMemsetAsync(wsum, 0, BB*NHD*NT*sizeof(float), stream);

  k_pool   <<<2048, 256, 0, stream>>>(x, avg_p, max_p);
  k_chmlp  <<<BB, 256, 0, stream>>>(avg_p, max_p, mlp_w1, mlp_b1, mlp_w2, mlp_b2, chs);
  k_chgatep<<<dim3(BB,16), 256, 0, stream>>>(x, chs, cmaxp, cmeanp);
  k_cred   <<<49, 256, 0, stream>>>(cmaxp, cmeanp, cmax, cmean);
  k_spconv <<<dim3(BB,4), 256, 0, stream>>>(cmax, cmean, sp_w, sp_g, sp_b, sp_mu, sp_var, sp);
  k_wfrag  <<<384, 256, 0, stream>>>(wq, wk, wv, Wf);
  k_sfuse  <<<dim3(NTILE,BB), 256, 0, stream>>>(x, chs, sp, xgT, p1);
  k_qkv_mfma<<<dim3(13,12,BB), 256, 0, stream>>>(xgT, Wf, bq, bk, bv, Qbf, Kbf, Vbf);
  k_attn6  <<<NTILE*128, 256, 0, stream>>>(Qbf, Kbf, wsum);
  k_attn_av<<<128, 256, 0, stream>>>(wsum, Vbf, abar);
  k_headA  <<<dim3(BB,8), 256, 0, stream>>>(p1, abar, wo, bo, pv);
  k_headB  <<<BB, 64, 0, stream>>>(pv, ln_g, ln_b, lnv);
  k_headC  <<<dim3(BB,8), 256, 0, stream>>>(lnv, fc1_w, fc1_b, h1);
  k_headD  <<<BB, 64, 0, stream>>>(h1, fc2_w, fc2_b, (float*)d_out);
}

// Round 9
// 292.640 us; speedup vs baseline: 1.2189x; 1.0312x over previous
//
#include <hip/hip_runtime.h>
#include <math.h>

// Problem constants
#define BB 16
#define CC 512
#define HW 784
#define RR 32
#define NHD 8
#define HD 64
#define NT 784
#define NTILE 49                       // 784 = 49 * 16 n-tiles
#define SROWH 20                       // halfs per m-row (16 data + 4 pad)
#define CBS 131                        // Cb bounce-tile stride (2-way max both phases)

// workspace layout (float offsets)
#define OFS_AVGP   0
#define OFS_MAXP   8192
#define OFS_CHS    16384
#define OFS_CMAX   24576
#define OFS_CMEAN  37120
#define OFS_SP     49664
#define OFS_P1     62208
#define OFS_ABAR   70400
#define OFS_XG     78592
#define XG_SZ      (BB*CC*HW)          // 6,422,528 floats (region reused below)
#define OFS_XGT    (OFS_XG + XG_SZ)            // bf16 frag xg^T  (XG_SZ bf16)
#define OFS_QBF    (OFS_XGT + XG_SZ/2)         // bf16 frag Q     (XG_SZ bf16)
#define OFS_KBF    (OFS_QBF + XG_SZ/2)         // bf16 frag K     (XG_SZ bf16)
#define OFS_V2     (OFS_KBF + XG_SZ/2)         // bf16 V [bh][n][d]
#define OFS_WF     (OFS_V2 + XG_SZ)            // bf16 frag weights (786432 bf16)
// overlays inside the dead xg region:
#define OFS_W      OFS_XG                      // wsum   (100352 floats)
#define OFS_PV     (OFS_XG + 131072)           // pv     (8192)
#define OFS_LNV    (OFS_PV + 8192)             // lnv    (8192)
#define OFS_H1     (OFS_LNV + 8192)            // h1     (8192)
#define OFS_CMAXP  (OFS_XG + 262144)           // partial cmax [16][16][784]
#define OFS_CMEANP (OFS_CMAXP + 200704)        // partial csum [16][16][784]

typedef __attribute__((ext_vector_type(8))) short bf16x8;
typedef __attribute__((ext_vector_type(4))) float f32x4;
typedef __attribute__((ext_vector_type(4))) _Float16 h16x4;

__device__ __forceinline__ unsigned short f2bf(float x) {
  union { float f; unsigned u; } v; v.f = x;
  unsigned r = v.u + 0x7fffu + ((v.u >> 16) & 1u);
  return (unsigned short)(r >> 16);
}
__device__ __forceinline__ float bf2f(unsigned short x) {
  union { unsigned u; float f; } v; v.u = ((unsigned)x) << 16;
  return v.f;
}

// ---------------- K1: per-(b,c) avg + max pooling over HW -------------------
__global__ void k_pool(const float* __restrict__ x, float* avg_p, float* max_p) {
  int wid = threadIdx.x >> 6;
  int lane = threadIdx.x & 63;
  int row = blockIdx.x * 4 + wid;                 // b*C + c, 8192 rows
  const float* xr = x + (size_t)row * HW;
  float s = 0.f, m = -INFINITY;
  for (int i = lane; i < HW; i += 64) { float v = xr[i]; s += v; m = fmaxf(m, v); }
  for (int o = 32; o; o >>= 1) { s += __shfl_down(s, o, 64); m = fmaxf(m, __shfl_down(m, o, 64)); }
  if (lane == 0) { avg_p[row] = s * (1.f/HW); max_p[row] = m; }
}

// ---------------- K2: channel-gate MLP, one block per batch -----------------
__global__ void k_chmlp(const float* avg_p, const float* max_p,
                        const float* w1, const float* b1,
                        const float* w2, const float* b2, float* chs) {
  __shared__ float pa[CC], pm[CC], part[256], hr[64];
  int b = blockIdx.x, t = threadIdx.x;
  for (int i = t; i < CC; i += 256) { pa[i] = avg_p[b*CC+i]; pm[i] = max_p[b*CC+i]; }
  __syncthreads();
  // phase 1: 64 dots (r,pool) x 4 chunks of 128
  {
    int rp = t & 63, ch = t >> 6;
    int r = rp & 31;
    const float* src = (rp < 32) ? pa : pm;
    const float* wr = w1 + (size_t)r*CC + ch*128;
    float s = 0.f;
    #pragma unroll 8
    for (int c = 0; c < 128; c++) s += src[ch*128 + c] * wr[c];
    part[t] = s;
  }
  __syncthreads();
  if (t < 64)
    hr[t] = fmaxf(part[t] + part[64+t] + part[128+t] + part[192+t] + b1[t & 31], 0.f);
  __syncthreads();
  for (int c = t; c < CC; c += 256) {
    float a = 2.f*b2[c];                          // b2 added by both mlp() calls
    const float* wr = w2 + c*RR;
    #pragma unroll
    for (int r = 0; r < RR; r++) a += (hr[r]+hr[32+r])*wr[r];
    chs[b*CC+c] = 1.f/(1.f+__expf(-a));
  }
}

// ---- K3a: channel gate partials: per (b, 32-ch chunk) max/sum per pixel ----
__global__ void k_chgatep(const float* __restrict__ x, const float* __restrict__ chs,
                          float* __restrict__ cmaxp, float* __restrict__ cmeanp) {
  __shared__ float cs[32];
  int b = blockIdx.x, cg = blockIdx.y, t = threadIdx.x;
  if (t < 32) cs[t] = chs[b*CC + cg*32 + t];
  __syncthreads();
  const float* xb = x + ((size_t)b*CC + cg*32)*HW;
  for (int pix = t; pix < HW; pix += 256) {
    float mx = -INFINITY, sm = 0.f;
    #pragma unroll
    for (int c = 0; c < 32; c++) {
      float v = xb[(size_t)c*HW + pix] * cs[c];
      mx = fmaxf(mx, v); sm += v;
    }
    cmaxp[(size_t)(cg*BB + b)*HW + pix] = mx;
    cmeanp[(size_t)(cg*BB + b)*HW + pix] = sm;
  }
}

// ---- K3b: reduce 16 partials -> final cmax / cmean -------------------------
__global__ void k_cred(const float* __restrict__ cmaxp, const float* __restrict__ cmeanp,
                       float* __restrict__ cmax, float* __restrict__ cmean) {
  int idx = blockIdx.x*256 + threadIdx.x;         // b*HW + pix
  if (idx >= BB*HW) return;
  int b = idx / HW, pix = idx % HW;
  float mx = -INFINITY, sm = 0.f;
  #pragma unroll
  for (int cg = 0; cg < 16; cg++) {
    mx = fmaxf(mx, cmaxp[(size_t)(cg*BB + b)*HW + pix]);
    sm += cmeanp[(size_t)(cg*BB + b)*HW + pix];
  }
  cmax[idx] = mx; cmean[idx] = sm * (1.f/CC);
}

// ---------------- K4: 7x7 spatial conv + BN(eval) + sigmoid -----------------
__global__ void k_spconv(const float* __restrict__ cmax, const float* __restrict__ cmean,
                         const float* __restrict__ w,
                         const float* g, const float* be, const float* mu, const float* var,
                         float* sp) {
  int b = blockIdx.x;
  int pix = blockIdx.y*256 + threadIdx.x;
  if (pix >= HW) return;
  int h = pix/28, wd = pix%28;
  float acc = 0.f;
  for (int kh = 0; kh < 7; kh++) {
    int ih = h + kh - 3; if (ih < 0 || ih >= 28) continue;
    for (int kw = 0; kw < 7; kw++) {
      int iw = wd + kw - 3; if (iw < 0 || iw >= 28) continue;
      int ip = ih*28+iw;
      acc += cmax[b*HW+ip]*w[kh*7+kw] + cmean[b*HW+ip]*w[49+kh*7+kw];
    }
  }
  float s = (acc - mu[0])*rsqrtf(var[0]+1e-5f)*g[0] + be[0];
  sp[b*HW+pix] = 1.f/(1.f+__expf(-s));
}

// ---- K5: fused gates -> fragment-ready bf16 xgT + pooled p1 ----------------
__global__ void k_sfuse(const float* __restrict__ x, const float* __restrict__ chs,
                        const float* __restrict__ sp, unsigned short* __restrict__ xgT,
                        float* __restrict__ p1) {
  __shared__ float cs[CC];
  int nt = blockIdx.x, b = blockIdx.y;
  int t = threadIdx.x, ln = t & 63;
  for (int i = t; i < CC; i += 256) cs[i] = chs[b*CC+i];
  __syncthreads();
  int n = nt*16 + (ln & 15);
  float spv = sp[b*HW + n];
  const float* xb = x + (size_t)b*CC*HW;
  #pragma unroll
  for (int i = 0; i < 4; i++) {
    int s = (t >> 6) + 4*i;
    int c = s*32 + (ln >> 4)*8;
    float v[8]; bf16x8 p;
    #pragma unroll
    for (int j = 0; j < 8; j++) {
      v[j] = xb[(size_t)(c+j)*HW + n] * cs[c+j] * spv;
      p[j] = (short)f2bf(v[j]);
    }
    *(bf16x8*)(xgT + ((((size_t)b*NTILE + nt)*16 + s)*64 + ln)*8) = p;
    #pragma unroll
    for (int j = 0; j < 8; j++) {
      float sv = v[j];
      sv += __shfl_xor(sv, 1, 64); sv += __shfl_xor(sv, 2, 64);
      sv += __shfl_xor(sv, 4, 64); sv += __shfl_xor(sv, 8, 64);
      if ((ln & 15) == 0) atomicAdd(&p1[b*CC + c + j], sv * (1.f/HW));
    }
  }
}

// ---- K5c: reformat wq/wk/wv into fragment-ready bf16 ----------------------
__global__ void k_wfrag(const float* __restrict__ wq, const float* __restrict__ wk,
                        const float* __restrict__ wv, unsigned short* __restrict__ Wf) {
  int idx = blockIdx.x*256 + threadIdx.x;         // 98304 chunks
  int ln = idx & 63;
  int s  = (idx >> 6) & 15;
  int ct = (idx >> 10) & 31;
  int mat = idx >> 15;
  const float* W = (mat==0)? wq : (mat==1)? wk : wv;
  const float* src = W + (size_t)(ct*16 + (ln & 15))*CC + s*32 + (ln >> 4)*8;
  float4 f0 = *(const float4*)src;
  float4 f1 = *(const float4*)(src + 4);
  bf16x8 p;
  p[0]=(short)f2bf(f0.x); p[1]=(short)f2bf(f0.y); p[2]=(short)f2bf(f0.z); p[3]=(short)f2bf(f0.w);
  p[4]=(short)f2bf(f1.x); p[5]=(short)f2bf(f1.y); p[6]=(short)f2bf(f1.z); p[7]=(short)f2bf(f1.w);
  *(bf16x8*)(Wf + (size_t)idx*8) = p;
}

// ---------------- K6: QKV projection — pure-MFMA, no LDS in K-loop ----------
// 1-D grid, XCD-swizzled: blk = yb*208 + (mt*16 + b). The 12 blocks sharing
// an A-panel (mt,b) are spaced 208 apart (208 % 8 == 0) -> same XCD L2.
__global__ __launch_bounds__(256) void k_qkv_mfma(
    const unsigned short* __restrict__ xgT, const unsigned short* __restrict__ Wf,
    const float* __restrict__ bq, const float* __restrict__ bk, const float* __restrict__ bv,
    unsigned short* __restrict__ Qbf, unsigned short* __restrict__ Kbf,
    unsigned short* __restrict__ Vbf) {
  __shared__ float Cb[64*CBS];                    // bounce tile, stride 131
  int blk = blockIdx.x;
  int yb = blk / 208;                             // 0..11: mat=yb>>2, c0=(yb&3)*128
  int r0 = blk % 208;
  int mt = r0 >> 4;                               // 0..12: n-tiles 4mt..4mt+3
  int b  = r0 & 15;
  int mat = yb >> 2;
  int c0 = (yb & 3) * 128;
  int t = threadIdx.x, w = t >> 6, ln = t & 63;
  const unsigned short* Ab = xgT + (size_t)b*NTILE*8192;
  const unsigned short* Bb = Wf + (size_t)mat*32*8192;
  int ctg0 = (c0 >> 4) + w*2;
  f32x4 acc[4][2];
  #pragma unroll
  for (int m = 0; m < 4; m++)
    #pragma unroll
    for (int c2 = 0; c2 < 2; c2++) acc[m][c2] = (f32x4){0.f,0.f,0.f,0.f};
  int ntc[4];
  #pragma unroll
  for (int m = 0; m < 4; m++) { int nt = 4*mt + m; ntc[m] = (nt > 48) ? 48 : nt; }
  #pragma unroll 2
  for (int s = 0; s < 16; s++) {
    bf16x8 bf0 = *(const bf16x8*)(Bb + (size_t)(ctg0*16 + s)*512 + ln*8);
    bf16x8 bf1 = *(const bf16x8*)(Bb + (size_t)((ctg0+1)*16 + s)*512 + ln*8);
    bf16x8 af[4];
    #pragma unroll
    for (int m = 0; m < 4; m++)
      af[m] = *(const bf16x8*)(Ab + (size_t)(ntc[m]*16 + s)*512 + ln*8);
    #pragma unroll
    for (int m = 0; m < 4; m++) {
      acc[m][0] = __builtin_amdgcn_mfma_f32_16x16x32_bf16(af[m], bf0, acc[m][0], 0,0,0);
      acc[m][1] = __builtin_amdgcn_mfma_f32_16x16x32_bf16(af[m], bf1, acc[m][1], 0,0,0);
    }
  }
  #pragma unroll
  for (int m = 0; m < 4; m++)
    #pragma unroll
    for (int c2 = 0; c2 < 2; c2++)
      #pragma unroll
      for (int r = 0; r < 4; r++)
        Cb[(m*16 + (ln>>4)*4 + r)*CBS + w*32 + c2*16 + (ln&15)] = acc[m][c2][r];
  __syncthreads();
  const float* bias = (mat==0)? bq : (mat==1)? bk : bv;
  #pragma unroll
  for (int i = 0; i < 4; i++) {
    int p = w*4 + i;                              // 16 (ntl, sl) pairs
    int ntl = p >> 2, sl = p & 3;
    int nt = 4*mt + ntl;
    if (nt > 48) continue;
    int row = ntl*16 + (ln & 15);
    int col = sl*32 + (ln >> 4)*8;
    float v[8];
    #pragma unroll
    for (int j = 0; j < 8; j++) v[j] = Cb[row*CBS + col + j] + bias[c0 + col + j];
    int token = nt*16 + (ln & 15);
    int h = (c0 >> 6) + (sl >> 1);
    int bh = b*NHD + h;
    bf16x8 pk;
    #pragma unroll
    for (int j = 0; j < 8; j++) pk[j] = (short)f2bf(v[j]);
    if (mat < 2) {
      unsigned short* Out = (mat == 0) ? Qbf : Kbf;
      *(bf16x8*)(Out + ((size_t)bh*NTILE + nt)*1024 + (size_t)(sl & 1)*512 + ln*8) = pk;
    } else {
      int d = (sl & 1)*32 + (ln >> 4)*8;
      *(bf16x8*)(Vbf + ((size_t)bh*NT + token)*HD + d) = pk;
    }
  }
}

// ---------------- K7: single-pass MFMA attention -> w_m (fp16 stripe) -------
__global__ __launch_bounds__(256, 5) void k_attn6(const unsigned short* __restrict__ Qbf,
    const unsigned short* __restrict__ Kbf, float* __restrict__ wsum) {
  __shared__ __align__(16) _Float16 Se[NT*SROWH]; // 31,360 B
  __shared__ float l_tmp[64];
  __shared__ float rl[16];
  int bh = blockIdx.x & 127, nt = blockIdx.x >> 7;
  int t = threadIdx.x, w = t >> 6, ln = t & 63;
  const unsigned short* Qb = Qbf + ((size_t)bh*NTILE + nt)*1024;
  const unsigned short* Kb = Kbf + (size_t)bh*NTILE*1024;
  bf16x8 q0 = *(const bf16x8*)(Qb + ln*8);
  bf16x8 q1 = *(const bf16x8*)(Qb + 512 + ln*8);
  float lp[4] = {0.f,0.f,0.f,0.f};
  // wave w owns contiguous K-tiles [w*12, w*12+12) (+tile 48 for w==3)
  int mt0 = w*12, cnt = (w == 3) ? 13 : 12;
  for (int i = 0; i < cnt; i += 2) {
    int mtA = mt0 + i;
    bool hasB = (i + 1) < cnt;
    int mtB = hasB ? (mtA + 1) : mtA;
    bf16x8 kA0 = *(const bf16x8*)(Kb + (size_t)mtA*1024 + ln*8);
    bf16x8 kA1 = *(const bf16x8*)(Kb + (size_t)mtA*1024 + 512 + ln*8);
    bf16x8 kB0 = *(const bf16x8*)(Kb + (size_t)mtB*1024 + ln*8);
    bf16x8 kB1 = *(const bf16x8*)(Kb + (size_t)mtB*1024 + 512 + ln*8);
    f32x4 a = {0.f,0.f,0.f,0.f};
    a = __builtin_amdgcn_mfma_f32_16x16x32_bf16(q0, kA0, a, 0,0,0);
    a = __builtin_amdgcn_mfma_f32_16x16x32_bf16(q1, kA1, a, 0,0,0);
    f32x4 c = {0.f,0.f,0.f,0.f};
    c = __builtin_amdgcn_mfma_f32_16x16x32_bf16(q0, kB0, c, 0,0,0);
    c = __builtin_amdgcn_mfma_f32_16x16x32_bf16(q1, kB1, c, 0,0,0);
    int mA = mtA*16 + (ln & 15);
    h16x4 ea;
    #pragma unroll
    for (int r = 0; r < 4; r++) {
      float e = __expf(a[r]*0.125f);              // n = (ln>>4)*4 + r
      lp[r] += e;
      ea[r] = (_Float16)e;
    }
    *(h16x4*)&Se[mA*SROWH + (ln>>4)*4] = ea;      // ds_write_b64
    if (hasB) {
      int mB = mtB*16 + (ln & 15);
      h16x4 eb;
      #pragma unroll
      for (int r = 0; r < 4; r++) {
        float e = __expf(c[r]*0.125f);
        lp[r] += e;
        eb[r] = (_Float16)e;
      }
      *(h16x4*)&Se[mB*SROWH + (ln>>4)*4] = eb;
    }
  }
  #pragma unroll
  for (int r = 0; r < 4; r++) {
    float v = lp[r];
    v += __shfl_xor(v,1,64); v += __shfl_xor(v,2,64);
    v += __shfl_xor(v,4,64); v += __shfl_xor(v,8,64);
    if ((ln & 15) == 0) l_tmp[w*16 + (ln>>4)*4 + r] = v;
  }
  __syncthreads();
  if (t < 16) rl[t] = 1.f / (l_tmp[t] + l_tmp[16+t] + l_tmp[32+t] + l_tmp[48+t]);
  __syncthreads();
  f32x4 rlv[4];
  #pragma unroll
  for (int j = 0; j < 4; j++) rlv[j] = *(const f32x4*)&rl[j*4];
  for (int m = t; m < NT; m += 256) {
    const _Float16* row = &Se[m*SROWH];
    float s = 0.f;
    #pragma unroll
    for (int j = 0; j < 4; j++) {
      h16x4 e = *(const h16x4*)&row[j*4];         // ds_read_b64
      s += (float)e[0]*rlv[j][0] + (float)e[1]*rlv[j][1]
         + (float)e[2]*rlv[j][2] + (float)e[3]*rlv[j][3];
    }
    atomicAdd(&wsum[bh*NT + m], s);
  }
}

// ---- K7c: abar[bh,d] = (1/N) sum_m w_m V[m,d] (V bf16) ---------------------
__global__ void k_attn_av(const float* __restrict__ w, const unsigned short* __restrict__ Vm,
                          float* __restrict__ abar) {
  __shared__ float red[256];
  int bh = blockIdx.x, t = threadIdx.x;
  int d = t & 63, chunk = t >> 6;                 // 4 chunks of 196 keys
  float acc = 0.f;
  const unsigned short* vb = Vm + (size_t)bh*NT*HD;
  const float* wb = w + bh*NT;
  for (int m = chunk*196; m < (chunk+1)*196; m++)
    acc += wb[m] * bf2f(vb[(size_t)m*HD + d]);
  red[t] = acc;
  __syncthreads();
  if (t < 64)
    abar[bh*HD + t] = (red[t] + red[64+t] + red[128+t] + red[192+t]) * (1.f/NT);
}

// --------- K8: pooled head, parallelized ------------------------------------
__global__ void k_headA(const float* __restrict__ p1, const float* __restrict__ abar,
                        const float* __restrict__ wo, const float* __restrict__ bo,
                        float* __restrict__ pv) {
  int b = blockIdx.x, cg = blockIdx.y;
  int t = threadIdx.x, w = t >> 6, ln = t & 63;
  float a[8];
  #pragma unroll
  for (int k = 0; k < 8; k++) a[k] = abar[b*CC + ln + 64*k];
  int c0 = cg*64 + w*16;
  for (int i = 0; i < 16; i++) {
    int c = c0 + i;
    const float* wr = wo + (size_t)c*CC;
    float s = 0.f;
    #pragma unroll
    for (int k = 0; k < 8; k++) s += a[k] * wr[ln + 64*k];
    for (int o = 32; o; o >>= 1) s += __shfl_down(s, o, 64);
    if (ln == 0) pv[b*CC + c] = s + bo[c] + p1[b*CC + c];
  }
}

__global__ void k_headB(const float* __restrict__ pv, const float* __restrict__ ln_g,
                        const float* __restrict__ ln_b, float* __restrict__ lnv) {
  int b = blockIdx.x, ln = threadIdx.x;
  float v[8], s = 0.f, s2 = 0.f;
  #pragma unroll
  for (int k = 0; k < 8; k++) { v[k] = pv[b*CC + ln + 64*k]; s += v[k]; s2 += v[k]*v[k]; }
  for (int o = 32; o; o >>= 1) { s += __shfl_down(s, o, 64); s2 += __shfl_down(s2, o, 64); }
  s = __shfl(s, 0, 64); s2 = __shfl(s2, 0, 64);
  float mean = s * (1.f/CC);
  float rs = rsqrtf(s2*(1.f/CC) - mean*mean + 1e-5f);
  #pragma unroll
  for (int k = 0; k < 8; k++) {
    int c = ln + 64*k;
    lnv[b*CC + c] = (v[k]-mean)*rs*ln_g[c] + ln_b[c];
  }
}

__global__ void k_headC(const float* __restrict__ lnv, const float* __restrict__ fc1_w,
                        const float* __restrict__ fc1_b, float* __restrict__ h1) {
  int b = blockIdx.x, cg = blockIdx.y;
  int t = threadIdx.x, w = t >> 6, ln = t & 63;
  float a[8];
  #pragma unroll
  for (int k = 0; k < 8; k++) a[k] = lnv[b*CC + ln + 64*k];
  int c0 = cg*64 + w*16;
  for (int i = 0; i < 16; i++) {
    int c = c0 + i;
    const float* wr = fc1_w + (size_t)c*CC;
    float s = 0.f;
    #pragma unroll
    for (int k = 0; k < 8; k++) s += a[k] * wr[ln + 64*k];
    for (int o = 32; o; o >>= 1) s += __shfl_down(s, o, 64);
    if (ln == 0) h1[b*CC + c] = fmaxf(s + fc1_b[c], 0.f);
  }
}

__global__ void k_headD(const float* __restrict__ h1, const float* __restrict__ fc2_w,
                        const float* __restrict__ fc2_b, float* __restrict__ out) {
  int b = blockIdx.x, ln = threadIdx.x;
  float s = 0.f;
  #pragma unroll
  for (int k = 0; k < 8; k++) s += h1[b*CC + ln + 64*k] * fc2_w[ln + 64*k];
  for (int o = 32; o; o >>= 1) s += __shfl_down(s, o, 64);
  if (ln == 0) out[b] = s + fc2_b[0];
}

extern "C" void kernel_launch(void* const* d_in, const int* in_sizes, int n_in,
                              void* d_out, int out_size, void* d_ws, size_t ws_size,
                              hipStream_t stream) {
  const float* x       = (const float*)d_in[0];
  const float* mlp_w1  = (const float*)d_in[1];
  const float* mlp_b1  = (const float*)d_in[2];
  const float* mlp_w2  = (const float*)d_in[3];
  const float* mlp_b2  = (const float*)d_in[4];
  const float* sp_w    = (const float*)d_in[5];
  const float* sp_g    = (const float*)d_in[6];
  const float* sp_b    = (const float*)d_in[7];
  const float* sp_mu   = (const float*)d_in[8];
  const float* sp_var  = (const float*)d_in[9];
  const float* wq      = (const float*)d_in[10];
  const float* bq      = (const float*)d_in[11];
  const float* wk      = (const float*)d_in[12];
  const float* bk      = (const float*)d_in[13];
  const float* wv      = (const float*)d_in[14];
  const float* bv      = (const float*)d_in[15];
  const float* wo      = (const float*)d_in[16];
  const float* bo      = (const float*)d_in[17];
  const float* ln_g    = (const float*)d_in[18];
  const float* ln_b    = (const float*)d_in[19];
  const float* fc1_w   = (const float*)d_in[20];
  const float* fc1_b   = (const float*)d_in[21];
  const float* fc2_w   = (const float*)d_in[22];
  const float* fc2_b   = (const float*)d_in[23];

  float* ws = (float*)d_ws;
  float* avg_p = ws + OFS_AVGP;
  float* max_p = ws + OFS_MAXP;
  float* chs   = ws + OFS_CHS;
  float* cmax  = ws + OFS_CMAX;
  float* cmean = ws + OFS_CMEAN;
  float* sp    = ws + OFS_SP;
  float* p1    = ws + OFS_P1;
  float* abar  = ws + OFS_ABAR;
  unsigned short* xgT = (unsigned short*)(ws + OFS_XGT);
  unsigned short* Qbf = (unsigned short*)(ws + OFS_QBF);
  unsigned short* Kbf = (unsigned short*)(ws + OFS_KBF);
  unsigned short* Vbf = (unsigned short*)(ws + OFS_V2);
  unsigned short* Wf  = (unsigned short*)(ws + OFS_WF);
  float* wsum  = ws + OFS_W;
  float* pv    = ws + OFS_PV;
  float* lnv   = ws + OFS_LNV;
  float* h1    = ws + OFS_H1;
  float* cmaxp = ws + OFS_CMAXP;
  float* cmeanp= ws + OFS_CMEANP;

  hipMemsetAsync(p1, 0, BB*CC*sizeof(float), stream);
  hipMemsetAsync(wsum, 0, BB*NHD*NT*sizeof(float), stream);

  k_pool   <<<2048, 256, 0, stream>>>(x, avg_p, max_p);
  k_chmlp  <<<BB, 256, 0, stream>>>(avg_p, max_p, mlp_w1, mlp_b1, mlp_w2, mlp_b2, chs);
  k_chgatep<<<dim3(BB,16), 256, 0, stream>>>(x, chs, cmaxp, cmeanp);
  k_cred   <<<49, 256, 0, stream>>>(cmaxp, cmeanp, cmax, cmean);
  k_spconv <<<dim3(BB,4), 256, 0, stream>>>(cmax, cmean, sp_w, sp_g, sp_b, sp_mu, sp_var, sp);
  k_wfrag  <<<384, 256, 0, stream>>>(wq, wk, wv, Wf);
  k_sfuse  <<<dim3(NTILE,BB), 256, 0, stream>>>(x, chs, sp, xgT, p1);
  k_qkv_mfma<<<2496, 256, 0, stream>>>(xgT, Wf, bq, bk, bv, Qbf, Kbf, Vbf);
  k_attn6  <<<NTILE*128, 256, 0, stream>>>(Qbf, Kbf, wsum);
  k_attn_av<<<128, 256, 0, stream>>>(wsum, Vbf, abar);
  k_headA  <<<dim3(BB,8), 256, 0, stream>>>(p1, abar, wo, bo, pv);
  k_headB  <<<BB, 64, 0, stream>>>(pv, ln_g, ln_b, lnv);
  k_headC  <<<dim3(BB,8), 256, 0, stream>>>(lnv, fc1_w, fc1_b, h1);
  k_headD  <<<BB, 64, 0, stream>>>(h1, fc2_w, fc2_b, (float*)d_out);
}

// Round 10
// 291.829 us; speedup vs baseline: 1.2222x; 1.0028x over previous
//
#include <hip/hip_runtime.h>
#include <math.h>

// Problem constants
#define BB 16
#define CC 512
#define HW 784
#define RR 32
#define NHD 8
#define HD 64
#define NT 784
#define NTILE 49                       // 784 = 49 * 16 n-tiles
#define CBS 131                        // Cb bounce-tile stride (2-way max both phases)

// workspace layout (float offsets)
#define OFS_AVGP   0
#define OFS_MAXP   8192
#define OFS_CHS    16384
#define OFS_CMAX   24576
#define OFS_CMEAN  37120
#define OFS_SP     49664
#define OFS_P1     62208
#define OFS_ABAR   70400
#define OFS_XG     78592
#define XG_SZ      (BB*CC*HW)          // 6,422,528 floats (region reused below)
#define OFS_XGT    (OFS_XG + XG_SZ)            // bf16 frag xg^T  (XG_SZ bf16)
#define OFS_QBF    (OFS_XGT + XG_SZ/2)         // bf16 frag Q     (XG_SZ bf16)
#define OFS_KBF    (OFS_QBF + XG_SZ/2)         // bf16 frag K     (XG_SZ bf16)
#define OFS_V2     (OFS_KBF + XG_SZ/2)         // bf16 V [bh][n][d]
#define OFS_WF     (OFS_V2 + XG_SZ)            // bf16 frag weights (786432 bf16)
// overlays inside the dead xg region:
#define OFS_W      OFS_XG                      // wsum   (100352 floats)
#define OFS_PV     (OFS_XG + 131072)           // pv     (8192)
#define OFS_LNV    (OFS_PV + 8192)             // lnv    (8192)
#define OFS_H1     (OFS_LNV + 8192)            // h1     (8192)
#define OFS_CMAXP  (OFS_XG + 262144)           // partial cmax [16][16][784]
#define OFS_CMEANP (OFS_CMAXP + 200704)        // partial csum [16][16][784]

typedef __attribute__((ext_vector_type(8))) short bf16x8;
typedef __attribute__((ext_vector_type(4))) float f32x4;

__device__ __forceinline__ unsigned short f2bf(float x) {
  union { float f; unsigned u; } v; v.f = x;
  unsigned r = v.u + 0x7fffu + ((v.u >> 16) & 1u);
  return (unsigned short)(r >> 16);
}
__device__ __forceinline__ float bf2f(unsigned short x) {
  union { unsigned u; float f; } v; v.u = ((unsigned)x) << 16;
  return v.f;
}

// ---------------- K1: per-(b,c) avg + max pooling over HW -------------------
__global__ void k_pool(const float* __restrict__ x, float* avg_p, float* max_p) {
  int wid = threadIdx.x >> 6;
  int lane = threadIdx.x & 63;
  int row = blockIdx.x * 4 + wid;                 // b*C + c, 8192 rows
  const float* xr = x + (size_t)row * HW;
  float s = 0.f, m = -INFINITY;
  for (int i = lane; i < HW; i += 64) { float v = xr[i]; s += v; m = fmaxf(m, v); }
  for (int o = 32; o; o >>= 1) { s += __shfl_down(s, o, 64); m = fmaxf(m, __shfl_down(m, o, 64)); }
  if (lane == 0) { avg_p[row] = s * (1.f/HW); max_p[row] = m; }
}

// ---------------- K2: channel-gate MLP, one block per batch -----------------
__global__ void k_chmlp(const float* avg_p, const float* max_p,
                        const float* w1, const float* b1,
                        const float* w2, const float* b2, float* chs) {
  __shared__ float pa[CC], pm[CC], part[256], hr[64];
  int b = blockIdx.x, t = threadIdx.x;
  for (int i = t; i < CC; i += 256) { pa[i] = avg_p[b*CC+i]; pm[i] = max_p[b*CC+i]; }
  __syncthreads();
  // phase 1: 64 dots (r,pool) x 4 chunks of 128
  {
    int rp = t & 63, ch = t >> 6;
    int r = rp & 31;
    const float* src = (rp < 32) ? pa : pm;
    const float* wr = w1 + (size_t)r*CC + ch*128;
    float s = 0.f;
    #pragma unroll 8
    for (int c = 0; c < 128; c++) s += src[ch*128 + c] * wr[c];
    part[t] = s;
  }
  __syncthreads();
  if (t < 64)
    hr[t] = fmaxf(part[t] + part[64+t] + part[128+t] + part[192+t] + b1[t & 31], 0.f);
  __syncthreads();
  for (int c = t; c < CC; c += 256) {
    float a = 2.f*b2[c];                          // b2 added by both mlp() calls
    const float* wr = w2 + c*RR;
    #pragma unroll
    for (int r = 0; r < RR; r++) a += (hr[r]+hr[32+r])*wr[r];
    chs[b*CC+c] = 1.f/(1.f+__expf(-a));
  }
}

// ---- K3a: channel gate partials: per (b, 32-ch chunk) max/sum per pixel ----
__global__ void k_chgatep(const float* __restrict__ x, const float* __restrict__ chs,
                          float* __restrict__ cmaxp, float* __restrict__ cmeanp) {
  __shared__ float cs[32];
  int b = blockIdx.x, cg = blockIdx.y, t = threadIdx.x;
  if (t < 32) cs[t] = chs[b*CC + cg*32 + t];
  __syncthreads();
  const float* xb = x + ((size_t)b*CC + cg*32)*HW;
  for (int pix = t; pix < HW; pix += 256) {
    float mx = -INFINITY, sm = 0.f;
    #pragma unroll
    for (int c = 0; c < 32; c++) {
      float v = xb[(size_t)c*HW + pix] * cs[c];
      mx = fmaxf(mx, v); sm += v;
    }
    cmaxp[(size_t)(cg*BB + b)*HW + pix] = mx;
    cmeanp[(size_t)(cg*BB + b)*HW + pix] = sm;
  }
}

// ---- K3b+K4 fused: reduce partials (LDS) -> 7x7 conv + BN + sigmoid --------
__global__ void k_credsp(const float* __restrict__ cmaxp, const float* __restrict__ cmeanp,
                         const float* __restrict__ w, const float* g, const float* be,
                         const float* mu, const float* var, float* __restrict__ sp) {
  __shared__ float cmx[HW], cmn[HW];
  int b = blockIdx.x, t = threadIdx.x;
  for (int pix = t; pix < HW; pix += 256) {
    float mx = -INFINITY, sm = 0.f;
    #pragma unroll
    for (int cg = 0; cg < 16; cg++) {
      mx = fmaxf(mx, cmaxp[(size_t)(cg*BB + b)*HW + pix]);
      sm += cmeanp[(size_t)(cg*BB + b)*HW + pix];
    }
    cmx[pix] = mx; cmn[pix] = sm * (1.f/CC);
  }
  __syncthreads();
  float bnscale = rsqrtf(var[0]+1e-5f)*g[0];
  for (int pix = t; pix < HW; pix += 256) {
    int h = pix/28, wd = pix%28;
    float acc = 0.f;
    for (int kh = 0; kh < 7; kh++) {
      int ih = h + kh - 3; if (ih < 0 || ih >= 28) continue;
      for (int kw = 0; kw < 7; kw++) {
        int iw = wd + kw - 3; if (iw < 0 || iw >= 28) continue;
        int ip = ih*28+iw;
        acc += cmx[ip]*w[kh*7+kw] + cmn[ip]*w[49+kh*7+kw];
      }
    }
    float s = (acc - mu[0])*bnscale + be[0];
    sp[b*HW+pix] = 1.f/(1.f+__expf(-s));
  }
}

// ---- K5: fused gates -> fragment-ready bf16 xgT + pooled p1 ----------------
__global__ void k_sfuse(const float* __restrict__ x, const float* __restrict__ chs,
                        const float* __restrict__ sp, unsigned short* __restrict__ xgT,
                        float* __restrict__ p1) {
  __shared__ float cs[CC];
  int nt = blockIdx.x, b = blockIdx.y;
  int t = threadIdx.x, ln = t & 63;
  for (int i = t; i < CC; i += 256) cs[i] = chs[b*CC+i];
  __syncthreads();
  int n = nt*16 + (ln & 15);
  float spv = sp[b*HW + n];
  const float* xb = x + (size_t)b*CC*HW;
  #pragma unroll
  for (int i = 0; i < 4; i++) {
    int s = (t >> 6) + 4*i;
    int c = s*32 + (ln >> 4)*8;
    float v[8]; bf16x8 p;
    #pragma unroll
    for (int j = 0; j < 8; j++) {
      v[j] = xb[(size_t)(c+j)*HW + n] * cs[c+j] * spv;
      p[j] = (short)f2bf(v[j]);
    }
    *(bf16x8*)(xgT + ((((size_t)b*NTILE + nt)*16 + s)*64 + ln)*8) = p;
    #pragma unroll
    for (int j = 0; j < 8; j++) {
      float sv = v[j];
      sv += __shfl_xor(sv, 1, 64); sv += __shfl_xor(sv, 2, 64);
      sv += __shfl_xor(sv, 4, 64); sv += __shfl_xor(sv, 8, 64);
      if ((ln & 15) == 0) atomicAdd(&p1[b*CC + c + j], sv * (1.f/HW));
    }
  }
}

// ---- K5c: reformat wq/wk/wv into fragment-ready bf16 ----------------------
__global__ void k_wfrag(const float* __restrict__ wq, const float* __restrict__ wk,
                        const float* __restrict__ wv, unsigned short* __restrict__ Wf) {
  int idx = blockIdx.x*256 + threadIdx.x;         // 98304 chunks
  int ln = idx & 63;
  int s  = (idx >> 6) & 15;
  int ct = (idx >> 10) & 31;
  int mat = idx >> 15;
  const float* W = (mat==0)? wq : (mat==1)? wk : wv;
  const float* src = W + (size_t)(ct*16 + (ln & 15))*CC + s*32 + (ln >> 4)*8;
  float4 f0 = *(const float4*)src;
  float4 f1 = *(const float4*)(src + 4);
  bf16x8 p;
  p[0]=(short)f2bf(f0.x); p[1]=(short)f2bf(f0.y); p[2]=(short)f2bf(f0.z); p[3]=(short)f2bf(f0.w);
  p[4]=(short)f2bf(f1.x); p[5]=(short)f2bf(f1.y); p[6]=(short)f2bf(f1.z); p[7]=(short)f2bf(f1.w);
  *(bf16x8*)(Wf + (size_t)idx*8) = p;
}

// ---------------- K6: QKV projection — pure-MFMA, no LDS in K-loop ----------
// 1-D grid, XCD-swizzled: blk = yb*208 + (mt*16 + b). The 12 blocks sharing
// an A-panel (mt,b) are spaced 208 apart (208 % 8 == 0) -> same XCD L2.
__global__ __launch_bounds__(256) void k_qkv_mfma(
    const unsigned short* __restrict__ xgT, const unsigned short* __restrict__ Wf,
    const float* __restrict__ bq, const float* __restrict__ bk, const float* __restrict__ bv,
    unsigned short* __restrict__ Qbf, unsigned short* __restrict__ Kbf,
    unsigned short* __restrict__ Vbf) {
  __shared__ float Cb[64*CBS];                    // bounce tile, stride 131
  int blk = blockIdx.x;
  int yb = blk / 208;                             // 0..11: mat=yb>>2, c0=(yb&3)*128
  int r0 = blk % 208;
  int mt = r0 >> 4;                               // 0..12: n-tiles 4mt..4mt+3
  int b  = r0 & 15;
  int mat = yb >> 2;
  int c0 = (yb & 3) * 128;
  int t = threadIdx.x, w = t >> 6, ln = t & 63;
  const unsigned short* Ab = xgT + (size_t)b*NTILE*8192;
  const unsigned short* Bb = Wf + (size_t)mat*32*8192;
  int ctg0 = (c0 >> 4) + w*2;
  f32x4 acc[4][2];
  #pragma unroll
  for (int m = 0; m < 4; m++)
    #pragma unroll
    for (int c2 = 0; c2 < 2; c2++) acc[m][c2] = (f32x4){0.f,0.f,0.f,0.f};
  int ntc[4];
  #pragma unroll
  for (int m = 0; m < 4; m++) { int nt = 4*mt + m; ntc[m] = (nt > 48) ? 48 : nt; }
  #pragma unroll 2
  for (int s = 0; s < 16; s++) {
    bf16x8 bf0 = *(const bf16x8*)(Bb + (size_t)(ctg0*16 + s)*512 + ln*8);
    bf16x8 bf1 = *(const bf16x8*)(Bb + (size_t)((ctg0+1)*16 + s)*512 + ln*8);
    bf16x8 af[4];
    #pragma unroll
    for (int m = 0; m < 4; m++)
      af[m] = *(const bf16x8*)(Ab + (size_t)(ntc[m]*16 + s)*512 + ln*8);
    #pragma unroll
    for (int m = 0; m < 4; m++) {
      acc[m][0] = __builtin_amdgcn_mfma_f32_16x16x32_bf16(af[m], bf0, acc[m][0], 0,0,0);
      acc[m][1] = __builtin_amdgcn_mfma_f32_16x16x32_bf16(af[m], bf1, acc[m][1], 0,0,0);
    }
  }
  #pragma unroll
  for (int m = 0; m < 4; m++)
    #pragma unroll
    for (int c2 = 0; c2 < 2; c2++)
      #pragma unroll
      for (int r = 0; r < 4; r++)
        Cb[(m*16 + (ln>>4)*4 + r)*CBS + w*32 + c2*16 + (ln&15)] = acc[m][c2][r];
  __syncthreads();
  const float* bias = (mat==0)? bq : (mat==1)? bk : bv;
  #pragma unroll
  for (int i = 0; i < 4; i++) {
    int p = w*4 + i;                              // 16 (ntl, sl) pairs
    int ntl = p >> 2, sl = p & 3;
    int nt = 4*mt + ntl;
    if (nt > 48) continue;
    int row = ntl*16 + (ln & 15);
    int col = sl*32 + (ln >> 4)*8;
    float v[8];
    #pragma unroll
    for (int j = 0; j < 8; j++) v[j] = Cb[row*CBS + col + j] + bias[c0 + col + j];
    int token = nt*16 + (ln & 15);
    int h = (c0 >> 6) + (sl >> 1);
    int bh = b*NHD + h;
    bf16x8 pk;
    #pragma unroll
    for (int j = 0; j < 8; j++) pk[j] = (short)f2bf(v[j]);
    if (mat < 2) {
      unsigned short* Out = (mat == 0) ? Qbf : Kbf;
      *(bf16x8*)(Out + ((size_t)bh*NTILE + nt)*1024 + (size_t)(sl & 1)*512 + ln*8) = pk;
    } else {
      int d = (sl & 1)*32 + (ln >> 4)*8;
      *(bf16x8*)(Vbf + ((size_t)bh*NT + token)*HD + d) = pk;
    }
  }
}

// ---------------- K7: single-pass MFMA attention, e in registers ------------
// Block = (16-query n-tile nt, bh). Wave w owns K-tiles {w, w+4, ..., w+48}.
// e = exp(s/8) kept in f32x4 ev[13] (register-resident, full unroll); after
// the l-reduction each lane rescales its own ev by rl and cross-lane-reduces.
// No Se stripe: LDS = 320 B.
__global__ __launch_bounds__(256, 5) void k_attn7(const unsigned short* __restrict__ Qbf,
    const unsigned short* __restrict__ Kbf, float* __restrict__ wsum) {
  __shared__ float l_tmp[64];
  __shared__ float rl[16];
  int bh = blockIdx.x & 127, nt = blockIdx.x >> 7;
  int t = threadIdx.x, w = t >> 6, ln = t & 63;
  const unsigned short* Qb = Qbf + ((size_t)bh*NTILE + nt)*1024;
  const unsigned short* Kb = Kbf + (size_t)bh*NTILE*1024;
  bf16x8 q0 = *(const bf16x8*)(Qb + ln*8);
  bf16x8 q1 = *(const bf16x8*)(Qb + 512 + ln*8);
  f32x4 ev[13];
  float lp[4] = {0.f,0.f,0.f,0.f};
  #pragma unroll
  for (int i = 0; i < 13; i++) {
    int mt = w + 4*i;
    bool valid = (i < 12) || (w == 0);            // only w==0 has a 13th tile
    int mtc = valid ? mt : 48;
    bf16x8 k0 = *(const bf16x8*)(Kb + (size_t)mtc*1024 + ln*8);
    bf16x8 k1 = *(const bf16x8*)(Kb + (size_t)mtc*1024 + 512 + ln*8);
    f32x4 a = {0.f,0.f,0.f,0.f};
    a = __builtin_amdgcn_mfma_f32_16x16x32_bf16(q0, k0, a, 0,0,0);
    a = __builtin_amdgcn_mfma_f32_16x16x32_bf16(q1, k1, a, 0,0,0);
    f32x4 e;
    #pragma unroll
    for (int r = 0; r < 4; r++) e[r] = __expf(a[r]*0.125f);  // n=(ln>>4)*4+r, m-col=ln&15
    ev[i] = e;
    if (valid) {
      #pragma unroll
      for (int r = 0; r < 4; r++) lp[r] += e[r];
    }
  }
  // reduce lp across the 16 m-columns (lane bits 0..3)
  #pragma unroll
  for (int r = 0; r < 4; r++) {
    float v = lp[r];
    v += __shfl_xor(v,1,64); v += __shfl_xor(v,2,64);
    v += __shfl_xor(v,4,64); v += __shfl_xor(v,8,64);
    if ((ln & 15) == 0) l_tmp[w*16 + (ln>>4)*4 + r] = v;
  }
  __syncthreads();
  if (t < 16) rl[t] = 1.f / (l_tmp[t] + l_tmp[16+t] + l_tmp[32+t] + l_tmp[48+t]);
  __syncthreads();
  f32x4 rlq = *(const f32x4*)&rl[(ln >> 4)*4];    // this lane's 4 n-rows
  #pragma unroll
  for (int i = 0; i < 13; i++) {
    int mt = w + 4*i;
    bool valid = (i < 12) || (w == 0);
    float v = ev[i][0]*rlq[0] + ev[i][1]*rlq[1] + ev[i][2]*rlq[2] + ev[i][3]*rlq[3];
    v += __shfl_xor(v, 16, 64);                   // sum over the 4 n-quads
    v += __shfl_xor(v, 32, 64);
    if (valid && ln < 16)
      atomicAdd(&wsum[bh*NT + mt*16 + ln], v);
  }
}

// ---- K7c: abar[bh,d] = (1/N) sum_m w_m V[m,d] (V bf16) ---------------------
__global__ void k_attn_av(const float* __restrict__ w, const unsigned short* __restrict__ Vm,
                          float* __restrict__ abar) {
  __shared__ float red[256];
  int bh = blockIdx.x, t = threadIdx.x;
  int d = t & 63, chunk = t >> 6;                 // 4 chunks of 196 keys
  float acc = 0.f;
  const unsigned short* vb = Vm + (size_t)bh*NT*HD;
  const float* wb = w + bh*NT;
  for (int m = chunk*196; m < (chunk+1)*196; m++)
    acc += wb[m] * bf2f(vb[(size_t)m*HD + d]);
  red[t] = acc;
  __syncthreads();
  if (t < 64)
    abar[bh*HD + t] = (red[t] + red[64+t] + red[128+t] + red[192+t]) * (1.f/NT);
}

// --------- K8: pooled head, parallelized ------------------------------------
__global__ void k_headA(const float* __restrict__ p1, const float* __restrict__ abar,
                        const float* __restrict__ wo, const float* __restrict__ bo,
                        float* __restrict__ pv) {
  int b = blockIdx.x, cg = blockIdx.y;
  int t = threadIdx.x, w = t >> 6, ln = t & 63;
  float a[8];
  #pragma unroll
  for (int k = 0; k < 8; k++) a[k] = abar[b*CC + ln + 64*k];
  int c0 = cg*64 + w*16;
  for (int i = 0; i < 16; i++) {
    int c = c0 + i;
    const float* wr = wo + (size_t)c*CC;
    float s = 0.f;
    #pragma unroll
    for (int k = 0; k < 8; k++) s += a[k] * wr[ln + 64*k];
    for (int o = 32; o; o >>= 1) s += __shfl_down(s, o, 64);
    if (ln == 0) pv[b*CC + c] = s + bo[c] + p1[b*CC + c];
  }
}

__global__ void k_headB(const float* __restrict__ pv, const float* __restrict__ ln_g,
                        const float* __restrict__ ln_b, float* __restrict__ lnv) {
  int b = blockIdx.x, ln = threadIdx.x;
  float v[8], s = 0.f, s2 = 0.f;
  #pragma unroll
  for (int k = 0; k < 8; k++) { v[k] = pv[b*CC + ln + 64*k]; s += v[k]; s2 += v[k]*v[k]; }
  for (int o = 32; o; o >>= 1) { s += __shfl_down(s, o, 64); s2 += __shfl_down(s2, o, 64); }
  s = __shfl(s, 0, 64); s2 = __shfl(s2, 0, 64);
  float mean = s * (1.f/CC);
  float rs = rsqrtf(s2*(1.f/CC) - mean*mean + 1e-5f);
  #pragma unroll
  for (int k = 0; k < 8; k++) {
    int c = ln + 64*k;
    lnv[b*CC + c] = (v[k]-mean)*rs*ln_g[c] + ln_b[c];
  }
}

__global__ void k_headC(const float* __restrict__ lnv, const float* __restrict__ fc1_w,
                        const float* __restrict__ fc1_b, float* __restrict__ h1) {
  int b = blockIdx.x, cg = blockIdx.y;
  int t = threadIdx.x, w = t >> 6, ln = t & 63;
  float a[8];
  #pragma unroll
  for (int k = 0; k < 8; k++) a[k] = lnv[b*CC + ln + 64*k];
  int c0 = cg*64 + w*16;
  for (int i = 0; i < 16; i++) {
    int c = c0 + i;
    const float* wr = fc1_w + (size_t)c*CC;
    float s = 0.f;
    #pragma unroll
    for (int k = 0; k < 8; k++) s += a[k] * wr[ln + 64*k];
    for (int o = 32; o; o >>= 1) s += __shfl_down(s, o, 64);
    if (ln == 0) h1[b*CC + c] = fmaxf(s + fc1_b[c], 0.f);
  }
}

__global__ void k_headD(const float* __restrict__ h1, const float* __restrict__ fc2_w,
                        const float* __restrict__ fc2_b, float* __restrict__ out) {
  int b = blockIdx.x, ln = threadIdx.x;
  float s = 0.f;
  #pragma unroll
  for (int k = 0; k < 8; k++) s += h1[b*CC + ln + 64*k] * fc2_w[ln + 64*k];
  for (int o = 32; o; o >>= 1) s += __shfl_down(s, o, 64);
  if (ln == 0) out[b] = s + fc2_b[0];
}

extern "C" void kernel_launch(void* const* d_in, const int* in_sizes, int n_in,
                              void* d_out, int out_size, void* d_ws, size_t ws_size,
                              hipStream_t stream) {
  const float* x       = (const float*)d_in[0];
  const float* mlp_w1  = (const float*)d_in[1];
  const float* mlp_b1  = (const float*)d_in[2];
  const float* mlp_w2  = (const float*)d_in[3];
  const float* mlp_b2  = (const float*)d_in[4];
  const float* sp_w    = (const float*)d_in[5];
  const float* sp_g    = (const float*)d_in[6];
  const float* sp_b    = (const float*)d_in[7];
  const float* sp_mu   = (const float*)d_in[8];
  const float* sp_var  = (const float*)d_in[9];
  const float* wq      = (const float*)d_in[10];
  const float* bq      = (const float*)d_in[11];
  const float* wk      = (const float*)d_in[12];
  const float* bk      = (const float*)d_in[13];
  const float* wv      = (const float*)d_in[14];
  const float* bv      = (const float*)d_in[15];
  const float* wo      = (const float*)d_in[16];
  const float* bo      = (const float*)d_in[17];
  const float* ln_g    = (const float*)d_in[18];
  const float* ln_b    = (const float*)d_in[19];
  const float* fc1_w   = (const float*)d_in[20];
  const float* fc1_b   = (const float*)d_in[21];
  const float* fc2_w   = (const float*)d_in[22];
  const float* fc2_b   = (const float*)d_in[23];

  float* ws = (float*)d_ws;
  float* avg_p = ws + OFS_AVGP;
  float* max_p = ws + OFS_MAXP;
  float* chs   = ws + OFS_CHS;
  float* sp    = ws + OFS_SP;
  float* p1    = ws + OFS_P1;
  float* abar  = ws + OFS_ABAR;
  unsigned short* xgT = (unsigned short*)(ws + OFS_XGT);
  unsigned short* Qbf = (unsigned short*)(ws + OFS_QBF);
  unsigned short* Kbf = (unsigned short*)(ws + OFS_KBF);
  unsigned short* Vbf = (unsigned short*)(ws + OFS_V2);
  unsigned short* Wf  = (unsigned short*)(ws + OFS_WF);
  float* wsum  = ws + OFS_W;
  float* pv    = ws + OFS_PV;
  float* lnv   = ws + OFS_LNV;
  float* h1    = ws + OFS_H1;
  float* cmaxp = ws + OFS_CMAXP;
  float* cmeanp= ws + OFS_CMEANP;

  hipMemsetAsync(p1, 0, BB*CC*sizeof(float), stream);
  hipMemsetAsync(wsum, 0, BB*NHD*NT*sizeof(float), stream);

  k_pool   <<<2048, 256, 0, stream>>>(x, avg_p, max_p);
  k_chmlp  <<<BB, 256, 0, stream>>>(avg_p, max_p, mlp_w1, mlp_b1, mlp_w2, mlp_b2, chs);
  k_chgatep<<<dim3(BB,16), 256, 0, stream>>>(x, chs, cmaxp, cmeanp);
  k_credsp <<<BB, 256, 0, stream>>>(cmaxp, cmeanp, sp_w, sp_g, sp_b, sp_mu, sp_var, sp);
  k_wfrag  <<<384, 256, 0, stream>>>(wq, wk, wv, Wf);
  k_sfuse  <<<dim3(NTILE,BB), 256, 0, stream>>>(x, chs, sp, xgT, p1);
  k_qkv_mfma<<<2496, 256, 0, stream>>>(xgT, Wf, bq, bk, bv, Qbf, Kbf, Vbf);
  k_attn7  <<<NTILE*128, 256, 0, stream>>>(Qbf, Kbf, wsum);
  k_attn_av<<<128, 256, 0, stream>>>(wsum, Vbf, abar);
  k_headA  <<<dim3(BB,8), 256, 0, stream>>>(p1, abar, wo, bo, pv);
  k_headB  <<<BB, 64, 0, stream>>>(pv, ln_g, ln_b, lnv);
  k_headC  <<<dim3(BB,8), 256, 0, stream>>>(lnv, fc1_w, fc1_b, h1);
  k_headD  <<<BB, 64, 0, stream>>>(h1, fc2_w, fc2_b, (float*)d_out);
}

// Round 11
// 273.106 us; speedup vs baseline: 1.3060x; 1.0686x over previous
//
#include <hip/hip_runtime.h>
#include <math.h>

// Problem constants
#define BB 16
#define CC 512
#define HW 784
#define RR 32
#define NHD 8
#define HD 64
#define NT 784
#define NTILE 49                       // 784 = 49 * 16 n-tiles
#define CBS 132                        // Cb stride: writes 2-way (S%8==4), b128 reads uniform

// workspace layout (float offsets)
#define OFS_AVGP   0
#define OFS_MAXP   8192
#define OFS_CHS    16384
#define OFS_SP     49664
#define OFS_P1     62208
#define OFS_ABAR   70400
#define OFS_XG     78592
#define XG_SZ      (BB*CC*HW)          // 6,422,528 floats (region reused below)
#define OFS_XGT    (OFS_XG + XG_SZ)            // bf16 frag xg^T  (XG_SZ bf16)
#define OFS_QBF    (OFS_XGT + XG_SZ/2)         // bf16 frag Q     (XG_SZ bf16)
#define OFS_KBF    (OFS_QBF + XG_SZ/2)         // bf16 frag K     (XG_SZ bf16)
#define OFS_V2     (OFS_KBF + XG_SZ/2)         // bf16 V [bh][n][d]
#define OFS_WF     (OFS_V2 + XG_SZ)            // bf16 frag weights (786432 bf16)
// overlays inside the dead xg region:
#define OFS_W      OFS_XG                      // wsum   (100352 floats)
#define OFS_PV     (OFS_XG + 131072)           // pv     (8192)
#define OFS_H1     (OFS_PV + 8192)             // h1     (8192)
#define OFS_CMAXP  (OFS_XG + 262144)           // partial cmax [16][16][784]
#define OFS_CMEANP (OFS_CMAXP + 200704)        // partial csum [16][16][784]

typedef __attribute__((ext_vector_type(8))) short bf16x8;
typedef __attribute__((ext_vector_type(4))) float f32x4;

__device__ __forceinline__ unsigned short f2bf(float x) {
  union { float f; unsigned u; } v; v.f = x;
  unsigned r = v.u + 0x7fffu + ((v.u >> 16) & 1u);
  return (unsigned short)(r >> 16);
}
__device__ __forceinline__ float bf2f(unsigned short x) {
  union { unsigned u; float f; } v; v.u = ((unsigned)x) << 16;
  return v.f;
}

// ---------------- K1: per-(b,c) avg + max pooling over HW -------------------
__global__ void k_pool(const float* __restrict__ x, float* avg_p, float* max_p) {
  int wid = threadIdx.x >> 6;
  int lane = threadIdx.x & 63;
  int row = blockIdx.x * 4 + wid;                 // b*C + c, 8192 rows
  const float* xr = x + (size_t)row * HW;
  float s = 0.f, m = -INFINITY;
  for (int i = lane; i < HW; i += 64) { float v = xr[i]; s += v; m = fmaxf(m, v); }
  for (int o = 32; o; o >>= 1) { s += __shfl_down(s, o, 64); m = fmaxf(m, __shfl_down(m, o, 64)); }
  if (lane == 0) { avg_p[row] = s * (1.f/HW); max_p[row] = m; }
}

// ---------------- K2: channel-gate MLP, one block per batch -----------------
__global__ void k_chmlp(const float* avg_p, const float* max_p,
                        const float* w1, const float* b1,
                        const float* w2, const float* b2, float* chs) {
  __shared__ float pa[CC], pm[CC], part[256], hr[64];
  int b = blockIdx.x, t = threadIdx.x;
  for (int i = t; i < CC; i += 256) { pa[i] = avg_p[b*CC+i]; pm[i] = max_p[b*CC+i]; }
  __syncthreads();
  {
    int rp = t & 63, ch = t >> 6;
    int r = rp & 31;
    const float* src = (rp < 32) ? pa : pm;
    const float* wr = w1 + (size_t)r*CC + ch*128;
    float s = 0.f;
    #pragma unroll 8
    for (int c = 0; c < 128; c++) s += src[ch*128 + c] * wr[c];
    part[t] = s;
  }
  __syncthreads();
  if (t < 64)
    hr[t] = fmaxf(part[t] + part[64+t] + part[128+t] + part[192+t] + b1[t & 31], 0.f);
  __syncthreads();
  for (int c = t; c < CC; c += 256) {
    float a = 2.f*b2[c];                          // b2 added by both mlp() calls
    const float* wr = w2 + c*RR;
    #pragma unroll
    for (int r = 0; r < RR; r++) a += (hr[r]+hr[32+r])*wr[r];
    chs[b*CC+c] = 1.f/(1.f+__expf(-a));
  }
}

// ---- K3a: channel gate partials: per (b, 32-ch chunk) max/sum per pixel ----
__global__ void k_chgatep(const float* __restrict__ x, const float* __restrict__ chs,
                          float* __restrict__ cmaxp, float* __restrict__ cmeanp) {
  __shared__ float cs[32];
  int b = blockIdx.x, cg = blockIdx.y, t = threadIdx.x;
  if (t < 32) cs[t] = chs[b*CC + cg*32 + t];
  __syncthreads();
  const float* xb = x + ((size_t)b*CC + cg*32)*HW;
  for (int pix = t; pix < HW; pix += 256) {
    float mx = -INFINITY, sm = 0.f;
    #pragma unroll
    for (int c = 0; c < 32; c++) {
      float v = xb[(size_t)c*HW + pix] * cs[c];
      mx = fmaxf(mx, v); sm += v;
    }
    cmaxp[(size_t)(cg*BB + b)*HW + pix] = mx;
    cmeanp[(size_t)(cg*BB + b)*HW + pix] = sm;
  }
}

// ---- K3b+K4 fused: reduce partials (LDS) -> 7x7 conv + BN + sigmoid --------
__global__ void k_credsp(const float* __restrict__ cmaxp, const float* __restrict__ cmeanp,
                         const float* __restrict__ w, const float* g, const float* be,
                         const float* mu, const float* var, float* __restrict__ sp) {
  __shared__ float cmx[HW], cmn[HW];
  int b = blockIdx.x, t = threadIdx.x;
  for (int pix = t; pix < HW; pix += 256) {
    float mx = -INFINITY, sm = 0.f;
    #pragma unroll
    for (int cg = 0; cg < 16; cg++) {
      mx = fmaxf(mx, cmaxp[(size_t)(cg*BB + b)*HW + pix]);
      sm += cmeanp[(size_t)(cg*BB + b)*HW + pix];
    }
    cmx[pix] = mx; cmn[pix] = sm * (1.f/CC);
  }
  __syncthreads();
  float bnscale = rsqrtf(var[0]+1e-5f)*g[0];
  for (int pix = t; pix < HW; pix += 256) {
    int h = pix/28, wd = pix%28;
    float acc = 0.f;
    for (int kh = 0; kh < 7; kh++) {
      int ih = h + kh - 3; if (ih < 0 || ih >= 28) continue;
      for (int kw = 0; kw < 7; kw++) {
        int iw = wd + kw - 3; if (iw < 0 || iw >= 28) continue;
        int ip = ih*28+iw;
        acc += cmx[ip]*w[kh*7+kw] + cmn[ip]*w[49+kh*7+kw];
      }
    }
    float s = (acc - mu[0])*bnscale + be[0];
    sp[b*HW+pix] = 1.f/(1.f+__expf(-s));
  }
}

// ---- K5: fused gates -> fragment-ready bf16 xgT (no p1 here) ---------------
__global__ void k_sfuse(const float* __restrict__ x, const float* __restrict__ chs,
                        const float* __restrict__ sp, unsigned short* __restrict__ xgT) {
  __shared__ float cs[CC];
  int nt = blockIdx.x, b = blockIdx.y;
  int t = threadIdx.x, ln = t & 63;
  for (int i = t; i < CC; i += 256) cs[i] = chs[b*CC+i];
  __syncthreads();
  int n = nt*16 + (ln & 15);
  float spv = sp[b*HW + n];
  const float* xb = x + (size_t)b*CC*HW;
  #pragma unroll
  for (int i = 0; i < 4; i++) {
    int s = (t >> 6) + 4*i;
    int c = s*32 + (ln >> 4)*8;
    bf16x8 p;
    #pragma unroll
    for (int j = 0; j < 8; j++)
      p[j] = (short)f2bf(xb[(size_t)(c+j)*HW + n] * cs[c+j] * spv);
    *(bf16x8*)(xgT + ((((size_t)b*NTILE + nt)*16 + s)*64 + ln)*8) = p;
  }
}

// ---- K5b: p1[b][c] = mean_n xgT (from bf16 fragments, coalesced b128) ------
__global__ void k_p1(const unsigned short* __restrict__ xgT, float* __restrict__ p1) {
  __shared__ float red[4][32];
  int b = blockIdx.x, s = blockIdx.y;
  int t = threadIdx.x, w = t >> 6, ln = t & 63;
  float acc[8] = {0.f,0.f,0.f,0.f,0.f,0.f,0.f,0.f};
  for (int nt = w; nt < NTILE; nt += 4) {
    bf16x8 p = *(const bf16x8*)(xgT + ((((size_t)b*NTILE + nt)*16 + s)*64 + ln)*8);
    #pragma unroll
    for (int j = 0; j < 8; j++) acc[j] += bf2f((unsigned short)p[j]);
  }
  #pragma unroll
  for (int j = 0; j < 8; j++) {
    float v = acc[j];
    v += __shfl_xor(v,1,64); v += __shfl_xor(v,2,64);
    v += __shfl_xor(v,4,64); v += __shfl_xor(v,8,64);
    if ((ln & 15) == 0) red[w][(ln>>4)*8 + j] = v;
  }
  __syncthreads();
  if (t < 32)
    p1[b*CC + s*32 + t] = (red[0][t]+red[1][t]+red[2][t]+red[3][t]) * (1.f/HW);
}

// ---- K5c: reformat wq/wk/wv into fragment-ready bf16 ----------------------
__global__ void k_wfrag(const float* __restrict__ wq, const float* __restrict__ wk,
                        const float* __restrict__ wv, unsigned short* __restrict__ Wf) {
  int idx = blockIdx.x*256 + threadIdx.x;         // 98304 chunks
  int ln = idx & 63;
  int s  = (idx >> 6) & 15;
  int ct = (idx >> 10) & 31;
  int mat = idx >> 15;
  const float* W = (mat==0)? wq : (mat==1)? wk : wv;
  const float* src = W + (size_t)(ct*16 + (ln & 15))*CC + s*32 + (ln >> 4)*8;
  float4 f0 = *(const float4*)src;
  float4 f1 = *(const float4*)(src + 4);
  bf16x8 p;
  p[0]=(short)f2bf(f0.x); p[1]=(short)f2bf(f0.y); p[2]=(short)f2bf(f0.z); p[3]=(short)f2bf(f0.w);
  p[4]=(short)f2bf(f1.x); p[5]=(short)f2bf(f1.y); p[6]=(short)f2bf(f1.z); p[7]=(short)f2bf(f1.w);
  *(bf16x8*)(Wf + (size_t)idx*8) = p;
}

// ---------------- K6: QKV projection — pure-MFMA, no LDS in K-loop ----------
// 1-D grid, XCD-swizzled: blk = yb*208 + (mt*16 + b). The 12 blocks sharing
// an A-panel (mt,b) are spaced 208 apart (208 % 8 == 0) -> same XCD L2.
__global__ __launch_bounds__(256) void k_qkv_mfma(
    const unsigned short* __restrict__ xgT, const unsigned short* __restrict__ Wf,
    const float* __restrict__ bq, const float* __restrict__ bk, const float* __restrict__ bv,
    unsigned short* __restrict__ Qbf, unsigned short* __restrict__ Kbf,
    unsigned short* __restrict__ Vbf) {
  __shared__ __align__(16) float Cb[64*CBS];      // bounce tile, stride 132
  int blk = blockIdx.x;
  int yb = blk / 208;                             // 0..11: mat=yb>>2, c0=(yb&3)*128
  int r0 = blk % 208;
  int mt = r0 >> 4;                               // 0..12: n-tiles 4mt..4mt+3
  int b  = r0 & 15;
  int mat = yb >> 2;
  int c0 = (yb & 3) * 128;
  int t = threadIdx.x, w = t >> 6, ln = t & 63;
  const unsigned short* Ab = xgT + (size_t)b*NTILE*8192;
  const unsigned short* Bb = Wf + (size_t)mat*32*8192;
  int ctg0 = (c0 >> 4) + w*2;
  f32x4 acc[4][2];
  #pragma unroll
  for (int m = 0; m < 4; m++)
    #pragma unroll
    for (int c2 = 0; c2 < 2; c2++) acc[m][c2] = (f32x4){0.f,0.f,0.f,0.f};
  int ntc[4];
  #pragma unroll
  for (int m = 0; m < 4; m++) { int nt = 4*mt + m; ntc[m] = (nt > 48) ? 48 : nt; }
  #pragma unroll 2
  for (int s = 0; s < 16; s++) {
    bf16x8 bf0 = *(const bf16x8*)(Bb + (size_t)(ctg0*16 + s)*512 + ln*8);
    bf16x8 bf1 = *(const bf16x8*)(Bb + (size_t)((ctg0+1)*16 + s)*512 + ln*8);
    bf16x8 af[4];
    #pragma unroll
    for (int m = 0; m < 4; m++)
      af[m] = *(const bf16x8*)(Ab + (size_t)(ntc[m]*16 + s)*512 + ln*8);
    #pragma unroll
    for (int m = 0; m < 4; m++) {
      acc[m][0] = __builtin_amdgcn_mfma_f32_16x16x32_bf16(af[m], bf0, acc[m][0], 0,0,0);
      acc[m][1] = __builtin_amdgcn_mfma_f32_16x16x32_bf16(af[m], bf1, acc[m][1], 0,0,0);
    }
  }
  #pragma unroll
  for (int m = 0; m < 4; m++)
    #pragma unroll
    for (int c2 = 0; c2 < 2; c2++)
      #pragma unroll
      for (int r = 0; r < 4; r++)
        Cb[(m*16 + (ln>>4)*4 + r)*CBS + w*32 + c2*16 + (ln&15)] = acc[m][c2][r];
  __syncthreads();
  const float* bias = (mat==0)? bq : (mat==1)? bk : bv;
  #pragma unroll
  for (int i = 0; i < 4; i++) {
    int p = w*4 + i;                              // 16 (ntl, sl) pairs
    int ntl = p >> 2, sl = p & 3;
    int nt = 4*mt + ntl;
    if (nt > 48) continue;
    int row = ntl*16 + (ln & 15);
    int col = sl*32 + (ln >> 4)*8;
    float4 v0 = *(const float4*)&Cb[row*CBS + col];      // ds_read_b128: uniform banks
    float4 v1 = *(const float4*)&Cb[row*CBS + col + 4];
    float v[8] = {v0.x, v0.y, v0.z, v0.w, v1.x, v1.y, v1.z, v1.w};
    #pragma unroll
    for (int j = 0; j < 8; j++) v[j] += bias[c0 + col + j];
    int token = nt*16 + (ln & 15);
    int h = (c0 >> 6) + (sl >> 1);
    int bh = b*NHD + h;
    bf16x8 pk;
    #pragma unroll
    for (int j = 0; j < 8; j++) pk[j] = (short)f2bf(v[j]);
    if (mat < 2) {
      unsigned short* Out = (mat == 0) ? Qbf : Kbf;
      *(bf16x8*)(Out + ((size_t)bh*NTILE + nt)*1024 + (size_t)(sl & 1)*512 + ln*8) = pk;
    } else {
      int d = (sl & 1)*32 + (ln >> 4)*8;
      *(bf16x8*)(Vbf + ((size_t)bh*NT + token)*HD + d) = pk;
    }
  }
}

// ---------------- K7: single-pass MFMA attention, e in registers ------------
// Block = (16-query n-tile nt, bh). Wave w owns K-tiles {w, w+4, ..., w+48}.
// e = exp(s/8) in f32x4 ev[13] (register-resident); 128-VGPR cap (bounds 4).
__global__ __launch_bounds__(256, 4) void k_attn7(const unsigned short* __restrict__ Qbf,
    const unsigned short* __restrict__ Kbf, float* __restrict__ wsum) {
  __shared__ float l_tmp[64];
  __shared__ float rl[16];
  int bh = blockIdx.x & 127, nt = blockIdx.x >> 7;
  int t = threadIdx.x, w = t >> 6, ln = t & 63;
  const unsigned short* Qb = Qbf + ((size_t)bh*NTILE + nt)*1024;
  const unsigned short* Kb = Kbf + (size_t)bh*NTILE*1024;
  bf16x8 q0 = *(const bf16x8*)(Qb + ln*8);
  bf16x8 q1 = *(const bf16x8*)(Qb + 512 + ln*8);
  f32x4 ev[13];
  float lp[4] = {0.f,0.f,0.f,0.f};
  #pragma unroll
  for (int i = 0; i < 13; i++) {
    int mt = w + 4*i;
    bool valid = (i < 12) || (w == 0);            // only w==0 has a 13th tile
    int mtc = valid ? mt : 48;
    bf16x8 k0 = *(const bf16x8*)(Kb + (size_t)mtc*1024 + ln*8);
    bf16x8 k1 = *(const bf16x8*)(Kb + (size_t)mtc*1024 + 512 + ln*8);
    f32x4 a = {0.f,0.f,0.f,0.f};
    a = __builtin_amdgcn_mfma_f32_16x16x32_bf16(q0, k0, a, 0,0,0);
    a = __builtin_amdgcn_mfma_f32_16x16x32_bf16(q1, k1, a, 0,0,0);
    f32x4 e;
    #pragma unroll
    for (int r = 0; r < 4; r++) e[r] = __expf(a[r]*0.125f);  // n=(ln>>4)*4+r, m-col=ln&15
    ev[i] = e;
    if (valid) {
      #pragma unroll
      for (int r = 0; r < 4; r++) lp[r] += e[r];
    }
  }
  #pragma unroll
  for (int r = 0; r < 4; r++) {
    float v = lp[r];
    v += __shfl_xor(v,1,64); v += __shfl_xor(v,2,64);
    v += __shfl_xor(v,4,64); v += __shfl_xor(v,8,64);
    if ((ln & 15) == 0) l_tmp[w*16 + (ln>>4)*4 + r] = v;
  }
  __syncthreads();
  if (t < 16) rl[t] = 1.f / (l_tmp[t] + l_tmp[16+t] + l_tmp[32+t] + l_tmp[48+t]);
  __syncthreads();
  f32x4 rlq = *(const f32x4*)&rl[(ln >> 4)*4];    // this lane's 4 n-rows
  #pragma unroll
  for (int i = 0; i < 13; i++) {
    int mt = w + 4*i;
    bool valid = (i < 12) || (w == 0);
    float v = ev[i][0]*rlq[0] + ev[i][1]*rlq[1] + ev[i][2]*rlq[2] + ev[i][3]*rlq[3];
    v += __shfl_xor(v, 16, 64);                   // sum over the 4 n-quads
    v += __shfl_xor(v, 32, 64);
    if (valid && ln < 16)
      atomicAdd(&wsum[bh*NT + mt*16 + ln], v);
  }
}

// ---- K7c: abar[bh,d] = (1/N) sum_m w_m V[m,d] (V bf16) ---------------------
__global__ void k_attn_av(const float* __restrict__ w, const unsigned short* __restrict__ Vm,
                          float* __restrict__ abar) {
  __shared__ float red[256];
  int bh = blockIdx.x, t = threadIdx.x;
  int d = t & 63, chunk = t >> 6;                 // 4 chunks of 196 keys
  float acc = 0.f;
  const unsigned short* vb = Vm + (size_t)bh*NT*HD;
  const float* wb = w + bh*NT;
  for (int m = chunk*196; m < (chunk+1)*196; m++)
    acc += wb[m] * bf2f(vb[(size_t)m*HD + d]);
  red[t] = acc;
  __syncthreads();
  if (t < 64)
    abar[bh*HD + t] = (red[t] + red[64+t] + red[128+t] + red[192+t]) * (1.f/NT);
}

// --------- K8: pooled head ---------------------------------------------------
__global__ void k_headA(const float* __restrict__ p1, const float* __restrict__ abar,
                        const float* __restrict__ wo, const float* __restrict__ bo,
                        float* __restrict__ pv) {
  int b = blockIdx.x, cg = blockIdx.y;
  int t = threadIdx.x, w = t >> 6, ln = t & 63;
  float a[8];
  #pragma unroll
  for (int k = 0; k < 8; k++) a[k] = abar[b*CC + ln + 64*k];
  int c0 = cg*64 + w*16;
  for (int i = 0; i < 16; i++) {
    int c = c0 + i;
    const float* wr = wo + (size_t)c*CC;
    float s = 0.f;
    #pragma unroll
    for (int k = 0; k < 8; k++) s += a[k] * wr[ln + 64*k];
    for (int o = 32; o; o >>= 1) s += __shfl_down(s, o, 64);
    if (ln == 0) pv[b*CC + c] = s + bo[c] + p1[b*CC + c];
  }
}

// B+C fused: per-wave LN (redundant across waves) then fc1 row dots
__global__ void k_headC(const float* __restrict__ pv, const float* __restrict__ ln_g,
                        const float* __restrict__ ln_b, const float* __restrict__ fc1_w,
                        const float* __restrict__ fc1_b, float* __restrict__ h1) {
  int b = blockIdx.x, cg = blockIdx.y;
  int t = threadIdx.x, w = t >> 6, ln = t & 63;
  float a[8];
  float s = 0.f, s2 = 0.f;
  #pragma unroll
  for (int k = 0; k < 8; k++) {
    a[k] = pv[b*CC + ln + 64*k];
    s += a[k]; s2 += a[k]*a[k];
  }
  for (int o = 32; o; o >>= 1) { s += __shfl_down(s, o, 64); s2 += __shfl_down(s2, o, 64); }
  s = __shfl(s, 0, 64); s2 = __shfl(s2, 0, 64);
  float mean = s * (1.f/CC);
  float rs = rsqrtf(s2*(1.f/CC) - mean*mean + 1e-5f);
  #pragma unroll
  for (int k = 0; k < 8; k++)
    a[k] = (a[k]-mean)*rs*ln_g[ln + 64*k] + ln_b[ln + 64*k];
  int c0 = cg*64 + w*16;
  for (int i = 0; i < 16; i++) {
    int c = c0 + i;
    const float* wr = fc1_w + (size_t)c*CC;
    float v = 0.f;
    #pragma unroll
    for (int k = 0; k < 8; k++) v += a[k] * wr[ln + 64*k];
    for (int o = 32; o; o >>= 1) v += __shfl_down(v, o, 64);
    if (ln == 0) h1[b*CC + c] = fmaxf(v + fc1_b[c], 0.f);
  }
}

__global__ void k_headD(const float* __restrict__ h1, const float* __restrict__ fc2_w,
                        const float* __restrict__ fc2_b, float* __restrict__ out) {
  int b = blockIdx.x, ln = threadIdx.x;
  float s = 0.f;
  #pragma unroll
  for (int k = 0; k < 8; k++) s += h1[b*CC + ln + 64*k] * fc2_w[ln + 64*k];
  for (int o = 32; o; o >>= 1) s += __shfl_down(s, o, 64);
  if (ln == 0) out[b] = s + fc2_b[0];
}

extern "C" void kernel_launch(void* const* d_in, const int* in_sizes, int n_in,
                              void* d_out, int out_size, void* d_ws, size_t ws_size,
                              hipStream_t stream) {
  const float* x       = (const float*)d_in[0];
  const float* mlp_w1  = (const float*)d_in[1];
  const float* mlp_b1  = (const float*)d_in[2];
  const float* mlp_w2  = (const float*)d_in[3];
  const float* mlp_b2  = (const float*)d_in[4];
  const float* sp_w    = (const float*)d_in[5];
  const float* sp_g    = (const float*)d_in[6];
  const float* sp_b    = (const float*)d_in[7];
  const float* sp_mu   = (const float*)d_in[8];
  const float* sp_var  = (const float*)d_in[9];
  const float* wq      = (const float*)d_in[10];
  const float* bq      = (const float*)d_in[11];
  const float* wk      = (const float*)d_in[12];
  const float* bk      = (const float*)d_in[13];
  const float* wv      = (const float*)d_in[14];
  const float* bv      = (const float*)d_in[15];
  const float* wo      = (const float*)d_in[16];
  const float* bo      = (const float*)d_in[17];
  const float* ln_g    = (const float*)d_in[18];
  const float* ln_b    = (const float*)d_in[19];
  const float* fc1_w   = (const float*)d_in[20];
  const float* fc1_b   = (const float*)d_in[21];
  const float* fc2_w   = (const float*)d_in[22];
  const float* fc2_b   = (const float*)d_in[23];

  float* ws = (float*)d_ws;
  float* avg_p = ws + OFS_AVGP;
  float* max_p = ws + OFS_MAXP;
  float* chs   = ws + OFS_CHS;
  float* sp    = ws + OFS_SP;
  float* p1    = ws + OFS_P1;
  float* abar  = ws + OFS_ABAR;
  unsigned short* xgT = (unsigned short*)(ws + OFS_XGT);
  unsigned short* Qbf = (unsigned short*)(ws + OFS_QBF);
  unsigned short* Kbf = (unsigned short*)(ws + OFS_KBF);
  unsigned short* Vbf = (unsigned short*)(ws + OFS_V2);
  unsigned short* Wf  = (unsigned short*)(ws + OFS_WF);
  float* wsum  = ws + OFS_W;
  float* pv    = ws + OFS_PV;
  float* h1    = ws + OFS_H1;
  float* cmaxp = ws + OFS_CMAXP;
  float* cmeanp= ws + OFS_CMEANP;

  hipMemsetAsync(wsum, 0, BB*NHD*NT*sizeof(float), stream);

  k_pool   <<<2048, 256, 0, stream>>>(x, avg_p, max_p);
  k_chmlp  <<<BB, 256, 0, stream>>>(avg_p, max_p, mlp_w1, mlp_b1, mlp_w2, mlp_b2, chs);
  k_chgatep<<<dim3(BB,16), 256, 0, stream>>>(x, chs, cmaxp, cmeanp);
  k_credsp <<<BB, 256, 0, stream>>>(cmaxp, cmeanp, sp_w, sp_g, sp_b, sp_mu, sp_var, sp);
  k_wfrag  <<<384, 256, 0, stream>>>(wq, wk, wv, Wf);
  k_sfuse  <<<dim3(NTILE,BB), 256, 0, stream>>>(x, chs, sp, xgT);
  k_p1     <<<dim3(BB,16), 256, 0, stream>>>(xgT, p1);
  k_qkv_mfma<<<2496, 256, 0, stream>>>(xgT, Wf, bq, bk, bv, Qbf, Kbf, Vbf);
  k_attn7  <<<NTILE*128, 256, 0, stream>>>(Qbf, Kbf, wsum);
  k_attn_av<<<128, 256, 0, stream>>>(wsum, Vbf, abar);
  k_headA  <<<dim3(BB,8), 256, 0, stream>>>(p1, abar, wo, bo, pv);
  k_headC  <<<dim3(BB,8), 256, 0, stream>>>(pv, ln_g, ln_b, fc1_w, fc1_b, h1);
  k_headD  <<<BB, 64, 0, stream>>>(h1, fc2_w, fc2_b, (float*)d_out);
}

// Round 12
// 270.375 us; speedup vs baseline: 1.3192x; 1.0101x over previous
//
#include <hip/hip_runtime.h>
#include <math.h>

// Problem constants
#define BB 16
#define CC 512
#define HW 784
#define RR 32
#define NHD 8
#define HD 64
#define NT 784
#define NTILE 49                       // 784 = 49 * 16 n-tiles
#define CBS 132                        // Cb stride: writes 2-way (S%8==4), b128 reads uniform

// workspace layout (float offsets)
#define OFS_AVGP   0
#define OFS_MAXP   8192
#define OFS_CHS    16384
#define OFS_SP     49664
#define OFS_P1     62208
#define OFS_ABAR   70400
#define OFS_XG     78592
#define XG_SZ      (BB*CC*HW)          // 6,422,528 floats (region reused below)
#define OFS_XGT    (OFS_XG + XG_SZ)            // bf16 frag xg^T  (XG_SZ bf16)
#define OFS_QBF    (OFS_XGT + XG_SZ/2)         // bf16 frag Q     (XG_SZ bf16)
#define OFS_KBF    (OFS_QBF + XG_SZ/2)         // bf16 frag K     (XG_SZ bf16)
#define OFS_V2     (OFS_KBF + XG_SZ/2)         // bf16 V [bh][n][d]
#define OFS_WF     (OFS_V2 + XG_SZ)            // bf16 frag weights (786432 bf16)
// overlays inside the dead xg region:
#define OFS_W      OFS_XG                      // wsum   (100352 floats)
#define OFS_PV     (OFS_XG + 131072)           // pv     (8192)
#define OFS_H1     (OFS_PV + 8192)             // h1     (8192)
#define OFS_CMAXP  (OFS_XG + 262144)           // partial cmax [16][16][784]
#define OFS_CMEANP (OFS_CMAXP + 200704)        // partial csum [16][16][784]

typedef __attribute__((ext_vector_type(8))) short bf16x8;
typedef __attribute__((ext_vector_type(4))) float f32x4;

__device__ __forceinline__ unsigned short f2bf(float x) {
  union { float f; unsigned u; } v; v.f = x;
  unsigned r = v.u + 0x7fffu + ((v.u >> 16) & 1u);
  return (unsigned short)(r >> 16);
}
__device__ __forceinline__ float bf2f(unsigned short x) {
  union { unsigned u; float f; } v; v.u = ((unsigned)x) << 16;
  return v.f;
}
// async global->LDS, 16 B per lane; lds base must be wave-uniform (lane scatters x16B)
__device__ __forceinline__ void async16(const unsigned short* g, unsigned short* l) {
  __builtin_amdgcn_global_load_lds(
      (const __attribute__((address_space(1))) unsigned int*)g,
      (__attribute__((address_space(3))) unsigned int*)l, 16, 0, 0);
}

// ---------------- K1: per-(b,c) avg + max pooling over HW -------------------
__global__ void k_pool(const float* __restrict__ x, float* avg_p, float* max_p) {
  int wid = threadIdx.x >> 6;
  int lane = threadIdx.x & 63;
  int row = blockIdx.x * 4 + wid;                 // b*C + c, 8192 rows
  const float* xr = x + (size_t)row * HW;
  float s = 0.f, m = -INFINITY;
  for (int i = lane; i < HW; i += 64) { float v = xr[i]; s += v; m = fmaxf(m, v); }
  for (int o = 32; o; o >>= 1) { s += __shfl_down(s, o, 64); m = fmaxf(m, __shfl_down(m, o, 64)); }
  if (lane == 0) { avg_p[row] = s * (1.f/HW); max_p[row] = m; }
}

// ---------------- K2: channel-gate MLP, one block per batch -----------------
__global__ void k_chmlp(const float* avg_p, const float* max_p,
                        const float* w1, const float* b1,
                        const float* w2, const float* b2, float* chs) {
  __shared__ float pa[CC], pm[CC], part[256], hr[64];
  int b = blockIdx.x, t = threadIdx.x;
  for (int i = t; i < CC; i += 256) { pa[i] = avg_p[b*CC+i]; pm[i] = max_p[b*CC+i]; }
  __syncthreads();
  {
    int rp = t & 63, ch = t >> 6;
    int r = rp & 31;
    const float* src = (rp < 32) ? pa : pm;
    const float* wr = w1 + (size_t)r*CC + ch*128;
    float s = 0.f;
    #pragma unroll 8
    for (int c = 0; c < 128; c++) s += src[ch*128 + c] * wr[c];
    part[t] = s;
  }
  __syncthreads();
  if (t < 64)
    hr[t] = fmaxf(part[t] + part[64+t] + part[128+t] + part[192+t] + b1[t & 31], 0.f);
  __syncthreads();
  for (int c = t; c < CC; c += 256) {
    float a = 2.f*b2[c];                          // b2 added by both mlp() calls
    const float* wr = w2 + c*RR;
    #pragma unroll
    for (int r = 0; r < RR; r++) a += (hr[r]+hr[32+r])*wr[r];
    chs[b*CC+c] = 1.f/(1.f+__expf(-a));
  }
}

// ---- K3a: channel gate partials: per (b, 32-ch chunk) max/sum per pixel ----
__global__ void k_chgatep(const float* __restrict__ x, const float* __restrict__ chs,
                          float* __restrict__ cmaxp, float* __restrict__ cmeanp) {
  __shared__ float cs[32];
  int b = blockIdx.x, cg = blockIdx.y, t = threadIdx.x;
  if (t < 32) cs[t] = chs[b*CC + cg*32 + t];
  __syncthreads();
  const float* xb = x + ((size_t)b*CC + cg*32)*HW;
  for (int pix = t; pix < HW; pix += 256) {
    float mx = -INFINITY, sm = 0.f;
    #pragma unroll
    for (int c = 0; c < 32; c++) {
      float v = xb[(size_t)c*HW + pix] * cs[c];
      mx = fmaxf(mx, v); sm += v;
    }
    cmaxp[(size_t)(cg*BB + b)*HW + pix] = mx;
    cmeanp[(size_t)(cg*BB + b)*HW + pix] = sm;
  }
}

// ---- K3b+K4 fused: reduce partials (LDS) -> 7x7 conv + BN + sigmoid --------
__global__ void k_credsp(const float* __restrict__ cmaxp, const float* __restrict__ cmeanp,
                         const float* __restrict__ w, const float* g, const float* be,
                         const float* mu, const float* var, float* __restrict__ sp) {
  __shared__ float cmx[HW], cmn[HW];
  int b = blockIdx.x, t = threadIdx.x;
  for (int pix = t; pix < HW; pix += 256) {
    float mx = -INFINITY, sm = 0.f;
    #pragma unroll
    for (int cg = 0; cg < 16; cg++) {
      mx = fmaxf(mx, cmaxp[(size_t)(cg*BB + b)*HW + pix]);
      sm += cmeanp[(size_t)(cg*BB + b)*HW + pix];
    }
    cmx[pix] = mx; cmn[pix] = sm * (1.f/CC);
  }
  __syncthreads();
  float bnscale = rsqrtf(var[0]+1e-5f)*g[0];
  for (int pix = t; pix < HW; pix += 256) {
    int h = pix/28, wd = pix%28;
    float acc = 0.f;
    for (int kh = 0; kh < 7; kh++) {
      int ih = h + kh - 3; if (ih < 0 || ih >= 28) continue;
      for (int kw = 0; kw < 7; kw++) {
        int iw = wd + kw - 3; if (iw < 0 || iw >= 28) continue;
        int ip = ih*28+iw;
        acc += cmx[ip]*w[kh*7+kw] + cmn[ip]*w[49+kh*7+kw];
      }
    }
    float s = (acc - mu[0])*bnscale + be[0];
    sp[b*HW+pix] = 1.f/(1.f+__expf(-s));
  }
}

// ---- K5: fused gates -> fragment-ready bf16 xgT (no p1 here) ---------------
__global__ void k_sfuse(const float* __restrict__ x, const float* __restrict__ chs,
                        const float* __restrict__ sp, unsigned short* __restrict__ xgT) {
  __shared__ float cs[CC];
  int nt = blockIdx.x, b = blockIdx.y;
  int t = threadIdx.x, ln = t & 63;
  for (int i = t; i < CC; i += 256) cs[i] = chs[b*CC+i];
  __syncthreads();
  int n = nt*16 + (ln & 15);
  float spv = sp[b*HW + n];
  const float* xb = x + (size_t)b*CC*HW;
  #pragma unroll
  for (int i = 0; i < 4; i++) {
    int s = (t >> 6) + 4*i;
    int c = s*32 + (ln >> 4)*8;
    bf16x8 p;
    #pragma unroll
    for (int j = 0; j < 8; j++)
      p[j] = (short)f2bf(xb[(size_t)(c+j)*HW + n] * cs[c+j] * spv);
    *(bf16x8*)(xgT + ((((size_t)b*NTILE + nt)*16 + s)*64 + ln)*8) = p;
  }
}

// ---- K5b: p1[b][c] = mean_n xgT (from bf16 fragments, coalesced b128) ------
__global__ void k_p1(const unsigned short* __restrict__ xgT, float* __restrict__ p1) {
  __shared__ float red[4][32];
  int b = blockIdx.x, s = blockIdx.y;
  int t = threadIdx.x, w = t >> 6, ln = t & 63;
  float acc[8] = {0.f,0.f,0.f,0.f,0.f,0.f,0.f,0.f};
  for (int nt = w; nt < NTILE; nt += 4) {
    bf16x8 p = *(const bf16x8*)(xgT + ((((size_t)b*NTILE + nt)*16 + s)*64 + ln)*8);
    #pragma unroll
    for (int j = 0; j < 8; j++) acc[j] += bf2f((unsigned short)p[j]);
  }
  #pragma unroll
  for (int j = 0; j < 8; j++) {
    float v = acc[j];
    v += __shfl_xor(v,1,64); v += __shfl_xor(v,2,64);
    v += __shfl_xor(v,4,64); v += __shfl_xor(v,8,64);
    if ((ln & 15) == 0) red[w][(ln>>4)*8 + j] = v;
  }
  __syncthreads();
  if (t < 32)
    p1[b*CC + s*32 + t] = (red[0][t]+red[1][t]+red[2][t]+red[3][t]) * (1.f/HW);
}

// ---- K5c: reformat wq/wk/wv into fragment-ready bf16 ----------------------
__global__ void k_wfrag(const float* __restrict__ wq, const float* __restrict__ wk,
                        const float* __restrict__ wv, unsigned short* __restrict__ Wf) {
  int idx = blockIdx.x*256 + threadIdx.x;         // 98304 chunks
  int ln = idx & 63;
  int s  = (idx >> 6) & 15;
  int ct = (idx >> 10) & 31;
  int mat = idx >> 15;
  const float* W = (mat==0)? wq : (mat==1)? wk : wv;
  const float* src = W + (size_t)(ct*16 + (ln & 15))*CC + s*32 + (ln >> 4)*8;
  float4 f0 = *(const float4*)src;
  float4 f1 = *(const float4*)(src + 4);
  bf16x8 p;
  p[0]=(short)f2bf(f0.x); p[1]=(short)f2bf(f0.y); p[2]=(short)f2bf(f0.z); p[3]=(short)f2bf(f0.w);
  p[4]=(short)f2bf(f1.x); p[5]=(short)f2bf(f1.y); p[6]=(short)f2bf(f1.z); p[7]=(short)f2bf(f1.w);
  *(bf16x8*)(Wf + (size_t)idx*8) = p;
}

// ---------------- K6: QKV projection — A staged in LDS, barrier-free K-loop -
// 1-D grid, XCD-swizzled: blk = yb*208 + (mt*16 + b); A-panel fetched from L2
// ONCE per block via global_load_lds (16B/lane, wave-uniform base), then the
// K-loop reads A via ds_read_b128 and only streams B from L2.
__global__ __launch_bounds__(256) void k_qkv_mfma(
    const unsigned short* __restrict__ xgT, const unsigned short* __restrict__ Wf,
    const float* __restrict__ bq, const float* __restrict__ bk, const float* __restrict__ bv,
    unsigned short* __restrict__ Qbf, unsigned short* __restrict__ Kbf,
    unsigned short* __restrict__ Vbf) {
  __shared__ __align__(16) unsigned char smem[65536];   // A-stage (64 KB) / Cb union
  unsigned short* Alds = (unsigned short*)smem;
  float* Cb = (float*)smem;                             // reused after K-loop (33.8 KB)
  int blk = blockIdx.x;
  int yb = blk / 208;                             // 0..11: mat=yb>>2, c0=(yb&3)*128
  int r0 = blk % 208;
  int mt = r0 >> 4;                               // 0..12: n-tiles 4mt..4mt+3
  int b  = r0 & 15;
  int mat = yb >> 2;
  int c0 = (yb & 3) * 128;
  int t = threadIdx.x, w = t >> 6, ln = t & 63;
  const unsigned short* Ab = xgT + (size_t)b*NTILE*8192;
  const unsigned short* Bb = Wf + (size_t)mat*32*8192;
  int ctg0 = (c0 >> 4) + w*2;
  int ntc[4];
  #pragma unroll
  for (int m = 0; m < 4; m++) { int nt = 4*mt + m; ntc[m] = (nt > 48) ? 48 : nt; }
  // ---- stage A: 4096 chunks x 16 B; chunk (j*64+ln) -> LDS halfs (j*64+ln)*8
  #pragma unroll
  for (int j0 = 0; j0 < 16; j0++) {
    int j = w + 4*j0;                             // uniform per wave-iteration
    int m = j >> 4, sj = j & 15;
    async16(Ab + (size_t)ntc[m]*8192 + (size_t)(sj*64 + ln)*8,
            Alds + (size_t)j*512);
  }
  f32x4 acc[4][2];
  #pragma unroll
  for (int m = 0; m < 4; m++)
    #pragma unroll
    for (int c2 = 0; c2 < 2; c2++) acc[m][c2] = (f32x4){0.f,0.f,0.f,0.f};
  __syncthreads();                                // drain staging (vmcnt) + barrier
  #pragma unroll 2
  for (int s = 0; s < 16; s++) {
    bf16x8 bf0 = *(const bf16x8*)(Bb + (size_t)(ctg0*16 + s)*512 + ln*8);
    bf16x8 bf1 = *(const bf16x8*)(Bb + (size_t)((ctg0+1)*16 + s)*512 + ln*8);
    bf16x8 af[4];
    #pragma unroll
    for (int m = 0; m < 4; m++)
      af[m] = *(const bf16x8*)(Alds + (size_t)(m*16 + s)*512 + ln*8);  // ds_read_b128
    #pragma unroll
    for (int m = 0; m < 4; m++) {
      acc[m][0] = __builtin_amdgcn_mfma_f32_16x16x32_bf16(af[m], bf0, acc[m][0], 0,0,0);
      acc[m][1] = __builtin_amdgcn_mfma_f32_16x16x32_bf16(af[m], bf1, acc[m][1], 0,0,0);
    }
  }
  __syncthreads();                                // A reads done; reuse LDS as Cb
  #pragma unroll
  for (int m = 0; m < 4; m++)
    #pragma unroll
    for (int c2 = 0; c2 < 2; c2++)
      #pragma unroll
      for (int r = 0; r < 4; r++)
        Cb[(m*16 + (ln>>4)*4 + r)*CBS + w*32 + c2*16 + (ln&15)] = acc[m][c2][r];
  __syncthreads();
  const float* bias = (mat==0)? bq : (mat==1)? bk : bv;
  #pragma unroll
  for (int i = 0; i < 4; i++) {
    int p = w*4 + i;                              // 16 (ntl, sl) pairs
    int ntl = p >> 2, sl = p & 3;
    int nt = 4*mt + ntl;
    if (nt > 48) continue;
    int row = ntl*16 + (ln & 15);
    int col = sl*32 + (ln >> 4)*8;
    float4 v0 = *(const float4*)&Cb[row*CBS + col];      // b128: uniform banks
    float4 v1 = *(const float4*)&Cb[row*CBS + col + 4];
    float v[8] = {v0.x, v0.y, v0.z, v0.w, v1.x, v1.y, v1.z, v1.w};
    #pragma unroll
    for (int j = 0; j < 8; j++) v[j] += bias[c0 + col + j];
    int token = nt*16 + (ln & 15);
    int h = (c0 >> 6) + (sl >> 1);
    int bh = b*NHD + h;
    bf16x8 pk;
    #pragma unroll
    for (int j = 0; j < 8; j++) pk[j] = (short)f2bf(v[j]);
    if (mat < 2) {
      unsigned short* Out = (mat == 0) ? Qbf : Kbf;
      *(bf16x8*)(Out + ((size_t)bh*NTILE + nt)*1024 + (size_t)(sl & 1)*512 + ln*8) = pk;
    } else {
      int d = (sl & 1)*32 + (ln >> 4)*8;
      *(bf16x8*)(Vbf + ((size_t)bh*NT + token)*HD + d) = pk;
    }
  }
}

// ---------------- K7: single-pass MFMA attention, e in registers ------------
__global__ __launch_bounds__(256, 4) void k_attn7(const unsigned short* __restrict__ Qbf,
    const unsigned short* __restrict__ Kbf, float* __restrict__ wsum) {
  __shared__ float l_tmp[64];
  __shared__ float rl[16];
  int bh = blockIdx.x & 127, nt = blockIdx.x >> 7;
  int t = threadIdx.x, w = t >> 6, ln = t & 63;
  const unsigned short* Qb = Qbf + ((size_t)bh*NTILE + nt)*1024;
  const unsigned short* Kb = Kbf + (size_t)bh*NTILE*1024;
  bf16x8 q0 = *(const bf16x8*)(Qb + ln*8);
  bf16x8 q1 = *(const bf16x8*)(Qb + 512 + ln*8);
  f32x4 ev[13];
  float lp[4] = {0.f,0.f,0.f,0.f};
  #pragma unroll
  for (int i = 0; i < 13; i++) {
    int mt = w + 4*i;
    bool valid = (i < 12) || (w == 0);            // only w==0 has a 13th tile
    int mtc = valid ? mt : 48;
    bf16x8 k0 = *(const bf16x8*)(Kb + (size_t)mtc*1024 + ln*8);
    bf16x8 k1 = *(const bf16x8*)(Kb + (size_t)mtc*1024 + 512 + ln*8);
    f32x4 a = {0.f,0.f,0.f,0.f};
    a = __builtin_amdgcn_mfma_f32_16x16x32_bf16(q0, k0, a, 0,0,0);
    a = __builtin_amdgcn_mfma_f32_16x16x32_bf16(q1, k1, a, 0,0,0);
    f32x4 e;
    #pragma unroll
    for (int r = 0; r < 4; r++) e[r] = __expf(a[r]*0.125f);  // n=(ln>>4)*4+r, m-col=ln&15
    ev[i] = e;
    if (valid) {
      #pragma unroll
      for (int r = 0; r < 4; r++) lp[r] += e[r];
    }
  }
  #pragma unroll
  for (int r = 0; r < 4; r++) {
    float v = lp[r];
    v += __shfl_xor(v,1,64); v += __shfl_xor(v,2,64);
    v += __shfl_xor(v,4,64); v += __shfl_xor(v,8,64);
    if ((ln & 15) == 0) l_tmp[w*16 + (ln>>4)*4 + r] = v;
  }
  __syncthreads();
  if (t < 16) rl[t] = 1.f / (l_tmp[t] + l_tmp[16+t] + l_tmp[32+t] + l_tmp[48+t]);
  __syncthreads();
  f32x4 rlq = *(const f32x4*)&rl[(ln >> 4)*4];    // this lane's 4 n-rows
  #pragma unroll
  for (int i = 0; i < 13; i++) {
    int mt = w + 4*i;
    bool valid = (i < 12) || (w == 0);
    float v = ev[i][0]*rlq[0] + ev[i][1]*rlq[1] + ev[i][2]*rlq[2] + ev[i][3]*rlq[3];
    v += __shfl_xor(v, 16, 64);                   // sum over the 4 n-quads
    v += __shfl_xor(v, 32, 64);
    if (valid && ln < 16)
      atomicAdd(&wsum[bh*NT + mt*16 + ln], v);
  }
}

// ---- K7c: abar[bh,d] = (1/N) sum_m w_m V[m,d] (V bf16) ---------------------
__global__ void k_attn_av(const float* __restrict__ w, const unsigned short* __restrict__ Vm,
                          float* __restrict__ abar) {
  __shared__ float red[256];
  int bh = blockIdx.x, t = threadIdx.x;
  int d = t & 63, chunk = t >> 6;                 // 4 chunks of 196 keys
  float acc = 0.f;
  const unsigned short* vb = Vm + (size_t)bh*NT*HD;
  const float* wb = w + bh*NT;
  for (int m = chunk*196; m < (chunk+1)*196; m++)
    acc += wb[m] * bf2f(vb[(size_t)m*HD + d]);
  red[t] = acc;
  __syncthreads();
  if (t < 64)
    abar[bh*HD + t] = (red[t] + red[64+t] + red[128+t] + red[192+t]) * (1.f/NT);
}

// --------- K8: pooled head ---------------------------------------------------
__global__ void k_headA(const float* __restrict__ p1, const float* __restrict__ abar,
                        const float* __restrict__ wo, const float* __restrict__ bo,
                        float* __restrict__ pv) {
  int b = blockIdx.x, cg = blockIdx.y;
  int t = threadIdx.x, w = t >> 6, ln = t & 63;
  float a[8];
  #pragma unroll
  for (int k = 0; k < 8; k++) a[k] = abar[b*CC + ln + 64*k];
  int c0 = cg*64 + w*16;
  for (int i = 0; i < 16; i++) {
    int c = c0 + i;
    const float* wr = wo + (size_t)c*CC;
    float s = 0.f;
    #pragma unroll
    for (int k = 0; k < 8; k++) s += a[k] * wr[ln + 64*k];
    for (int o = 32; o; o >>= 1) s += __shfl_down(s, o, 64);
    if (ln == 0) pv[b*CC + c] = s + bo[c] + p1[b*CC + c];
  }
}

// B+C fused: per-wave LN (redundant across waves) then fc1 row dots
__global__ void k_headC(const float* __restrict__ pv, const float* __restrict__ ln_g,
                        const float* __restrict__ ln_b, const float* __restrict__ fc1_w,
                        const float* __restrict__ fc1_b, float* __restrict__ h1) {
  int b = blockIdx.x, cg = blockIdx.y;
  int t = threadIdx.x, w = t >> 6, ln = t & 63;
  float a[8];
  float s = 0.f, s2 = 0.f;
  #pragma unroll
  for (int k = 0; k < 8; k++) {
    a[k] = pv[b*CC + ln + 64*k];
    s += a[k]; s2 += a[k]*a[k];
  }
  for (int o = 32; o; o >>= 1) { s += __shfl_down(s, o, 64); s2 += __shfl_down(s2, o, 64); }
  s = __shfl(s, 0, 64); s2 = __shfl(s2, 0, 64);
  float mean = s * (1.f/CC);
  float rs = rsqrtf(s2*(1.f/CC) - mean*mean + 1e-5f);
  #pragma unroll
  for (int k = 0; k < 8; k++)
    a[k] = (a[k]-mean)*rs*ln_g[ln + 64*k] + ln_b[ln + 64*k];
  int c0 = cg*64 + w*16;
  for (int i = 0; i < 16; i++) {
    int c = c0 + i;
    const float* wr = fc1_w + (size_t)c*CC;
    float v = 0.f;
    #pragma unroll
    for (int k = 0; k < 8; k++) v += a[k] * wr[ln + 64*k];
    for (int o = 32; o; o >>= 1) v += __shfl_down(v, o, 64);
    if (ln == 0) h1[b*CC + c] = fmaxf(v + fc1_b[c], 0.f);
  }
}

__global__ void k_headD(const float* __restrict__ h1, const float* __restrict__ fc2_w,
                        const float* __restrict__ fc2_b, float* __restrict__ out) {
  int b = blockIdx.x, ln = threadIdx.x;
  float s = 0.f;
  #pragma unroll
  for (int k = 0; k < 8; k++) s += h1[b*CC + ln + 64*k] * fc2_w[ln + 64*k];
  for (int o = 32; o; o >>= 1) s += __shfl_down(s, o, 64);
  if (ln == 0) out[b] = s + fc2_b[0];
}

extern "C" void kernel_launch(void* const* d_in, const int* in_sizes, int n_in,
                              void* d_out, int out_size, void* d_ws, size_t ws_size,
                              hipStream_t stream) {
  const float* x       = (const float*)d_in[0];
  const float* mlp_w1  = (const float*)d_in[1];
  const float* mlp_b1  = (const float*)d_in[2];
  const float* mlp_w2  = (const float*)d_in[3];
  const float* mlp_b2  = (const float*)d_in[4];
  const float* sp_w    = (const float*)d_in[5];
  const float* sp_g    = (const float*)d_in[6];
  const float* sp_b    = (const float*)d_in[7];
  const float* sp_mu   = (const float*)d_in[8];
  const float* sp_var  = (const float*)d_in[9];
  const float* wq      = (const float*)d_in[10];
  const float* bq      = (const float*)d_in[11];
  const float* wk      = (const float*)d_in[12];
  const float* bk      = (const float*)d_in[13];
  const float* wv      = (const float*)d_in[14];
  const float* bv      = (const float*)d_in[15];
  const float* wo      = (const float*)d_in[16];
  const float* bo      = (const float*)d_in[17];
  const float* ln_g    = (const float*)d_in[18];
  const float* ln_b    = (const float*)d_in[19];
  const float* fc1_w   = (const float*)d_in[20];
  const float* fc1_b   = (const float*)d_in[21];
  const float* fc2_w   = (const float*)d_in[22];
  const float* fc2_b   = (const float*)d_in[23];

  float* ws = (float*)d_ws;
  float* avg_p = ws + OFS_AVGP;
  float* max_p = ws + OFS_MAXP;
  float* chs   = ws + OFS_CHS;
  float* sp    = ws + OFS_SP;
  float* p1    = ws + OFS_P1;
  float* abar  = ws + OFS_ABAR;
  unsigned short* xgT = (unsigned short*)(ws + OFS_XGT);
  unsigned short* Qbf = (unsigned short*)(ws + OFS_QBF);
  unsigned short* Kbf = (unsigned short*)(ws + OFS_KBF);
  unsigned short* Vbf = (unsigned short*)(ws + OFS_V2);
  unsigned short* Wf  = (unsigned short*)(ws + OFS_WF);
  float* wsum  = ws + OFS_W;
  float* pv    = ws + OFS_PV;
  float* h1    = ws + OFS_H1;
  float* cmaxp = ws + OFS_CMAXP;
  float* cmeanp= ws + OFS_CMEANP;

  hipMemsetAsync(wsum, 0, BB*NHD*NT*sizeof(float), stream);

  k_pool   <<<2048, 256, 0, stream>>>(x, avg_p, max_p);
  k_chmlp  <<<BB, 256, 0, stream>>>(avg_p, max_p, mlp_w1, mlp_b1, mlp_w2, mlp_b2, chs);
  k_chgatep<<<dim3(BB,16), 256, 0, stream>>>(x, chs, cmaxp, cmeanp);
  k_credsp <<<BB, 256, 0, stream>>>(cmaxp, cmeanp, sp_w, sp_g, sp_b, sp_mu, sp_var, sp);
  k_wfrag  <<<384, 256, 0, stream>>>(wq, wk, wv, Wf);
  k_sfuse  <<<dim3(NTILE,BB), 256, 0, stream>>>(x, chs, sp, xgT);
  k_p1     <<<dim3(BB,16), 256, 0, stream>>>(xgT, p1);
  k_qkv_mfma<<<2496, 256, 0, stream>>>(xgT, Wf, bq, bk, bv, Qbf, Kbf, Vbf);
  k_attn7  <<<NTILE*128, 256, 0, stream>>>(Qbf, Kbf, wsum);
  k_attn_av<<<128, 256, 0, stream>>>(wsum, Vbf, abar);
  k_headA  <<<dim3(BB,8), 256, 0, stream>>>(p1, abar, wo, bo, pv);
  k_headC  <<<dim3(BB,8), 256, 0, stream>>>(pv, ln_g, ln_b, fc1_w, fc1_b, h1);
  k_headD  <<<BB, 64, 0, stream>>>(h1, fc2_w, fc2_b, (float*)d_out);
}

// Round 13
// 268.981 us; speedup vs baseline: 1.3261x; 1.0052x over previous
//
#include <hip/hip_runtime.h>
#include <math.h>

// Problem constants
#define BB 16
#define CC 512
#define HW 784
#define RR 32
#define NHD 8
#define HD 64
#define NT 784
#define NTILE 49                       // 784 = 49 * 16 n-tiles
#define CBS 132                        // Cb stride: writes 2-way (S%8==4), b128 reads uniform

// workspace layout (float offsets)
#define OFS_AVGP   0
#define OFS_MAXP   8192
#define OFS_CHS    16384
#define OFS_SP     49664
#define OFS_P1     62208
#define OFS_ABAR   70400
#define OFS_XG     78592
#define XG_SZ      (BB*CC*HW)          // 6,422,528 floats (region reused below)
#define OFS_XGT    (OFS_XG + XG_SZ)            // bf16 frag xg^T  (XG_SZ bf16)
#define OFS_QBF    (OFS_XGT + XG_SZ/2)         // bf16 frag Q     (XG_SZ bf16)
#define OFS_KBF    (OFS_QBF + XG_SZ/2)         // bf16 frag K     (XG_SZ bf16)
#define OFS_V2     (OFS_KBF + XG_SZ/2)         // bf16 V [bh][n][d]
#define OFS_WF     (OFS_V2 + XG_SZ)            // bf16 frag weights (786432 bf16)
// overlays inside the dead xg region:
#define OFS_W      OFS_XG                      // wsum   (100352 floats)
#define OFS_PV     (OFS_XG + 131072)           // pv     (8192)
#define OFS_H1     (OFS_PV + 8192)             // h1     (8192)
#define OFS_CMAXP  (OFS_XG + 262144)           // partial cmax [16][16][784]
#define OFS_CMEANP (OFS_CMAXP + 200704)        // partial csum [16][16][784]

typedef __attribute__((ext_vector_type(8))) short bf16x8;
typedef __attribute__((ext_vector_type(4))) float f32x4;

__device__ __forceinline__ unsigned short f2bf(float x) {
  union { float f; unsigned u; } v; v.f = x;
  unsigned r = v.u + 0x7fffu + ((v.u >> 16) & 1u);
  return (unsigned short)(r >> 16);
}
__device__ __forceinline__ float bf2f(unsigned short x) {
  union { unsigned u; float f; } v; v.u = ((unsigned)x) << 16;
  return v.f;
}
// async global->LDS, 16 B per lane; lds base must be wave-uniform (lane scatters x16B)
__device__ __forceinline__ void async16(const unsigned short* g, unsigned short* l) {
  __builtin_amdgcn_global_load_lds(
      (const __attribute__((address_space(1))) unsigned int*)g,
      (__attribute__((address_space(3))) unsigned int*)l, 16, 0, 0);
}

// ---------------- K1: per-(b,c) avg + max pooling over HW -------------------
__global__ void k_pool(const float* __restrict__ x, float* avg_p, float* max_p) {
  int wid = threadIdx.x >> 6;
  int lane = threadIdx.x & 63;
  int row = blockIdx.x * 4 + wid;                 // b*C + c, 8192 rows
  const float* xr = x + (size_t)row * HW;
  float s = 0.f, m = -INFINITY;
  for (int i = lane; i < HW; i += 64) { float v = xr[i]; s += v; m = fmaxf(m, v); }
  for (int o = 32; o; o >>= 1) { s += __shfl_down(s, o, 64); m = fmaxf(m, __shfl_down(m, o, 64)); }
  if (lane == 0) { avg_p[row] = s * (1.f/HW); max_p[row] = m; }
}

// ---------------- K2: channel-gate MLP, one block per batch -----------------
__global__ void k_chmlp(const float* avg_p, const float* max_p,
                        const float* w1, const float* b1,
                        const float* w2, const float* b2, float* chs) {
  __shared__ float pa[CC], pm[CC], part[256], hr[64];
  int b = blockIdx.x, t = threadIdx.x;
  for (int i = t; i < CC; i += 256) { pa[i] = avg_p[b*CC+i]; pm[i] = max_p[b*CC+i]; }
  __syncthreads();
  {
    int rp = t & 63, ch = t >> 6;
    int r = rp & 31;
    const float* src = (rp < 32) ? pa : pm;
    const float* wr = w1 + (size_t)r*CC + ch*128;
    float s = 0.f;
    #pragma unroll 8
    for (int c = 0; c < 128; c++) s += src[ch*128 + c] * wr[c];
    part[t] = s;
  }
  __syncthreads();
  if (t < 64)
    hr[t] = fmaxf(part[t] + part[64+t] + part[128+t] + part[192+t] + b1[t & 31], 0.f);
  __syncthreads();
  for (int c = t; c < CC; c += 256) {
    float a = 2.f*b2[c];                          // b2 added by both mlp() calls
    const float* wr = w2 + c*RR;
    #pragma unroll
    for (int r = 0; r < RR; r++) a += (hr[r]+hr[32+r])*wr[r];
    chs[b*CC+c] = 1.f/(1.f+__expf(-a));
  }
}

// ---- K3a: channel gate partials: per (b, 32-ch chunk) max/sum per pixel ----
__global__ void k_chgatep(const float* __restrict__ x, const float* __restrict__ chs,
                          float* __restrict__ cmaxp, float* __restrict__ cmeanp) {
  __shared__ float cs[32];
  int b = blockIdx.x, cg = blockIdx.y, t = threadIdx.x;
  if (t < 32) cs[t] = chs[b*CC + cg*32 + t];
  __syncthreads();
  const float* xb = x + ((size_t)b*CC + cg*32)*HW;
  for (int pix = t; pix < HW; pix += 256) {
    float mx = -INFINITY, sm = 0.f;
    #pragma unroll
    for (int c = 0; c < 32; c++) {
      float v = xb[(size_t)c*HW + pix] * cs[c];
      mx = fmaxf(mx, v); sm += v;
    }
    cmaxp[(size_t)(cg*BB + b)*HW + pix] = mx;
    cmeanp[(size_t)(cg*BB + b)*HW + pix] = sm;
  }
}

// ---- K3b+K4 fused: reduce partials (LDS) -> 7x7 conv + BN + sigmoid --------
__global__ void k_credsp(const float* __restrict__ cmaxp, const float* __restrict__ cmeanp,
                         const float* __restrict__ w, const float* g, const float* be,
                         const float* mu, const float* var, float* __restrict__ sp) {
  __shared__ float cmx[HW], cmn[HW];
  int b = blockIdx.x, t = threadIdx.x;
  for (int pix = t; pix < HW; pix += 256) {
    float mx = -INFINITY, sm = 0.f;
    #pragma unroll
    for (int cg = 0; cg < 16; cg++) {
      mx = fmaxf(mx, cmaxp[(size_t)(cg*BB + b)*HW + pix]);
      sm += cmeanp[(size_t)(cg*BB + b)*HW + pix];
    }
    cmx[pix] = mx; cmn[pix] = sm * (1.f/CC);
  }
  __syncthreads();
  float bnscale = rsqrtf(var[0]+1e-5f)*g[0];
  for (int pix = t; pix < HW; pix += 256) {
    int h = pix/28, wd = pix%28;
    float acc = 0.f;
    for (int kh = 0; kh < 7; kh++) {
      int ih = h + kh - 3; if (ih < 0 || ih >= 28) continue;
      for (int kw = 0; kw < 7; kw++) {
        int iw = wd + kw - 3; if (iw < 0 || iw >= 28) continue;
        int ip = ih*28+iw;
        acc += cmx[ip]*w[kh*7+kw] + cmn[ip]*w[49+kh*7+kw];
      }
    }
    float s = (acc - mu[0])*bnscale + be[0];
    sp[b*HW+pix] = 1.f/(1.f+__expf(-s));
  }
}

// ---- K5: fused gates -> fragment-ready bf16 xgT (no p1 here) ---------------
__global__ void k_sfuse(const float* __restrict__ x, const float* __restrict__ chs,
                        const float* __restrict__ sp, unsigned short* __restrict__ xgT) {
  __shared__ float cs[CC];
  int nt = blockIdx.x, b = blockIdx.y;
  int t = threadIdx.x, ln = t & 63;
  for (int i = t; i < CC; i += 256) cs[i] = chs[b*CC+i];
  __syncthreads();
  int n = nt*16 + (ln & 15);
  float spv = sp[b*HW + n];
  const float* xb = x + (size_t)b*CC*HW;
  #pragma unroll
  for (int i = 0; i < 4; i++) {
    int s = (t >> 6) + 4*i;
    int c = s*32 + (ln >> 4)*8;
    bf16x8 p;
    #pragma unroll
    for (int j = 0; j < 8; j++)
      p[j] = (short)f2bf(xb[(size_t)(c+j)*HW + n] * cs[c+j] * spv);
    *(bf16x8*)(xgT + ((((size_t)b*NTILE + nt)*16 + s)*64 + ln)*8) = p;
  }
}

// ---- K5b: p1[b][c] = mean_n xgT (from bf16 fragments, coalesced b128) ------
__global__ void k_p1(const unsigned short* __restrict__ xgT, float* __restrict__ p1) {
  __shared__ float red[4][32];
  int b = blockIdx.x, s = blockIdx.y;
  int t = threadIdx.x, w = t >> 6, ln = t & 63;
  float acc[8] = {0.f,0.f,0.f,0.f,0.f,0.f,0.f,0.f};
  for (int nt = w; nt < NTILE; nt += 4) {
    bf16x8 p = *(const bf16x8*)(xgT + ((((size_t)b*NTILE + nt)*16 + s)*64 + ln)*8);
    #pragma unroll
    for (int j = 0; j < 8; j++) acc[j] += bf2f((unsigned short)p[j]);
  }
  #pragma unroll
  for (int j = 0; j < 8; j++) {
    float v = acc[j];
    v += __shfl_xor(v,1,64); v += __shfl_xor(v,2,64);
    v += __shfl_xor(v,4,64); v += __shfl_xor(v,8,64);
    if ((ln & 15) == 0) red[w][(ln>>4)*8 + j] = v;
  }
  __syncthreads();
  if (t < 32)
    p1[b*CC + s*32 + t] = (red[0][t]+red[1][t]+red[2][t]+red[3][t]) * (1.f/HW);
}

// ---- K5c: reformat wq/wk/wv into fragment-ready bf16 ----------------------
__global__ void k_wfrag(const float* __restrict__ wq, const float* __restrict__ wk,
                        const float* __restrict__ wv, unsigned short* __restrict__ Wf) {
  int idx = blockIdx.x*256 + threadIdx.x;         // 98304 chunks
  int ln = idx & 63;
  int s  = (idx >> 6) & 15;
  int ct = (idx >> 10) & 31;
  int mat = idx >> 15;
  const float* W = (mat==0)? wq : (mat==1)? wk : wv;
  const float* src = W + (size_t)(ct*16 + (ln & 15))*CC + s*32 + (ln >> 4)*8;
  float4 f0 = *(const float4*)src;
  float4 f1 = *(const float4*)(src + 4);
  bf16x8 p;
  p[0]=(short)f2bf(f0.x); p[1]=(short)f2bf(f0.y); p[2]=(short)f2bf(f0.z); p[3]=(short)f2bf(f0.w);
  p[4]=(short)f2bf(f1.x); p[5]=(short)f2bf(f1.y); p[6]=(short)f2bf(f1.z); p[7]=(short)f2bf(f1.w);
  *(bf16x8*)(Wf + (size_t)idx*8) = p;
}

// ---------------- K6: QKV projection — A staged in LDS, barrier-free K-loop -
__global__ __launch_bounds__(256) void k_qkv_mfma(
    const unsigned short* __restrict__ xgT, const unsigned short* __restrict__ Wf,
    const float* __restrict__ bq, const float* __restrict__ bk, const float* __restrict__ bv,
    unsigned short* __restrict__ Qbf, unsigned short* __restrict__ Kbf,
    unsigned short* __restrict__ Vbf) {
  __shared__ __align__(16) unsigned char smem[65536];   // A-stage (64 KB) / Cb union
  unsigned short* Alds = (unsigned short*)smem;
  float* Cb = (float*)smem;                             // reused after K-loop (33.8 KB)
  int blk = blockIdx.x;
  int yb = blk / 208;                             // 0..11: mat=yb>>2, c0=(yb&3)*128
  int r0 = blk % 208;
  int mt = r0 >> 4;                               // 0..12: n-tiles 4mt..4mt+3
  int b  = r0 & 15;
  int mat = yb >> 2;
  int c0 = (yb & 3) * 128;
  int t = threadIdx.x, w = t >> 6, ln = t & 63;
  const unsigned short* Ab = xgT + (size_t)b*NTILE*8192;
  const unsigned short* Bb = Wf + (size_t)mat*32*8192;
  int ctg0 = (c0 >> 4) + w*2;
  int ntc[4];
  #pragma unroll
  for (int m = 0; m < 4; m++) { int nt = 4*mt + m; ntc[m] = (nt > 48) ? 48 : nt; }
  #pragma unroll
  for (int j0 = 0; j0 < 16; j0++) {
    int j = w + 4*j0;                             // uniform per wave-iteration
    int m = j >> 4, sj = j & 15;
    async16(Ab + (size_t)ntc[m]*8192 + (size_t)(sj*64 + ln)*8,
            Alds + (size_t)j*512);
  }
  f32x4 acc[4][2];
  #pragma unroll
  for (int m = 0; m < 4; m++)
    #pragma unroll
    for (int c2 = 0; c2 < 2; c2++) acc[m][c2] = (f32x4){0.f,0.f,0.f,0.f};
  __syncthreads();                                // drain staging (vmcnt) + barrier
  #pragma unroll 2
  for (int s = 0; s < 16; s++) {
    bf16x8 bf0 = *(const bf16x8*)(Bb + (size_t)(ctg0*16 + s)*512 + ln*8);
    bf16x8 bf1 = *(const bf16x8*)(Bb + (size_t)((ctg0+1)*16 + s)*512 + ln*8);
    bf16x8 af[4];
    #pragma unroll
    for (int m = 0; m < 4; m++)
      af[m] = *(const bf16x8*)(Alds + (size_t)(m*16 + s)*512 + ln*8);  // ds_read_b128
    #pragma unroll
    for (int m = 0; m < 4; m++) {
      acc[m][0] = __builtin_amdgcn_mfma_f32_16x16x32_bf16(af[m], bf0, acc[m][0], 0,0,0);
      acc[m][1] = __builtin_amdgcn_mfma_f32_16x16x32_bf16(af[m], bf1, acc[m][1], 0,0,0);
    }
  }
  __syncthreads();                                // A reads done; reuse LDS as Cb
  #pragma unroll
  for (int m = 0; m < 4; m++)
    #pragma unroll
    for (int c2 = 0; c2 < 2; c2++)
      #pragma unroll
      for (int r = 0; r < 4; r++)
        Cb[(m*16 + (ln>>4)*4 + r)*CBS + w*32 + c2*16 + (ln&15)] = acc[m][c2][r];
  __syncthreads();
  const float* bias = (mat==0)? bq : (mat==1)? bk : bv;
  #pragma unroll
  for (int i = 0; i < 4; i++) {
    int p = w*4 + i;                              // 16 (ntl, sl) pairs
    int ntl = p >> 2, sl = p & 3;
    int nt = 4*mt + ntl;
    if (nt > 48) continue;
    int row = ntl*16 + (ln & 15);
    int col = sl*32 + (ln >> 4)*8;
    float4 v0 = *(const float4*)&Cb[row*CBS + col];      // b128: uniform banks
    float4 v1 = *(const float4*)&Cb[row*CBS + col + 4];
    float v[8] = {v0.x, v0.y, v0.z, v0.w, v1.x, v1.y, v1.z, v1.w};
    #pragma unroll
    for (int j = 0; j < 8; j++) v[j] += bias[c0 + col + j];
    int token = nt*16 + (ln & 15);
    int h = (c0 >> 6) + (sl >> 1);
    int bh = b*NHD + h;
    bf16x8 pk;
    #pragma unroll
    for (int j = 0; j < 8; j++) pk[j] = (short)f2bf(v[j]);
    if (mat < 2) {
      unsigned short* Out = (mat == 0) ? Qbf : Kbf;
      *(bf16x8*)(Out + ((size_t)bh*NTILE + nt)*1024 + (size_t)(sl & 1)*512 + ln*8) = pk;
    } else {
      int d = (sl & 1)*32 + (ln >> 4)*8;
      *(bf16x8*)(Vbf + ((size_t)bh*NT + token)*HD + d) = pk;
    }
  }
}

// ---------------- K7: single-pass MFMA attention, 2 q-tiles per block -------
// Block = (q-tile pair pg, bh); K panel streamed ONCE for both tiles.
// e kept in registers (ev[2][13]); partials for both tiles merged pre-atomic.
__global__ __launch_bounds__(256, 3) void k_attn8(const unsigned short* __restrict__ Qbf,
    const unsigned short* __restrict__ Kbf, float* __restrict__ wsum) {
  __shared__ float l_tmp[2][64];
  __shared__ float rl[2][16];
  int bh = blockIdx.x & 127, pg = blockIdx.x >> 7;
  int t = threadIdx.x, w = t >> 6, ln = t & 63;
  int ntA = pg*2;
  bool hasB = (ntA + 1) < NTILE;
  int ntB = hasB ? (ntA + 1) : ntA;
  const unsigned short* QbA = Qbf + ((size_t)bh*NTILE + ntA)*1024;
  const unsigned short* QbB = Qbf + ((size_t)bh*NTILE + ntB)*1024;
  const unsigned short* Kb = Kbf + (size_t)bh*NTILE*1024;
  bf16x8 qA0 = *(const bf16x8*)(QbA + ln*8);
  bf16x8 qA1 = *(const bf16x8*)(QbA + 512 + ln*8);
  bf16x8 qB0 = *(const bf16x8*)(QbB + ln*8);
  bf16x8 qB1 = *(const bf16x8*)(QbB + 512 + ln*8);
  f32x4 evA[13], evB[13];
  float lpA[4] = {0.f,0.f,0.f,0.f}, lpB[4] = {0.f,0.f,0.f,0.f};
  #pragma unroll
  for (int i = 0; i < 13; i++) {
    int mt = w + 4*i;
    bool valid = (i < 12) || (w == 0);            // only w==0 has a 13th tile
    int mtc = valid ? mt : 48;
    bf16x8 k0 = *(const bf16x8*)(Kb + (size_t)mtc*1024 + ln*8);
    bf16x8 k1 = *(const bf16x8*)(Kb + (size_t)mtc*1024 + 512 + ln*8);
    f32x4 a = {0.f,0.f,0.f,0.f};
    a = __builtin_amdgcn_mfma_f32_16x16x32_bf16(qA0, k0, a, 0,0,0);
    a = __builtin_amdgcn_mfma_f32_16x16x32_bf16(qA1, k1, a, 0,0,0);
    f32x4 c = {0.f,0.f,0.f,0.f};
    c = __builtin_amdgcn_mfma_f32_16x16x32_bf16(qB0, k0, c, 0,0,0);
    c = __builtin_amdgcn_mfma_f32_16x16x32_bf16(qB1, k1, c, 0,0,0);
    f32x4 ea, eb;
    #pragma unroll
    for (int r = 0; r < 4; r++) {
      ea[r] = __expf(a[r]*0.125f);                // n=(ln>>4)*4+r, m-col=ln&15
      eb[r] = __expf(c[r]*0.125f);
    }
    evA[i] = ea; evB[i] = eb;
    if (valid) {
      #pragma unroll
      for (int r = 0; r < 4; r++) { lpA[r] += ea[r]; lpB[r] += eb[r]; }
    }
  }
  #pragma unroll
  for (int r = 0; r < 4; r++) {
    float v = lpA[r];
    v += __shfl_xor(v,1,64); v += __shfl_xor(v,2,64);
    v += __shfl_xor(v,4,64); v += __shfl_xor(v,8,64);
    if ((ln & 15) == 0) l_tmp[0][w*16 + (ln>>4)*4 + r] = v;
    float u = lpB[r];
    u += __shfl_xor(u,1,64); u += __shfl_xor(u,2,64);
    u += __shfl_xor(u,4,64); u += __shfl_xor(u,8,64);
    if ((ln & 15) == 0) l_tmp[1][w*16 + (ln>>4)*4 + r] = u;
  }
  __syncthreads();
  if (t < 32) {
    int g = t >> 4, q = t & 15;
    rl[g][q] = 1.f / (l_tmp[g][q] + l_tmp[g][16+q] + l_tmp[g][32+q] + l_tmp[g][48+q]);
  }
  __syncthreads();
  f32x4 rlA = *(const f32x4*)&rl[0][(ln >> 4)*4];
  f32x4 rlB = *(const f32x4*)&rl[1][(ln >> 4)*4];
  #pragma unroll
  for (int i = 0; i < 13; i++) {
    int mt = w + 4*i;
    bool valid = (i < 12) || (w == 0);
    float v = evA[i][0]*rlA[0] + evA[i][1]*rlA[1] + evA[i][2]*rlA[2] + evA[i][3]*rlA[3];
    if (hasB)
      v += evB[i][0]*rlB[0] + evB[i][1]*rlB[1] + evB[i][2]*rlB[2] + evB[i][3]*rlB[3];
    v += __shfl_xor(v, 16, 64);                   // sum over the 4 n-quads
    v += __shfl_xor(v, 32, 64);
    if (valid && ln < 16)
      atomicAdd(&wsum[bh*NT + mt*16 + ln], v);
  }
}

// ---- K7c: abar[bh,d] = (1/N) sum_m w_m V[m,d] (V bf16) ---------------------
__global__ void k_attn_av(const float* __restrict__ w, const unsigned short* __restrict__ Vm,
                          float* __restrict__ abar) {
  __shared__ float red[256];
  int bh = blockIdx.x, t = threadIdx.x;
  int d = t & 63, chunk = t >> 6;                 // 4 chunks of 196 keys
  float acc = 0.f;
  const unsigned short* vb = Vm + (size_t)bh*NT*HD;
  const float* wb = w + bh*NT;
  for (int m = chunk*196; m < (chunk+1)*196; m++)
    acc += wb[m] * bf2f(vb[(size_t)m*HD + d]);
  red[t] = acc;
  __syncthreads();
  if (t < 64)
    abar[bh*HD + t] = (red[t] + red[64+t] + red[128+t] + red[192+t]) * (1.f/NT);
}

// --------- K8: pooled head ---------------------------------------------------
// A: pv = bo + p1 + abar @ wo^T;  grid (16,16), 32 c'/block
__global__ void k_headA(const float* __restrict__ p1, const float* __restrict__ abar,
                        const float* __restrict__ wo, const float* __restrict__ bo,
                        float* __restrict__ pv) {
  int b = blockIdx.x, cg = blockIdx.y;
  int t = threadIdx.x, w = t >> 6, ln = t & 63;
  float a[8];
  #pragma unroll
  for (int k = 0; k < 8; k++) a[k] = abar[b*CC + ln + 64*k];
  int c0 = cg*32 + w*8;
  for (int i = 0; i < 8; i++) {
    int c = c0 + i;
    const float* wr = wo + (size_t)c*CC;
    float s = 0.f;
    #pragma unroll
    for (int k = 0; k < 8; k++) s += a[k] * wr[ln + 64*k];
    for (int o = 32; o; o >>= 1) s += __shfl_down(s, o, 64);
    if (ln == 0) pv[b*CC + c] = s + bo[c] + p1[b*CC + c];
  }
}

// C: per-wave LN, fc1 dots + ReLU, fused fc2 partial dot -> atomicAdd(out)
__global__ void k_headC(const float* __restrict__ pv, const float* __restrict__ ln_g,
                        const float* __restrict__ ln_b, const float* __restrict__ fc1_w,
                        const float* __restrict__ fc1_b, const float* __restrict__ fc2_w,
                        const float* __restrict__ fc2_b, float* __restrict__ out) {
  int b = blockIdx.x, cg = blockIdx.y;
  int t = threadIdx.x, w = t >> 6, ln = t & 63;
  float a[8];
  float s = 0.f, s2 = 0.f;
  #pragma unroll
  for (int k = 0; k < 8; k++) {
    a[k] = pv[b*CC + ln + 64*k];
    s += a[k]; s2 += a[k]*a[k];
  }
  for (int o = 32; o; o >>= 1) { s += __shfl_down(s, o, 64); s2 += __shfl_down(s2, o, 64); }
  s = __shfl(s, 0, 64); s2 = __shfl(s2, 0, 64);
  float mean = s * (1.f/CC);
  float rs = rsqrtf(s2*(1.f/CC) - mean*mean + 1e-5f);
  #pragma unroll
  for (int k = 0; k < 8; k++)
    a[k] = (a[k]-mean)*rs*ln_g[ln + 64*k] + ln_b[ln + 64*k];
  int c0 = cg*32 + w*8;
  float o2 = 0.f;                                 // fc2 partial over this wave's 8 c
  for (int i = 0; i < 8; i++) {
    int c = c0 + i;
    const float* wr = fc1_w + (size_t)c*CC;
    float v = 0.f;
    #pragma unroll
    for (int k = 0; k < 8; k++) v += a[k] * wr[ln + 64*k];
    for (int o = 32; o; o >>= 1) v += __shfl_down(v, o, 64);
    if (ln == 0) o2 += fmaxf(v + fc1_b[c], 0.f) * fc2_w[c];
  }
  if (ln == 0) {
    if (cg == 0 && w == 0) o2 += fc2_b[0];
    atomicAdd(&out[b], o2);
  }
}

extern "C" void kernel_launch(void* const* d_in, const int* in_sizes, int n_in,
                              void* d_out, int out_size, void* d_ws, size_t ws_size,
                              hipStream_t stream) {
  const float* x       = (const float*)d_in[0];
  const float* mlp_w1  = (const float*)d_in[1];
  const float* mlp_b1  = (const float*)d_in[2];
  const float* mlp_w2  = (const float*)d_in[3];
  const float* mlp_b2  = (const float*)d_in[4];
  const float* sp_w    = (const float*)d_in[5];
  const float* sp_g    = (const float*)d_in[6];
  const float* sp_b    = (const float*)d_in[7];
  const float* sp_mu   = (const float*)d_in[8];
  const float* sp_var  = (const float*)d_in[9];
  const float* wq      = (const float*)d_in[10];
  const float* bq      = (const float*)d_in[11];
  const float* wk      = (const float*)d_in[12];
  const float* bk      = (const float*)d_in[13];
  const float* wv      = (const float*)d_in[14];
  const float* bv      = (const float*)d_in[15];
  const float* wo      = (const float*)d_in[16];
  const float* bo      = (const float*)d_in[17];
  const float* ln_g    = (const float*)d_in[18];
  const float* ln_b    = (const float*)d_in[19];
  const float* fc1_w   = (const float*)d_in[20];
  const float* fc1_b   = (const float*)d_in[21];
  const float* fc2_w   = (const float*)d_in[22];
  const float* fc2_b   = (const float*)d_in[23];

  float* ws = (float*)d_ws;
  float* avg_p = ws + OFS_AVGP;
  float* max_p = ws + OFS_MAXP;
  float* chs   = ws + OFS_CHS;
  float* sp    = ws + OFS_SP;
  float* p1    = ws + OFS_P1;
  float* abar  = ws + OFS_ABAR;
  unsigned short* xgT = (unsigned short*)(ws + OFS_XGT);
  unsigned short* Qbf = (unsigned short*)(ws + OFS_QBF);
  unsigned short* Kbf = (unsigned short*)(ws + OFS_KBF);
  unsigned short* Vbf = (unsigned short*)(ws + OFS_V2);
  unsigned short* Wf  = (unsigned short*)(ws + OFS_WF);
  float* wsum  = ws + OFS_W;
  float* pv    = ws + OFS_PV;
  float* cmaxp = ws + OFS_CMAXP;
  float* cmeanp= ws + OFS_CMEANP;

  hipMemsetAsync(wsum, 0, BB*NHD*NT*sizeof(float), stream);
  hipMemsetAsync(d_out, 0, (size_t)out_size*sizeof(float), stream);

  k_pool   <<<2048, 256, 0, stream>>>(x, avg_p, max_p);
  k_chmlp  <<<BB, 256, 0, stream>>>(avg_p, max_p, mlp_w1, mlp_b1, mlp_w2, mlp_b2, chs);
  k_chgatep<<<dim3(BB,16), 256, 0, stream>>>(x, chs, cmaxp, cmeanp);
  k_credsp <<<BB, 256, 0, stream>>>(cmaxp, cmeanp, sp_w, sp_g, sp_b, sp_mu, sp_var, sp);
  k_wfrag  <<<384, 256, 0, stream>>>(wq, wk, wv, Wf);
  k_sfuse  <<<dim3(NTILE,BB), 256, 0, stream>>>(x, chs, sp, xgT);
  k_p1     <<<dim3(BB,16), 256, 0, stream>>>(xgT, p1);
  k_qkv_mfma<<<2496, 256, 0, stream>>>(xgT, Wf, bq, bk, bv, Qbf, Kbf, Vbf);
  k_attn8  <<<25*128, 256, 0, stream>>>(Qbf, Kbf, wsum);
  k_attn_av<<<128, 256, 0, stream>>>(wsum, Vbf, abar);
  k_headA  <<<dim3(BB,16), 256, 0, stream>>>(p1, abar, wo, bo, pv);
  k_headC  <<<dim3(BB,16), 256, 0, stream>>>(pv, ln_g, ln_b, fc1_w, fc1_b,
                                             fc2_w, fc2_b, (float*)d_out);
}